// Round 1
// baseline (3213.215 us; speedup 1.0000x reference)
//
#include <hip/hip_runtime.h>
#include <hip/hip_bf16.h>
#include <cstdint>
#include <cstddef>

// ---------------------------------------------------------------------------
// RGNN_53755810677120 — fp32 baseline implementation.
//
// Pipeline (all fp32):
//   enc:    x[N,112] -> pad/PE/W_emb -> h[N,128]
//   CSR:    per edge-label counting-sort by dst (hist + 3-kernel scan + place)
//   layer l in {0,1}:
//     attn(l,0)(in)        -> xout            (root)
//     for e: attn(l,e+1)(in)-> xt ; xout[dst] += sum_{edges} xt[src]  (CSR gather)
//     (relu applied lazily on next consumer's load)
//   pool:   per-graph mean of relu(xout)  -> g[64,128]
//   dec:    relu(g@W1+b1)@W2+b2 -> out[64]
// ---------------------------------------------------------------------------

#define NB 16   // nodes per attention tile

// ---------------------------- encoder --------------------------------------
__global__ __launch_bounds__(128) void enc_kernel(
    const float* __restrict__ x, const float* __restrict__ Wemb,
    float* __restrict__ h, int N)
{
    __shared__ float sxr[8 * 112];
    __shared__ float spe[128];
    __shared__ float sW[1024];
    const int t = threadIdx.x;           // 128 threads
    const int n0 = blockIdx.x * 8;

    // positional encoding pe[s][f], s = t>>5, f = t&31
    {
        int s = t >> 5, f = t & 31;
        int i2 = f >> 1;
        float div = __expf(-(float)(2 * i2) * (logf(10000.0f) / 32.0f));
        float ang = (float)s * div;
        spe[t] = (f & 1) ? cosf(ang) : sinf(ang);
    }
    for (int i = t; i < 1024; i += 128) sW[i] = Wemb[i];
    for (int i = t; i < 8 * 112; i += 128) {
        int n = n0 + i / 112;
        sxr[i] = (n < N) ? x[(size_t)n0 * 112 + i] : 0.f;
    }
    __syncthreads();

    const int ts = t >> 5, c = t & 31;
    const int offs_[4] = {0, 16, 48, 80};
    const int lens_[4] = {16, 32, 32, 32};
    const int off = offs_[ts], len = lens_[ts];

    float acc[8];
#pragma unroll
    for (int i = 0; i < 8; ++i) acc[i] = 0.f;
    float pw = 0.f;                       // sum_f pe[s][f]*W[f][c] (pad region included)
    for (int f = 0; f < 32; ++f) {
        float wv = sW[f * 32 + c];
        float pv = spe[ts * 32 + f];
        pw += pv * wv;
        if (f < len) {
#pragma unroll
            for (int i = 0; i < 8; ++i) acc[i] += sxr[i * 112 + off + f] * wv;
        }
    }
#pragma unroll
    for (int i = 0; i < 8; ++i) {
        int n = n0 + i;
        if (n < N) h[(size_t)n * 128 + ts * 32 + c] = acc[i] + pw;
    }
}

// ---------------------------- attention ------------------------------------
// Block = 256 threads processes NB=16 nodes/tile. All GEMM stages register-
// block 8 nodes per thread so each LDS weight read feeds 8 (qkv: 24) FMAs.
__global__ __launch_bounds__(256) void attn_kernel(
    const float* __restrict__ in, float* __restrict__ out,
    const float* __restrict__ Wqkv,                 // [32*96]
    const float* __restrict__ W1, const float* __restrict__ B1,
    const float* __restrict__ W2, const float* __restrict__ B2,
    int N, int relu_in)
{
    __shared__ float sW[32 * 96];
    __shared__ float sW1[32 * 32];
    __shared__ float sW2[32 * 32];
    __shared__ float sB1[32];
    __shared__ float sB2[32];
    __shared__ float sX[NB * 4 * 33];   // stride-33 padded [node][s][c]
    __shared__ float sQ[NB * 4 * 33];
    __shared__ float sK[NB * 4 * 33];
    __shared__ float sV[NB * 4 * 33];
    __shared__ float sY[NB * 4 * 33];
    __shared__ float sAtt[NB * 17];

    const int t = threadIdx.x;
    for (int i = t; i < 3072; i += 256) sW[i] = Wqkv[i];
    for (int i = t; i < 1024; i += 256) { sW1[i] = W1[i]; sW2[i] = W2[i]; }
    if (t < 32) { sB1[t] = B1[t]; sB2[t] = B2[t]; }

    const int g  = t >> 7;        // node-group 0..1 (8 nodes each)
    const int ts = (t >> 5) & 3;  // token
    const int c  = t & 31;        // channel

    const int ntiles = (N + NB - 1) / NB;
    for (int tile = blockIdx.x; tile < ntiles; tile += gridDim.x) {
        const int n0 = tile * NB;
        __syncthreads();  // weights ready (iter 0); sX free from prev iter

        // ---- stage X: load 16x128, optional relu ----
        {
            const float4* in4 = (const float4*)(in + (size_t)n0 * 128);
            for (int p = 0; p < 2; ++p) {
                int idx = t + p * 256;            // 0..511
                int nl = idx >> 5, j4 = idx & 31;
                float4 v = make_float4(0.f, 0.f, 0.f, 0.f);
                if (n0 + nl < N) v = in4[nl * 32 + j4];
                if (relu_in) {
                    v.x = fmaxf(v.x, 0.f); v.y = fmaxf(v.y, 0.f);
                    v.z = fmaxf(v.z, 0.f); v.w = fmaxf(v.w, 0.f);
                }
                int ss = j4 >> 3, cc = (j4 & 7) * 4;
                float* dst = &sX[nl * 132 + ss * 33 + cc];
                dst[0] = v.x; dst[1] = v.y; dst[2] = v.z; dst[3] = v.w;
            }
        }
        __syncthreads();

        // ---- qkv: q|k|v[nl][ts][c] = sum_f x[nl][ts][f] * W[f][{c,32+c,64+c}]
        float aq[8], ak[8], av[8];
#pragma unroll
        for (int i = 0; i < 8; ++i) { aq[i] = 0.f; ak[i] = 0.f; av[i] = 0.f; }
        {
            const float* xb = &sX[g * 8 * 132 + ts * 33];
            for (int f = 0; f < 32; ++f) {
                float wq = sW[f * 96 + c];
                float wk = sW[f * 96 + 32 + c];
                float wv = sW[f * 96 + 64 + c];
#pragma unroll
                for (int i = 0; i < 8; ++i) {
                    float xv = xb[i * 132 + f];
                    aq[i] += xv * wq; ak[i] += xv * wk; av[i] += xv * wv;
                }
            }
        }
#pragma unroll
        for (int i = 0; i < 8; ++i) {
            int base = (g * 8 + i) * 132 + ts * 33 + c;
            sQ[base] = aq[i]; sK[base] = ak[i]; sV[base] = av[i];
        }
        __syncthreads();

        // ---- scores: 256 threads = 16 nodes x 16 (s,t) pairs ----
        {
            int nl = t >> 4, ss = (t >> 2) & 3, tt = t & 3;
            const float* qp = &sQ[nl * 132 + ss * 33];
            const float* kp = &sK[nl * 132 + tt * 33];
            float d = 0.f;
#pragma unroll 8
            for (int c2 = 0; c2 < 32; ++c2) d += qp[c2] * kp[c2];
            sAtt[nl * 17 + ss * 4 + tt] = d * 0.1767766952966369f;  // 1/sqrt(32)
        }
        __syncthreads();

        // ---- softmax over 4 ----
        if (t < 64) {
            int nl = t >> 2, ss = t & 3;
            float* a = &sAtt[nl * 17 + ss * 4];
            float a0 = a[0], a1 = a[1], a2 = a[2], a3 = a[3];
            float m = fmaxf(fmaxf(a0, a1), fmaxf(a2, a3));
            float e0 = __expf(a0 - m), e1 = __expf(a1 - m);
            float e2 = __expf(a2 - m), e3 = __expf(a3 - m);
            float inv = 1.0f / (e0 + e1 + e2 + e3);
            a[0] = e0 * inv; a[1] = e1 * inv; a[2] = e2 * inv; a[3] = e3 * inv;
        }
        __syncthreads();

        // ---- y = att @ v (kept in regs for residual) ----
        float yv[8];
#pragma unroll
        for (int i = 0; i < 8; ++i) {
            int nl = g * 8 + i;
            const float* ap = &sAtt[nl * 17 + ts * 4];
            const float* vp = &sV[nl * 132 + c];
            float acc = ap[0] * vp[0] + ap[1] * vp[33] + ap[2] * vp[66] + ap[3] * vp[99];
            yv[i] = acc;
            sY[nl * 132 + ts * 33 + c] = acc;
        }
        __syncthreads();

        // ---- ffn1: z = relu(y@W1+b1) -> stored into sX (reuse) ----
        {
            float z[8];
#pragma unroll
            for (int i = 0; i < 8; ++i) z[i] = sB1[c];
            const float* yb = &sY[g * 8 * 132 + ts * 33];
            for (int f = 0; f < 32; ++f) {
                float w = sW1[f * 32 + c];
#pragma unroll
                for (int i = 0; i < 8; ++i) z[i] += yb[i * 132 + f] * w;
            }
#pragma unroll
            for (int i = 0; i < 8; ++i)
                sX[(g * 8 + i) * 132 + ts * 33 + c] = fmaxf(z[i], 0.f);
        }
        __syncthreads();

        // ---- ffn2 + residual + store ----
        {
            float o[8];
#pragma unroll
            for (int i = 0; i < 8; ++i) o[i] = yv[i] + sB2[c];
            const float* zb = &sX[g * 8 * 132 + ts * 33];
            for (int f = 0; f < 32; ++f) {
                float w = sW2[f * 32 + c];
#pragma unroll
                for (int i = 0; i < 8; ++i) o[i] += zb[i * 132 + f] * w;
            }
#pragma unroll
            for (int i = 0; i < 8; ++i) {
                int n = n0 + g * 8 + i;
                if (n < N) out[(size_t)n * 128 + ts * 32 + c] = o[i];
            }
        }
    }
}

// ---------------------------- CSR build ------------------------------------
__global__ void hist3_kernel(const int* __restrict__ e0, const int* __restrict__ e1,
                             const int* __restrict__ e2, int* __restrict__ cnt3,
                             int E, int N)
{
    int i = blockIdx.x * blockDim.x + threadIdx.x;
    if (i >= E) return;
    atomicAdd(&cnt3[0 * N + e0[E + i]], 1);
    atomicAdd(&cnt3[1 * N + e1[E + i]], 1);
    atomicAdd(&cnt3[2 * N + e2[E + i]], 1);
}

__global__ __launch_bounds__(256) void scan1_kernel(
    const int* __restrict__ cnt, int* __restrict__ incl, int* __restrict__ bsum, int N)
{
    __shared__ int sd[256];
    int t = threadIdx.x, i = blockIdx.x * 256 + t;
    sd[t] = (i < N) ? cnt[i] : 0;
    __syncthreads();
    for (int o = 1; o < 256; o <<= 1) {
        int v = (t >= o) ? sd[t - o] : 0;
        __syncthreads();
        sd[t] += v;
        __syncthreads();
    }
    if (i < N) incl[i] = sd[t];
    if (t == 255) bsum[blockIdx.x] = sd[255];
}

__global__ __launch_bounds__(512) void scan2_kernel(int* __restrict__ bsum, int nb)
{
    __shared__ int sd[512];
    int t = threadIdx.x;
    sd[t] = (t < nb) ? bsum[t] : 0;
    __syncthreads();
    for (int o = 1; o < 512; o <<= 1) {
        int v = (t >= o) ? sd[t - o] : 0;
        __syncthreads();
        sd[t] += v;
        __syncthreads();
    }
    if (t < nb) bsum[t] = sd[t];
}

__global__ void scan3_kernel(const int* __restrict__ incl, const int* __restrict__ bsum,
                             int* __restrict__ offs, int N)
{
    int i = blockIdx.x * 256 + threadIdx.x;
    if (i >= N) return;
    int add = (blockIdx.x > 0) ? bsum[blockIdx.x - 1] : 0;
    offs[i + 1] = incl[i] + add;
    if (i == 0) offs[0] = 0;
}

__global__ void place3_kernel(const int* __restrict__ e0, const int* __restrict__ e1,
                              const int* __restrict__ e2, const int* __restrict__ offs3,
                              int* __restrict__ fill3, int* __restrict__ csr3,
                              int E, int N)
{
    int i = blockIdx.x * blockDim.x + threadIdx.x;
    if (i >= E) return;
    const int* eptr[3] = {e0, e1, e2};
#pragma unroll
    for (int lab = 0; lab < 3; ++lab) {
        const int* e = eptr[lab];
        int src = e[i], dst = e[E + i];
        int pos = atomicAdd(&fill3[lab * N + dst], 1);
        csr3[(size_t)lab * E + offs3[lab * (N + 1) + dst] + pos] = src;
    }
}

// ---------------------------- aggregation (atomic-free) ---------------------
__global__ __launch_bounds__(256) void agg_kernel(
    const float* __restrict__ xt, const int* __restrict__ csr,
    const int* __restrict__ offs, float* __restrict__ xout, int N)
{
    int w = threadIdx.x >> 6, lane = threadIdx.x & 63;
    int dst = blockIdx.x * 4 + w;
    if (dst >= N) return;
    int beg = offs[dst], end = offs[dst + 1];
    const float2* x2 = (const float2*)xt;
    float2 acc = make_float2(0.f, 0.f);
    for (int k = beg; k < end; ++k) {
        int src = csr[k];                       // wave-uniform -> broadcast
        float2 v = x2[(size_t)src * 64 + lane]; // 512B coalesced row
        acc.x += v.x; acc.y += v.y;
    }
    float2* o2 = (float2*)xout;
    float2 cur = o2[(size_t)dst * 64 + lane];
    cur.x += acc.x; cur.y += acc.y;
    o2[(size_t)dst * 64 + lane] = cur;          // wave owns dst: no atomics
}

// ---------------------------- pool / counts / decoder ----------------------
__global__ __launch_bounds__(256) void pool_kernel(
    const float* __restrict__ in, const int* __restrict__ batch,
    float* __restrict__ gsum, int N)
{
    int t = threadIdx.x;
    int j = t & 127, half = t >> 7;
    int n0 = blockIdx.x * 64 + half * 32;
    float acc = 0.f; int cur = -1;
    for (int i = 0; i < 32; ++i) {
        int n = n0 + i;
        if (n >= N) break;
        int g = batch[n];                  // sorted -> few flushes per thread
        if (g != cur) {
            if (cur >= 0) atomicAdd(&gsum[cur * 128 + j], acc);
            cur = g; acc = 0.f;
        }
        acc += fmaxf(in[(size_t)n * 128 + j], 0.f);
    }
    if (cur >= 0) atomicAdd(&gsum[cur * 128 + j], acc);
}

__global__ __launch_bounds__(256) void cnt_kernel(
    const int* __restrict__ batch, float* __restrict__ gcnt, int N)
{
    __shared__ float lh[64];
    int t = threadIdx.x;
    if (t < 64) lh[t] = 0.f;
    __syncthreads();
    int i = blockIdx.x * 256 + t;
    if (i < N) atomicAdd(&lh[batch[i]], 1.0f);
    __syncthreads();
    if (t < 64 && lh[t] != 0.f) atomicAdd(&gcnt[t], lh[t]);
}

__global__ __launch_bounds__(128) void dec_kernel(
    const float* __restrict__ gsum, const float* __restrict__ gcnt,
    const float* __restrict__ W1, const float* __restrict__ B1,
    const float* __restrict__ W2, const float* __restrict__ B2,
    float* __restrict__ out)
{
    __shared__ float sg[128];
    __shared__ float sh[128];
    int t = threadIdx.x, b = blockIdx.x;
    float cinv = 1.0f / fmaxf(gcnt[b], 1.0f);
    sg[t] = gsum[b * 128 + t] * cinv;
    __syncthreads();
    float acc = B1[t];
    for (int f = 0; f < 128; ++f) acc += sg[f] * W1[f * 128 + t];
    sh[t] = fmaxf(acc, 0.f) * W2[t];
    __syncthreads();
    for (int o = 64; o > 0; o >>= 1) {
        if (t < o) sh[t] += sh[t + o];
        __syncthreads();
    }
    if (t == 0) out[b] = sh[0] + B2[0];
}

// ---------------------------- launch ---------------------------------------
extern "C" void kernel_launch(void* const* d_in, const int* in_sizes, int n_in,
                              void* d_out, int out_size, void* d_ws, size_t ws_size,
                              hipStream_t stream)
{
    const float* x    = (const float*)d_in[0];
    const int*   e0   = (const int*)d_in[1];
    const int*   e1   = (const int*)d_in[2];
    const int*   e2   = (const int*)d_in[3];
    const int*   bat  = (const int*)d_in[4];
    const float* Wemb = (const float*)d_in[5];
    const float* qkv  = (const float*)d_in[6];
    const float* fw1  = (const float*)d_in[7];
    const float* fb1  = (const float*)d_in[8];
    const float* fw2  = (const float*)d_in[9];
    const float* fb2  = (const float*)d_in[10];
    const float* mw1  = (const float*)d_in[11];
    const float* mb1  = (const float*)d_in[12];
    const float* mw2  = (const float*)d_in[13];
    const float* mb2  = (const float*)d_in[14];
    const int N = in_sizes[0] / 112;
    const int E = in_sizes[1] / 2;
    float* outp = (float*)d_out;
    (void)n_in; (void)out_size; (void)ws_size;

    // workspace carve-out (~167 MB total)
    char* w = (char*)d_ws;
    auto alloc = [&](size_t bytes) {
        char* p = w; w += (bytes + 255) & ~(size_t)255; return p;
    };
    float* buf0  = (float*)alloc((size_t)N * 128 * 4);
    float* buf1  = (float*)alloc((size_t)N * 128 * 4);
    float* bufxt = (float*)alloc((size_t)N * 128 * 4);
    int*   csr3  = (int*)alloc((size_t)3 * E * 4);
    int*   offs3 = (int*)alloc((size_t)3 * (N + 1) * 4);
    int*   cnt3  = (int*)alloc((size_t)3 * N * 4);
    int*   fill3 = (int*)alloc((size_t)3 * N * 4);
    int*   incl  = (int*)alloc((size_t)N * 4);
    int*   bsum  = (int*)alloc(4096);
    float* gsum  = (float*)alloc(64 * 128 * 4);
    float* gcnt  = (float*)alloc(64 * 4);

    const int nb = (N + 255) / 256;   // 391 blocks; scan2 assumes nb <= 512

    hipMemsetAsync(cnt3, 0, (size_t)3 * N * 4, stream);
    hipMemsetAsync(fill3, 0, (size_t)3 * N * 4, stream);
    hipMemsetAsync(gsum, 0, 64 * 128 * 4, stream);
    hipMemsetAsync(gcnt, 0, 64 * 4, stream);

    // encoder
    enc_kernel<<<(N + 7) / 8, 128, 0, stream>>>(x, Wemb, buf0, N);

    // CSR by dst, per label (built once, reused for both layers)
    hist3_kernel<<<(E + 255) / 256, 256, 0, stream>>>(e0, e1, e2, cnt3, E, N);
    for (int lab = 0; lab < 3; ++lab) {
        scan1_kernel<<<nb, 256, 0, stream>>>(cnt3 + (size_t)lab * N, incl, bsum, N);
        scan2_kernel<<<1, 512, 0, stream>>>(bsum, nb);
        scan3_kernel<<<nb, 256, 0, stream>>>(incl, bsum, offs3 + (size_t)lab * (N + 1), N);
    }
    place3_kernel<<<(E + 255) / 256, 256, 0, stream>>>(e0, e1, e2, offs3, fill3, csr3, E, N);

    const int ATT_GRID = (N + NB - 1) / NB;
    auto run_layer = [&](const float* lin, float* lout, int l, int relu_in) {
        for (int a = 0; a < 4; ++a) {
            size_t pi = (size_t)(l * 4 + a);
            const float* wq = qkv + pi * 32 * 96;
            const float* w1 = fw1 + pi * 32 * 32;
            const float* b1 = fb1 + pi * 32;
            const float* w2 = fw2 + pi * 32 * 32;
            const float* b2 = fb2 + pi * 32;
            float* dst = (a == 0) ? lout : bufxt;
            attn_kernel<<<ATT_GRID, 256, 0, stream>>>(lin, dst, wq, w1, b1, w2, b2, N, relu_in);
            if (a > 0) {
                int lab = a - 1;
                agg_kernel<<<(N + 3) / 4, 256, 0, stream>>>(
                    bufxt, csr3 + (size_t)lab * E, offs3 + (size_t)lab * (N + 1), lout, N);
            }
        }
    };
    run_layer(buf0, buf1, 0, /*relu_in=*/0);   // layer 0: h0 -> buf1
    run_layer(buf1, buf0, 1, /*relu_in=*/1);   // layer 1: relu(buf1) -> buf0

    // pool (applies relu) + counts + decoder
    pool_kernel<<<(N + 63) / 64, 256, 0, stream>>>(buf0, bat, gsum, N);
    cnt_kernel<<<(N + 255) / 256, 256, 0, stream>>>(bat, gcnt, N);
    dec_kernel<<<64, 128, 0, stream>>>(gsum, gcnt, mw1, mb1, mw2, mb2, outp);
}

// Round 2
// 1216.106 us; speedup vs baseline: 2.6422x; 2.6422x over previous
//
#include <hip/hip_runtime.h>
#include <hip/hip_bf16.h>
#include <cstdint>
#include <cstddef>

// ---------------------------------------------------------------------------
// RGNN_53755810677120 — round 2: MFMA bf16 attention.
//
//   enc:    x[N,112] -> pad/PE/W_emb -> h[N,128]                    (fp32)
//   CSR:    per edge-label counting-sort by dst
//   attn:   bf16 MFMA 16x16x32, fp32 accum, wave-private LDS bounce
//   agg:    CSR gather, wave-per-dst, atomic-free                   (fp32)
//   pool/dec: fp32
// ---------------------------------------------------------------------------

typedef __attribute__((ext_vector_type(8))) short bf16x8;
typedef __attribute__((ext_vector_type(4))) float f32x4;

__device__ inline short f2bf(float f) {
    union { float f; unsigned u; } v; v.f = f;
    unsigned r = (v.u + 0x7FFFu + ((v.u >> 16) & 1u)) >> 16;   // RNE
    return (short)r;
}

// ---------------------------- encoder --------------------------------------
__global__ __launch_bounds__(128) void enc_kernel(
    const float* __restrict__ x, const float* __restrict__ Wemb,
    float* __restrict__ h, int N)
{
    __shared__ float sxr[8 * 112];
    __shared__ float spe[128];
    __shared__ float sW[1024];
    const int t = threadIdx.x;           // 128 threads
    const int n0 = blockIdx.x * 8;

    {
        int s = t >> 5, f = t & 31;
        int i2 = f >> 1;
        float div = __expf(-(float)(2 * i2) * (logf(10000.0f) / 32.0f));
        float ang = (float)s * div;
        spe[t] = (f & 1) ? cosf(ang) : sinf(ang);
    }
    for (int i = t; i < 1024; i += 128) sW[i] = Wemb[i];
    for (int i = t; i < 8 * 112; i += 128) {
        int n = n0 + i / 112;
        sxr[i] = (n < N) ? x[(size_t)n0 * 112 + i] : 0.f;
    }
    __syncthreads();

    const int ts = t >> 5, c = t & 31;
    const int offs_[4] = {0, 16, 48, 80};
    const int lens_[4] = {16, 32, 32, 32};
    const int off = offs_[ts], len = lens_[ts];

    float acc[8];
#pragma unroll
    for (int i = 0; i < 8; ++i) acc[i] = 0.f;
    float pw = 0.f;
    for (int f = 0; f < 32; ++f) {
        float wv = sW[f * 32 + c];
        float pv = spe[ts * 32 + f];
        pw += pv * wv;
        if (f < len) {
#pragma unroll
            for (int i = 0; i < 8; ++i) acc[i] += sxr[i * 112 + off + f] * wv;
        }
    }
#pragma unroll
    for (int i = 0; i < 8; ++i) {
        int n = n0 + i;
        if (n < N) h[(size_t)n * 128 + ts * 32 + c] = acc[i] + pw;
    }
}

// ---------------------------- MFMA attention --------------------------------
// 4 waves/block; each wave owns a 4-node M-tile (16 rows = 4 nodes x 4 tokens)
// and a private 4864B LDS scratch (no __syncthreads). All GEMM stages use
// v_mfma_f32_16x16x32_bf16 (K=32 exact; PV zero-pads K 16->32).
//
// Layouts (verified per guide §3):
//   A-frag:  A[m = lane&15][k = (lane>>4)*8 + j], j=0..7
//   B-frag:  B[k = (lane>>4)*8 + j][n = lane&15]
//   C/D:     col = lane&15, row = (lane>>4)*4 + reg
#define ATT_WAVES 4
#define WLDS 4864

__global__ __launch_bounds__(256) void attn_mfma_kernel(
    const float* __restrict__ in, float* __restrict__ out,
    const float* __restrict__ Wqkv,
    const float* __restrict__ W1, const float* __restrict__ B1,
    const float* __restrict__ W2, const float* __restrict__ B2,
    int N, int relu_in)
{
    __shared__ char smem[ATT_WAVES * WLDS];
    const int lane = threadIdx.x & 63;
    const int wave = threadIdx.x >> 6;
    const int q = lane >> 4;      // quad 0..3
    const int m = lane & 15;      // row (A/C) or col (B/C) within tile

    char* wb = smem + wave * WLDS;
    short* Qb = (short*)(wb);          // [16][40] shorts, 80B row stride (also Y)
    short* Kb = (short*)(wb + 1280);   // [16][40]                       (also Z)
    short* VT = (short*)(wb + 2560);   // [32][24] shorts, 48B row stride (V^T)
    short* Pb = (short*)(wb + 4096);   // [16][24] shorts, 48B row stride

    const f32x4 zf = {0.f, 0.f, 0.f, 0.f};

    // ---- weight B-frags (register-resident, loaded once per wave) ----
    bf16x8 wqkv[6];
#pragma unroll
    for (int ci = 0; ci < 6; ++ci) {
        bf16x8 f;
#pragma unroll
        for (int j = 0; j < 8; ++j)
            f[j] = f2bf(Wqkv[(q * 8 + j) * 96 + ci * 16 + m]);
        wqkv[ci] = f;
    }
    bf16x8 w1f[2], w2f[2];
#pragma unroll
    for (int t = 0; t < 2; ++t) {
        bf16x8 f1, f2;
#pragma unroll
        for (int j = 0; j < 8; ++j) {
            f1[j] = f2bf(W1[(q * 8 + j) * 32 + t * 16 + m]);
            f2[j] = f2bf(W2[(q * 8 + j) * 32 + t * 16 + m]);
        }
        w1f[t] = f1; w2f[t] = f2;
    }
    const float b1v[2] = {B1[m], B1[m + 16]};
    const float b2v[2] = {B2[m], B2[m + 16]};

    const int ntiles = (N + 3) >> 2;
    for (int tile = blockIdx.x * ATT_WAVES + wave; tile < ntiles;
         tile += gridDim.x * ATT_WAVES) {
        const int n0 = tile * 4;
        const int node_m = n0 + (m >> 2);   // node of A-row m

        // ---- X A-frag: X[m][q*8+j] = in[n0*128 + m*32 + q*8 + j] ----
        float xr[8];
        {
            const float* xb = in + (size_t)n0 * 128 + m * 32 + q * 8;
            float4 v0 = make_float4(0.f, 0.f, 0.f, 0.f), v1 = v0;
            if (node_m < N) {
                v0 = *(const float4*)xb;
                v1 = *(const float4*)(xb + 4);
            }
            xr[0] = v0.x; xr[1] = v0.y; xr[2] = v0.z; xr[3] = v0.w;
            xr[4] = v1.x; xr[5] = v1.y; xr[6] = v1.z; xr[7] = v1.w;
            if (relu_in) {
#pragma unroll
                for (int j = 0; j < 8; ++j) xr[j] = fmaxf(xr[j], 0.f);
            }
        }
        bf16x8 ax;
#pragma unroll
        for (int j = 0; j < 8; ++j) ax[j] = f2bf(xr[j]);

        // ---- qkv: 6 MFMAs -> Q,K (row-major LDS), V (transposed LDS) ----
        f32x4 accq[6];
#pragma unroll
        for (int ci = 0; ci < 6; ++ci)
            accq[ci] = __builtin_amdgcn_mfma_f32_16x16x32_bf16(ax, wqkv[ci], zf, 0, 0, 0);
#pragma unroll
        for (int t = 0; t < 2; ++t) {
#pragma unroll
            for (int r = 0; r < 4; ++r) {
                Qb[(q * 4 + r) * 40 + m + 16 * t] = f2bf(accq[t][r]);
                Kb[(q * 4 + r) * 40 + m + 16 * t] = f2bf(accq[2 + t][r]);
            }
            uint2 d;
            d.x = (unsigned short)f2bf(accq[4 + t][0]) |
                  ((unsigned)(unsigned short)f2bf(accq[4 + t][1]) << 16);
            d.y = (unsigned short)f2bf(accq[4 + t][2]) |
                  ((unsigned)(unsigned short)f2bf(accq[4 + t][3]) << 16);
            *(uint2*)((char*)VT + (size_t)(m + 16 * t) * 48 + q * 8) = d;
        }

        // ---- scores: S = Q @ K^T  (K^T as B == A-layout read of K) ----
        bf16x8 aq = *(const bf16x8*)((char*)Qb + m * 80 + q * 16);
        bf16x8 bk = *(const bf16x8*)((char*)Kb + m * 80 + q * 16);
        f32x4 s = __builtin_amdgcn_mfma_f32_16x16x32_bf16(aq, bk, zf, 0, 0, 0);

        // ---- softmax over 4 tokens (4-lane butterfly; valid block only) ----
        const bool valid = ((m >> 2) == q);
        float p[4];
#pragma unroll
        for (int r = 0; r < 4; ++r) {
            float v = s[r] * 0.1767766952966369f;   // 1/sqrt(32)
            float mx = fmaxf(v, __shfl_xor(v, 1));
            mx = fmaxf(mx, __shfl_xor(mx, 2));
            float e = __expf(v - mx);
            float sm = e + __shfl_xor(e, 1);
            sm += __shfl_xor(sm, 2);
            p[r] = e / sm;
        }
#pragma unroll
        for (int r = 0; r < 4; ++r)
            Pb[(q * 4 + r) * 24 + m] = valid ? f2bf(p[r]) : (short)0;

        // ---- PV: Y = P @ V (K padded 16->32 with zeros) ----
        bf16x8 ap = {0, 0, 0, 0, 0, 0, 0, 0};
        if (q < 2) ap = *(const bf16x8*)((char*)Pb + m * 48 + q * 16);
        f32x4 y[2];
#pragma unroll
        for (int t = 0; t < 2; ++t) {
            bf16x8 bv = {0, 0, 0, 0, 0, 0, 0, 0};
            if (q < 2) bv = *(const bf16x8*)((char*)VT + (size_t)(m + 16 * t) * 48 + q * 16);
            y[t] = __builtin_amdgcn_mfma_f32_16x16x32_bf16(ap, bv, zf, 0, 0, 0);
        }

        // ---- Y bounce (into Q buffer) -> ffn1 ----
#pragma unroll
        for (int t = 0; t < 2; ++t)
#pragma unroll
            for (int r = 0; r < 4; ++r)
                Qb[(q * 4 + r) * 40 + m + 16 * t] = f2bf(y[t][r]);
        bf16x8 ay = *(const bf16x8*)((char*)Qb + m * 80 + q * 16);
        f32x4 z1[2];
#pragma unroll
        for (int t = 0; t < 2; ++t)
            z1[t] = __builtin_amdgcn_mfma_f32_16x16x32_bf16(ay, w1f[t], zf, 0, 0, 0);

        // ---- relu(z1+b1) bounce (into K buffer) -> ffn2 ----
#pragma unroll
        for (int t = 0; t < 2; ++t)
#pragma unroll
            for (int r = 0; r < 4; ++r)
                Kb[(q * 4 + r) * 40 + m + 16 * t] = f2bf(fmaxf(z1[t][r] + b1v[t], 0.f));
        bf16x8 az = *(const bf16x8*)((char*)Kb + m * 80 + q * 16);
        f32x4 o[2];
#pragma unroll
        for (int t = 0; t < 2; ++t)
            o[t] = __builtin_amdgcn_mfma_f32_16x16x32_bf16(az, w2f[t], zf, 0, 0, 0);

        // ---- residual + bias + store (fp32) ----
#pragma unroll
        for (int t = 0; t < 2; ++t)
#pragma unroll
            for (int r = 0; r < 4; ++r) {
                int row = q * 4 + r;
                int node = n0 + (row >> 2);
                if (node < N)
                    out[(size_t)n0 * 128 + row * 32 + m + 16 * t] =
                        y[t][r] + o[t][r] + b2v[t];
            }
    }
}

// ---------------------------- CSR build ------------------------------------
__global__ void hist3_kernel(const int* __restrict__ e0, const int* __restrict__ e1,
                             const int* __restrict__ e2, int* __restrict__ cnt3,
                             int E, int N)
{
    int i = blockIdx.x * blockDim.x + threadIdx.x;
    if (i >= E) return;
    atomicAdd(&cnt3[0 * N + e0[E + i]], 1);
    atomicAdd(&cnt3[1 * N + e1[E + i]], 1);
    atomicAdd(&cnt3[2 * N + e2[E + i]], 1);
}

__global__ __launch_bounds__(256) void scan1_kernel(
    const int* __restrict__ cnt, int* __restrict__ incl, int* __restrict__ bsum, int N)
{
    __shared__ int sd[256];
    int t = threadIdx.x, i = blockIdx.x * 256 + t;
    sd[t] = (i < N) ? cnt[i] : 0;
    __syncthreads();
    for (int o = 1; o < 256; o <<= 1) {
        int v = (t >= o) ? sd[t - o] : 0;
        __syncthreads();
        sd[t] += v;
        __syncthreads();
    }
    if (i < N) incl[i] = sd[t];
    if (t == 255) bsum[blockIdx.x] = sd[255];
}

__global__ __launch_bounds__(512) void scan2_kernel(int* __restrict__ bsum, int nb)
{
    __shared__ int sd[512];
    int t = threadIdx.x;
    sd[t] = (t < nb) ? bsum[t] : 0;
    __syncthreads();
    for (int o = 1; o < 512; o <<= 1) {
        int v = (t >= o) ? sd[t - o] : 0;
        __syncthreads();
        sd[t] += v;
        __syncthreads();
    }
    if (t < nb) bsum[t] = sd[t];
}

__global__ void scan3_kernel(const int* __restrict__ incl, const int* __restrict__ bsum,
                             int* __restrict__ offs, int N)
{
    int i = blockIdx.x * 256 + threadIdx.x;
    if (i >= N) return;
    int add = (blockIdx.x > 0) ? bsum[blockIdx.x - 1] : 0;
    offs[i + 1] = incl[i] + add;
    if (i == 0) offs[0] = 0;
}

__global__ void place3_kernel(const int* __restrict__ e0, const int* __restrict__ e1,
                              const int* __restrict__ e2, const int* __restrict__ offs3,
                              int* __restrict__ fill3, int* __restrict__ csr3,
                              int E, int N)
{
    int i = blockIdx.x * blockDim.x + threadIdx.x;
    if (i >= E) return;
    const int* eptr[3] = {e0, e1, e2};
#pragma unroll
    for (int lab = 0; lab < 3; ++lab) {
        const int* e = eptr[lab];
        int src = e[i], dst = e[E + i];
        int pos = atomicAdd(&fill3[lab * N + dst], 1);
        csr3[(size_t)lab * E + offs3[lab * (N + 1) + dst] + pos] = src;
    }
}

// ---------------------------- aggregation (atomic-free) ---------------------
__global__ __launch_bounds__(256) void agg_kernel(
    const float* __restrict__ xt, const int* __restrict__ csr,
    const int* __restrict__ offs, float* __restrict__ xout, int N)
{
    int w = threadIdx.x >> 6, lane = threadIdx.x & 63;
    int dst = blockIdx.x * 4 + w;
    if (dst >= N) return;
    int beg = offs[dst], end = offs[dst + 1];
    const float2* x2 = (const float2*)xt;
    float2 acc = make_float2(0.f, 0.f);
    for (int k = beg; k < end; ++k) {
        int src = csr[k];
        float2 v = x2[(size_t)src * 64 + lane];
        acc.x += v.x; acc.y += v.y;
    }
    float2* o2 = (float2*)xout;
    float2 cur = o2[(size_t)dst * 64 + lane];
    cur.x += acc.x; cur.y += acc.y;
    o2[(size_t)dst * 64 + lane] = cur;
}

// ---------------------------- pool / counts / decoder ----------------------
__global__ __launch_bounds__(256) void pool_kernel(
    const float* __restrict__ in, const int* __restrict__ batch,
    float* __restrict__ gsum, int N)
{
    int t = threadIdx.x;
    int j = t & 127, half = t >> 7;
    int n0 = blockIdx.x * 64 + half * 32;
    float acc = 0.f; int cur = -1;
    for (int i = 0; i < 32; ++i) {
        int n = n0 + i;
        if (n >= N) break;
        int g = batch[n];
        if (g != cur) {
            if (cur >= 0) atomicAdd(&gsum[cur * 128 + j], acc);
            cur = g; acc = 0.f;
        }
        acc += fmaxf(in[(size_t)n * 128 + j], 0.f);
    }
    if (cur >= 0) atomicAdd(&gsum[cur * 128 + j], acc);
}

__global__ __launch_bounds__(256) void cnt_kernel(
    const int* __restrict__ batch, float* __restrict__ gcnt, int N)
{
    __shared__ float lh[64];
    int t = threadIdx.x;
    if (t < 64) lh[t] = 0.f;
    __syncthreads();
    int i = blockIdx.x * 256 + t;
    if (i < N) atomicAdd(&lh[batch[i]], 1.0f);
    __syncthreads();
    if (t < 64 && lh[t] != 0.f) atomicAdd(&gcnt[t], lh[t]);
}

__global__ __launch_bounds__(128) void dec_kernel(
    const float* __restrict__ gsum, const float* __restrict__ gcnt,
    const float* __restrict__ W1, const float* __restrict__ B1,
    const float* __restrict__ W2, const float* __restrict__ B2,
    float* __restrict__ out)
{
    __shared__ float sg[128];
    __shared__ float sh[128];
    int t = threadIdx.x, b = blockIdx.x;
    float cinv = 1.0f / fmaxf(gcnt[b], 1.0f);
    sg[t] = gsum[b * 128 + t] * cinv;
    __syncthreads();
    float acc = B1[t];
    for (int f = 0; f < 128; ++f) acc += sg[f] * W1[f * 128 + t];
    sh[t] = fmaxf(acc, 0.f) * W2[t];
    __syncthreads();
    for (int o = 64; o > 0; o >>= 1) {
        if (t < o) sh[t] += sh[t + o];
        __syncthreads();
    }
    if (t == 0) out[b] = sh[0] + B2[0];
}

// ---------------------------- launch ---------------------------------------
extern "C" void kernel_launch(void* const* d_in, const int* in_sizes, int n_in,
                              void* d_out, int out_size, void* d_ws, size_t ws_size,
                              hipStream_t stream)
{
    const float* x    = (const float*)d_in[0];
    const int*   e0   = (const int*)d_in[1];
    const int*   e1   = (const int*)d_in[2];
    const int*   e2   = (const int*)d_in[3];
    const int*   bat  = (const int*)d_in[4];
    const float* Wemb = (const float*)d_in[5];
    const float* qkv  = (const float*)d_in[6];
    const float* fw1  = (const float*)d_in[7];
    const float* fb1  = (const float*)d_in[8];
    const float* fw2  = (const float*)d_in[9];
    const float* fb2  = (const float*)d_in[10];
    const float* mw1  = (const float*)d_in[11];
    const float* mb1  = (const float*)d_in[12];
    const float* mw2  = (const float*)d_in[13];
    const float* mb2  = (const float*)d_in[14];
    const int N = in_sizes[0] / 112;
    const int E = in_sizes[1] / 2;
    float* outp = (float*)d_out;
    (void)n_in; (void)out_size; (void)ws_size;

    char* w = (char*)d_ws;
    auto alloc = [&](size_t bytes) {
        char* p = w; w += (bytes + 255) & ~(size_t)255; return p;
    };
    float* buf0  = (float*)alloc((size_t)N * 128 * 4);
    float* buf1  = (float*)alloc((size_t)N * 128 * 4);
    float* bufxt = (float*)alloc((size_t)N * 128 * 4);
    int*   csr3  = (int*)alloc((size_t)3 * E * 4);
    int*   offs3 = (int*)alloc((size_t)3 * (N + 1) * 4);
    int*   cnt3  = (int*)alloc((size_t)3 * N * 4);
    int*   fill3 = (int*)alloc((size_t)3 * N * 4);
    int*   incl  = (int*)alloc((size_t)N * 4);
    int*   bsum  = (int*)alloc(4096);
    float* gsum  = (float*)alloc(64 * 128 * 4);
    float* gcnt  = (float*)alloc(64 * 4);

    const int nb = (N + 255) / 256;   // scan2 assumes nb <= 512

    hipMemsetAsync(cnt3, 0, (size_t)3 * N * 4, stream);
    hipMemsetAsync(fill3, 0, (size_t)3 * N * 4, stream);
    hipMemsetAsync(gsum, 0, 64 * 128 * 4, stream);
    hipMemsetAsync(gcnt, 0, 64 * 4, stream);

    enc_kernel<<<(N + 7) / 8, 128, 0, stream>>>(x, Wemb, buf0, N);

    hist3_kernel<<<(E + 255) / 256, 256, 0, stream>>>(e0, e1, e2, cnt3, E, N);
    for (int lab = 0; lab < 3; ++lab) {
        scan1_kernel<<<nb, 256, 0, stream>>>(cnt3 + (size_t)lab * N, incl, bsum, N);
        scan2_kernel<<<1, 512, 0, stream>>>(bsum, nb);
        scan3_kernel<<<nb, 256, 0, stream>>>(incl, bsum, offs3 + (size_t)lab * (N + 1), N);
    }
    place3_kernel<<<(E + 255) / 256, 256, 0, stream>>>(e0, e1, e2, offs3, fill3, csr3, E, N);

    const int ATT_GRID = 1024;    // persistent: 4 waves/block, grid-stride tiles
    auto run_layer = [&](const float* lin, float* lout, int l, int relu_in) {
        for (int a = 0; a < 4; ++a) {
            size_t pi = (size_t)(l * 4 + a);
            const float* wq = qkv + pi * 32 * 96;
            const float* w1 = fw1 + pi * 32 * 32;
            const float* b1 = fb1 + pi * 32;
            const float* w2 = fw2 + pi * 32 * 32;
            const float* b2 = fb2 + pi * 32;
            float* dst = (a == 0) ? lout : bufxt;
            attn_mfma_kernel<<<ATT_GRID, 256, 0, stream>>>(lin, dst, wq, w1, b1, w2, b2, N, relu_in);
            if (a > 0) {
                int lab = a - 1;
                agg_kernel<<<(N + 3) / 4, 256, 0, stream>>>(
                    bufxt, csr3 + (size_t)lab * E, offs3 + (size_t)lab * (N + 1), lout, N);
            }
        }
    };
    run_layer(buf0, buf1, 0, /*relu_in=*/0);
    run_layer(buf1, buf0, 1, /*relu_in=*/1);

    pool_kernel<<<(N + 63) / 64, 256, 0, stream>>>(buf0, bat, gsum, N);
    cnt_kernel<<<(N + 255) / 256, 256, 0, stream>>>(bat, gcnt, N);
    dec_kernel<<<64, 128, 0, stream>>>(gsum, gcnt, mw1, mb1, mw2, mb2, outp);
}

// Round 3
// 1100.402 us; speedup vs baseline: 2.9200x; 1.1051x over previous
//
#include <hip/hip_runtime.h>
#include <hip/hip_bf16.h>
#include <cstdint>
#include <cstddef>

// ---------------------------------------------------------------------------
// RGNN_53755810677120 — round 3.
//   enc:    x[N,112] -> pad/PE/W_emb -> h[N,128]                    (fp32)
//   CSR:    hist -> 3-kernel scan (label-batched) -> two-phase bucketed place
//   attn2:  2 param-sets per launch, bf16 MFMA, shared input read
//   agg:    bf16 gather rows, fp32 RMW accumulate, atomic-free
//   pool/dec: fp32
// ---------------------------------------------------------------------------

typedef __attribute__((ext_vector_type(8))) short bf16x8;
typedef __attribute__((ext_vector_type(4))) float f32x4;

__device__ inline short f2bf(float f) {
    union { float f; unsigned u; } v; v.f = f;
    unsigned r = (v.u + 0x7FFFu + ((v.u >> 16) & 1u)) >> 16;   // RNE
    return (short)r;
}
__device__ inline float bf2f(unsigned short b) {
    union { unsigned u; float f; } v; v.u = ((unsigned)b) << 16;
    return v.f;
}

// ---------------------------- encoder --------------------------------------
__global__ __launch_bounds__(128) void enc_kernel(
    const float* __restrict__ x, const float* __restrict__ Wemb,
    float* __restrict__ h, int N)
{
    __shared__ float sxr[8 * 112];
    __shared__ float spe[128];
    __shared__ float sW[1024];
    const int t = threadIdx.x;
    const int n0 = blockIdx.x * 8;

    {
        int s = t >> 5, f = t & 31;
        int i2 = f >> 1;
        float div = __expf(-(float)(2 * i2) * (logf(10000.0f) / 32.0f));
        float ang = (float)s * div;
        spe[t] = (f & 1) ? cosf(ang) : sinf(ang);
    }
    for (int i = t; i < 1024; i += 128) sW[i] = Wemb[i];
    for (int i = t; i < 8 * 112; i += 128) {
        int n = n0 + i / 112;
        sxr[i] = (n < N) ? x[(size_t)n0 * 112 + i] : 0.f;
    }
    __syncthreads();

    const int ts = t >> 5, c = t & 31;
    const int offs_[4] = {0, 16, 48, 80};
    const int lens_[4] = {16, 32, 32, 32};
    const int off = offs_[ts], len = lens_[ts];

    float acc[8];
#pragma unroll
    for (int i = 0; i < 8; ++i) acc[i] = 0.f;
    float pw = 0.f;
    for (int f = 0; f < 32; ++f) {
        float wv = sW[f * 32 + c];
        float pv = spe[ts * 32 + f];
        pw += pv * wv;
        if (f < len) {
#pragma unroll
            for (int i = 0; i < 8; ++i) acc[i] += sxr[i * 112 + off + f] * wv;
        }
    }
#pragma unroll
    for (int i = 0; i < 8; ++i) {
        int n = n0 + i;
        if (n < N) h[(size_t)n * 128 + ts * 32 + c] = acc[i] + pw;
    }
}

// ---------------------------- dual-set MFMA attention -----------------------
// 4 waves/block, wave-private LDS scratch, 2 parameter sets per launch
// (shared input read). Layouts as round 2 (verified).
#define ATT_WAVES 4
#define WLDS 4864

__global__ __launch_bounds__(256, 2) void attn2_kernel(
    const float* __restrict__ in, void* __restrict__ out0, void* __restrict__ out1,
    const float* __restrict__ qkv, const float* __restrict__ fw1,
    const float* __restrict__ fb1, const float* __restrict__ fw2,
    const float* __restrict__ fb2,
    int pi0, int pi1, int N, int relu_in, int bf16_mask)
{
    __shared__ char smem[ATT_WAVES * WLDS];
    const int lane = threadIdx.x & 63;
    const int wave = threadIdx.x >> 6;
    const int q = lane >> 4;
    const int m = lane & 15;

    char* wb = smem + wave * WLDS;
    short* Qb = (short*)(wb);          // [16][40] shorts (also Y)
    short* Kb = (short*)(wb + 1280);   // [16][40] (also Z)
    short* VT = (short*)(wb + 2560);   // [32][24] shorts (V^T)
    short* Pb = (short*)(wb + 4096);   // [16][24] shorts

    const f32x4 zf = {0.f, 0.f, 0.f, 0.f};

    // ---- register weight fragments for both sets ----
    bf16x8 wqkv[2][6], w1f[2][2], w2f[2][2];
    float b1v[2][2], b2v[2][2];
    const int pis[2] = {pi0, pi1};
#pragma unroll
    for (int s = 0; s < 2; ++s) {
        const float* Wq = qkv + (size_t)pis[s] * 32 * 96;
        const float* W1 = fw1 + (size_t)pis[s] * 32 * 32;
        const float* W2 = fw2 + (size_t)pis[s] * 32 * 32;
#pragma unroll
        for (int ci = 0; ci < 6; ++ci) {
            bf16x8 f;
#pragma unroll
            for (int j = 0; j < 8; ++j)
                f[j] = f2bf(Wq[(q * 8 + j) * 96 + ci * 16 + m]);
            wqkv[s][ci] = f;
        }
#pragma unroll
        for (int t = 0; t < 2; ++t) {
            bf16x8 f1, f2;
#pragma unroll
            for (int j = 0; j < 8; ++j) {
                f1[j] = f2bf(W1[(q * 8 + j) * 32 + t * 16 + m]);
                f2[j] = f2bf(W2[(q * 8 + j) * 32 + t * 16 + m]);
            }
            w1f[s][t] = f1; w2f[s][t] = f2;
            b1v[s][t] = fb1[pis[s] * 32 + t * 16 + m];
            b2v[s][t] = fb2[pis[s] * 32 + t * 16 + m];
        }
    }

    const int ntiles = (N + 3) >> 2;
    for (int tile = blockIdx.x * ATT_WAVES + wave; tile < ntiles;
         tile += gridDim.x * ATT_WAVES) {
        const int n0 = tile * 4;
        const int node_m = n0 + (m >> 2);

        // ---- shared X A-frag load (once for both sets) ----
        float xr[8];
        {
            const float* xb = in + (size_t)n0 * 128 + m * 32 + q * 8;
            float4 v0 = make_float4(0.f, 0.f, 0.f, 0.f), v1 = v0;
            if (node_m < N) {
                v0 = *(const float4*)xb;
                v1 = *(const float4*)(xb + 4);
            }
            xr[0] = v0.x; xr[1] = v0.y; xr[2] = v0.z; xr[3] = v0.w;
            xr[4] = v1.x; xr[5] = v1.y; xr[6] = v1.z; xr[7] = v1.w;
            if (relu_in) {
#pragma unroll
                for (int j = 0; j < 8; ++j) xr[j] = fmaxf(xr[j], 0.f);
            }
        }
        bf16x8 ax;
#pragma unroll
        for (int j = 0; j < 8; ++j) ax[j] = f2bf(xr[j]);

#pragma unroll
        for (int s = 0; s < 2; ++s) {
            // ---- qkv ----
            f32x4 accq[6];
#pragma unroll
            for (int ci = 0; ci < 6; ++ci)
                accq[ci] = __builtin_amdgcn_mfma_f32_16x16x32_bf16(ax, wqkv[s][ci], zf, 0, 0, 0);
#pragma unroll
            for (int t = 0; t < 2; ++t) {
#pragma unroll
                for (int r = 0; r < 4; ++r) {
                    Qb[(q * 4 + r) * 40 + m + 16 * t] = f2bf(accq[t][r]);
                    Kb[(q * 4 + r) * 40 + m + 16 * t] = f2bf(accq[2 + t][r]);
                }
                uint2 d;
                d.x = (unsigned short)f2bf(accq[4 + t][0]) |
                      ((unsigned)(unsigned short)f2bf(accq[4 + t][1]) << 16);
                d.y = (unsigned short)f2bf(accq[4 + t][2]) |
                      ((unsigned)(unsigned short)f2bf(accq[4 + t][3]) << 16);
                *(uint2*)((char*)VT + (size_t)(m + 16 * t) * 48 + q * 8) = d;
            }

            // ---- scores ----
            bf16x8 aq = *(const bf16x8*)((char*)Qb + m * 80 + q * 16);
            bf16x8 bk = *(const bf16x8*)((char*)Kb + m * 80 + q * 16);
            f32x4 sc = __builtin_amdgcn_mfma_f32_16x16x32_bf16(aq, bk, zf, 0, 0, 0);

            // ---- softmax over 4 tokens ----
            const bool valid = ((m >> 2) == q);
            float p[4];
#pragma unroll
            for (int r = 0; r < 4; ++r) {
                float v = sc[r] * 0.1767766952966369f;
                float mx = fmaxf(v, __shfl_xor(v, 1));
                mx = fmaxf(mx, __shfl_xor(mx, 2));
                float e = __expf(v - mx);
                float sm = e + __shfl_xor(e, 1);
                sm += __shfl_xor(sm, 2);
                p[r] = e / sm;
            }
#pragma unroll
            for (int r = 0; r < 4; ++r)
                Pb[(q * 4 + r) * 24 + m] = valid ? f2bf(p[r]) : (short)0;

            // ---- PV ----
            bf16x8 ap = {0, 0, 0, 0, 0, 0, 0, 0};
            if (q < 2) ap = *(const bf16x8*)((char*)Pb + m * 48 + q * 16);
            f32x4 y[2];
#pragma unroll
            for (int t = 0; t < 2; ++t) {
                bf16x8 bv = {0, 0, 0, 0, 0, 0, 0, 0};
                if (q < 2) bv = *(const bf16x8*)((char*)VT + (size_t)(m + 16 * t) * 48 + q * 16);
                y[t] = __builtin_amdgcn_mfma_f32_16x16x32_bf16(ap, bv, zf, 0, 0, 0);
            }

            // ---- ffn1 ----
#pragma unroll
            for (int t = 0; t < 2; ++t)
#pragma unroll
                for (int r = 0; r < 4; ++r)
                    Qb[(q * 4 + r) * 40 + m + 16 * t] = f2bf(y[t][r]);
            bf16x8 ay = *(const bf16x8*)((char*)Qb + m * 80 + q * 16);
            f32x4 z1[2];
#pragma unroll
            for (int t = 0; t < 2; ++t)
                z1[t] = __builtin_amdgcn_mfma_f32_16x16x32_bf16(ay, w1f[s][t], zf, 0, 0, 0);

            // ---- ffn2 ----
#pragma unroll
            for (int t = 0; t < 2; ++t)
#pragma unroll
                for (int r = 0; r < 4; ++r)
                    Kb[(q * 4 + r) * 40 + m + 16 * t] = f2bf(fmaxf(z1[t][r] + b1v[s][t], 0.f));
            bf16x8 az = *(const bf16x8*)((char*)Kb + m * 80 + q * 16);
            f32x4 o[2];
#pragma unroll
            for (int t = 0; t < 2; ++t)
                o[t] = __builtin_amdgcn_mfma_f32_16x16x32_bf16(az, w2f[s][t], zf, 0, 0, 0);

            // ---- epilogue: residual + bias + store (fp32 or bf16) ----
            void* op = s ? out1 : out0;
            const bool asbf = (bf16_mask >> s) & 1;
#pragma unroll
            for (int t = 0; t < 2; ++t)
#pragma unroll
                for (int r = 0; r < 4; ++r) {
                    int row = q * 4 + r;
                    int node = n0 + (row >> 2);
                    if (node < N) {
                        size_t idx = (size_t)n0 * 128 + row * 32 + m + 16 * t;
                        float val = y[t][r] + o[t][r] + b2v[s][t];
                        if (asbf) ((unsigned short*)op)[idx] = (unsigned short)f2bf(val);
                        else      ((float*)op)[idx] = val;
                    }
                }
        }
    }
}

// ---------------------------- CSR build ------------------------------------
__global__ void hist3_kernel(const int* __restrict__ e0, const int* __restrict__ e1,
                             const int* __restrict__ e2, int* __restrict__ cnt3,
                             int E, int N)
{
    int i = blockIdx.x * blockDim.x + threadIdx.x;
    if (i >= E) return;
    atomicAdd(&cnt3[0 * N + e0[E + i]], 1);
    atomicAdd(&cnt3[1 * N + e1[E + i]], 1);
    atomicAdd(&cnt3[2 * N + e2[E + i]], 1);
}

// label-batched scans: blockIdx.y = label
__global__ __launch_bounds__(256) void scan1_kernel(
    const int* __restrict__ cnt3, int* __restrict__ incl3, int* __restrict__ bsum3, int N)
{
    __shared__ int sd[256];
    int lab = blockIdx.y;
    int t = threadIdx.x, i = blockIdx.x * 256 + t;
    sd[t] = (i < N) ? cnt3[(size_t)lab * N + i] : 0;
    __syncthreads();
    for (int o = 1; o < 256; o <<= 1) {
        int v = (t >= o) ? sd[t - o] : 0;
        __syncthreads();
        sd[t] += v;
        __syncthreads();
    }
    if (i < N) incl3[(size_t)lab * N + i] = sd[t];
    if (t == 255) bsum3[lab * 1024 + blockIdx.x] = sd[255];
}

__global__ __launch_bounds__(512) void scan2_kernel(int* __restrict__ bsum3, int nb)
{
    __shared__ int sd[512];
    int lab = blockIdx.y;
    int t = threadIdx.x;
    sd[t] = (t < nb) ? bsum3[lab * 1024 + t] : 0;
    __syncthreads();
    for (int o = 1; o < 512; o <<= 1) {
        int v = (t >= o) ? sd[t - o] : 0;
        __syncthreads();
        sd[t] += v;
        __syncthreads();
    }
    if (t < nb) bsum3[lab * 1024 + t] = sd[t];
}

__global__ void scan3_kernel(const int* __restrict__ incl3, const int* __restrict__ bsum3,
                             int* __restrict__ offs3, int N)
{
    int lab = blockIdx.y;
    int i = blockIdx.x * 256 + threadIdx.x;
    if (i >= N) return;
    int add = (blockIdx.x > 0) ? bsum3[lab * 1024 + blockIdx.x - 1] : 0;
    offs3[(size_t)lab * (N + 1) + i + 1] = incl3[(size_t)lab * N + i] + add;
    if (i == 0) offs3[(size_t)lab * (N + 1)] = 0;
}

// ---- two-phase placement ----
#define PA_CHUNK 4096
#define PA_SHIFT 9
#define PA_MAXB  256

// Phase A: bin edges by dst>>9 into pair array (regions = CSR offset space),
// coalesced per-bin run flushes. blockIdx.y = label.
__global__ __launch_bounds__(256) void placeA_kernel(
    const int* __restrict__ e0, const int* __restrict__ e1, const int* __restrict__ e2,
    const int* __restrict__ offs3, int* __restrict__ gfill,
    int2* __restrict__ pairs, int E, int N)
{
    __shared__ int2 sStage[PA_CHUNK];
    __shared__ int sCnt[PA_MAXB], sScan[PA_MAXB], sCur[PA_MAXB], sGB[PA_MAXB];

    const int lab = blockIdx.y;
    const int t = threadIdx.x;
    const int base = blockIdx.x * PA_CHUNK;
    const int* e = (lab == 0) ? e0 : (lab == 1) ? e1 : e2;
    const int* offs = offs3 + (size_t)lab * (N + 1);
    const int nbins = (N + (1 << PA_SHIFT) - 1) >> PA_SHIFT;

    for (int i = t; i < PA_MAXB; i += 256) { sCnt[i] = 0; sCur[i] = 0; }
    __syncthreads();

    int msrc[16], mdst[16];
    const int cnt_total = min(PA_CHUNK, E - base);
#pragma unroll
    for (int k = 0; k < 16; ++k) {
        int i = base + k * 256 + t;
        if (i < E) {
            msrc[k] = e[i];
            int d = e[E + i];
            mdst[k] = d;
            atomicAdd(&sCnt[d >> PA_SHIFT], 1);
        } else mdst[k] = -1;
    }
    __syncthreads();

    // exclusive scan of sCnt (256 wide)
    sScan[t] = sCnt[t];
    __syncthreads();
    for (int o = 1; o < 256; o <<= 1) {
        int v = (t >= o) ? sScan[t - o] : 0;
        __syncthreads();
        sScan[t] += v;
        __syncthreads();
    }
    // global run reservation per bin
    if (t < nbins && sCnt[t] > 0) {
        int node = t << PA_SHIFT; if (node > N) node = N;
        sGB[t] = offs[node] + atomicAdd(&gfill[lab * PA_MAXB + t], sCnt[t]);
    }
    __syncthreads();

    // place into LDS stage sorted by bin
#pragma unroll
    for (int k = 0; k < 16; ++k) {
        if (mdst[k] >= 0) {
            int bin = mdst[k] >> PA_SHIFT;
            int r = atomicAdd(&sCur[bin], 1);
            sStage[(sScan[bin] - sCnt[bin]) + r] = make_int2(msrc[k], mdst[k]);
        }
    }
    __syncthreads();

    // coalesced flush
    int2* gp = pairs + (size_t)lab * E;
    for (int i = t; i < cnt_total; i += 256) {
        int2 pr = sStage[i];
        int bin = pr.y >> PA_SHIFT;
        gp[sGB[bin] + (i - (sScan[bin] - sCnt[bin]))] = pr;
    }
}

// Phase B: one block per (label,bin); scatter within single-block-local region.
__global__ __launch_bounds__(256) void placeB_kernel(
    const int2* __restrict__ pairs, const int* __restrict__ offs3,
    int* __restrict__ csr3, int E, int N, int nbins)
{
    __shared__ int sOffs[513];
    __shared__ int sFill[512];
    const int lab = blockIdx.x / nbins;
    const int bin = blockIdx.x % nbins;
    const int t = threadIdx.x;
    const int n0 = bin << PA_SHIFT;
    const int n1 = min(n0 + 512, N);
    const int len = n1 - n0;
    const int* offs = offs3 + (size_t)lab * (N + 1);

    for (int i = t; i <= len; i += 256) sOffs[i] = offs[n0 + i];
    for (int i = t; i < len; i += 256) sFill[i] = 0;
    __syncthreads();

    const int rb = sOffs[0], re = sOffs[len];
    const int2* gp = pairs + (size_t)lab * E;
    int* csr = csr3 + (size_t)lab * E;
    for (int i = rb + t; i < re; i += 256) {
        int2 pr = gp[i];
        int ln = pr.y - n0;
        int p = atomicAdd(&sFill[ln], 1);
        csr[sOffs[ln] + p] = pr.x;
    }
}

// ---------------------------- aggregation (bf16 gather, atomic-free) --------
__global__ __launch_bounds__(256) void agg_kernel(
    const unsigned short* __restrict__ xt, const int* __restrict__ csr,
    const int* __restrict__ offs, float* __restrict__ xout, int N)
{
    int w = threadIdx.x >> 6, lane = threadIdx.x & 63;
    int dst = blockIdx.x * 4 + w;
    if (dst >= N) return;
    int beg = offs[dst], end = offs[dst + 1];
    const ushort2* x2 = (const ushort2*)xt;
    float2 acc = make_float2(0.f, 0.f);
    for (int k = beg; k < end; ++k) {
        int src = csr[k];
        ushort2 v = x2[(size_t)src * 64 + lane];
        acc.x += bf2f(v.x); acc.y += bf2f(v.y);
    }
    float2* o2 = (float2*)xout;
    float2 cur = o2[(size_t)dst * 64 + lane];
    cur.x += acc.x; cur.y += acc.y;
    o2[(size_t)dst * 64 + lane] = cur;
}

// ---------------------------- pool / counts / decoder ----------------------
__global__ __launch_bounds__(256) void pool_kernel(
    const float* __restrict__ in, const int* __restrict__ batch,
    float* __restrict__ gsum, int N)
{
    int t = threadIdx.x;
    int j = t & 127, half = t >> 7;
    int n0 = blockIdx.x * 64 + half * 32;
    float acc = 0.f; int cur = -1;
    for (int i = 0; i < 32; ++i) {
        int n = n0 + i;
        if (n >= N) break;
        int g = batch[n];
        if (g != cur) {
            if (cur >= 0) atomicAdd(&gsum[cur * 128 + j], acc);
            cur = g; acc = 0.f;
        }
        acc += fmaxf(in[(size_t)n * 128 + j], 0.f);
    }
    if (cur >= 0) atomicAdd(&gsum[cur * 128 + j], acc);
}

__global__ __launch_bounds__(256) void cnt_kernel(
    const int* __restrict__ batch, float* __restrict__ gcnt, int N)
{
    __shared__ float lh[64];
    int t = threadIdx.x;
    if (t < 64) lh[t] = 0.f;
    __syncthreads();
    int i = blockIdx.x * 256 + t;
    if (i < N) atomicAdd(&lh[batch[i]], 1.0f);
    __syncthreads();
    if (t < 64 && lh[t] != 0.f) atomicAdd(&gcnt[t], lh[t]);
}

__global__ __launch_bounds__(128) void dec_kernel(
    const float* __restrict__ gsum, const float* __restrict__ gcnt,
    const float* __restrict__ W1, const float* __restrict__ B1,
    const float* __restrict__ W2, const float* __restrict__ B2,
    float* __restrict__ out)
{
    __shared__ float sg[128];
    __shared__ float sh[128];
    int t = threadIdx.x, b = blockIdx.x;
    float cinv = 1.0f / fmaxf(gcnt[b], 1.0f);
    sg[t] = gsum[b * 128 + t] * cinv;
    __syncthreads();
    float acc = B1[t];
    for (int f = 0; f < 128; ++f) acc += sg[f] * W1[f * 128 + t];
    sh[t] = fmaxf(acc, 0.f) * W2[t];
    __syncthreads();
    for (int o = 64; o > 0; o >>= 1) {
        if (t < o) sh[t] += sh[t + o];
        __syncthreads();
    }
    if (t == 0) out[b] = sh[0] + B2[0];
}

// ---------------------------- launch ---------------------------------------
extern "C" void kernel_launch(void* const* d_in, const int* in_sizes, int n_in,
                              void* d_out, int out_size, void* d_ws, size_t ws_size,
                              hipStream_t stream)
{
    const float* x    = (const float*)d_in[0];
    const int*   e0   = (const int*)d_in[1];
    const int*   e1   = (const int*)d_in[2];
    const int*   e2   = (const int*)d_in[3];
    const int*   bat  = (const int*)d_in[4];
    const float* Wemb = (const float*)d_in[5];
    const float* qkv  = (const float*)d_in[6];
    const float* fw1  = (const float*)d_in[7];
    const float* fb1  = (const float*)d_in[8];
    const float* fw2  = (const float*)d_in[9];
    const float* fb2  = (const float*)d_in[10];
    const float* mw1  = (const float*)d_in[11];
    const float* mb1  = (const float*)d_in[12];
    const float* mw2  = (const float*)d_in[13];
    const float* mb2  = (const float*)d_in[14];
    const int N = in_sizes[0] / 112;
    const int E = in_sizes[1] / 2;
    float* outp = (float*)d_out;
    (void)n_in; (void)out_size; (void)ws_size;

    char* w = (char*)d_ws;
    auto alloc = [&](size_t bytes) {
        char* p = w; w += (bytes + 255) & ~(size_t)255; return p;
    };
    float*          buf0 = (float*)alloc((size_t)N * 128 * 4);
    float*          buf1 = (float*)alloc((size_t)N * 128 * 4);
    unsigned short* xtA  = (unsigned short*)alloc((size_t)N * 128 * 2);
    unsigned short* xtB  = (unsigned short*)alloc((size_t)N * 128 * 2);
    int*   csr3  = (int*)alloc((size_t)3 * E * 4);
    int*   offs3 = (int*)alloc((size_t)3 * (N + 1) * 4);
    int*   bsum3 = (int*)alloc(3 * 1024 * 4);
    int*   gfill = (int*)alloc(3 * PA_MAXB * 4);
    float* gsum  = (float*)alloc(64 * 128 * 4);
    float* gcnt  = (float*)alloc(64 * 4);
    // aliased into the xtA/xtB region (dead before first attn2 writes xt):
    //   pairs: 3*E*8 = 19.2 MB ; cnt3: 1.2 MB ; incl3: 1.2 MB   (<= 51.2 MB)
    char* xtbase = (char*)xtA;
    int2* pairs = (int2*)xtbase;
    int*  cnt3  = (int*)(xtbase + ((size_t)3 * E * 8 + 255 & ~(size_t)255));
    int*  incl3 = (int*)((char*)cnt3 + (((size_t)3 * N * 4 + 255) & ~(size_t)255));

    const int nb = (N + 255) / 256;                         // scan blocks (<=1024)
    const int nbins = (N + (1 << PA_SHIFT) - 1) >> PA_SHIFT;

    hipMemsetAsync(cnt3, 0, (size_t)3 * N * 4, stream);
    hipMemsetAsync(gfill, 0, 3 * PA_MAXB * 4, stream);
    hipMemsetAsync(gsum, 0, 64 * 128 * 4, stream);
    hipMemsetAsync(gcnt, 0, 64 * 4, stream);

    enc_kernel<<<(N + 7) / 8, 128, 0, stream>>>(x, Wemb, buf0, N);

    hist3_kernel<<<(E + 255) / 256, 256, 0, stream>>>(e0, e1, e2, cnt3, E, N);
    scan1_kernel<<<dim3(nb, 3), 256, 0, stream>>>(cnt3, incl3, bsum3, N);
    scan2_kernel<<<dim3(1, 3), 512, 0, stream>>>(bsum3, nb);
    scan3_kernel<<<dim3(nb, 3), 256, 0, stream>>>(incl3, bsum3, offs3, N);
    placeA_kernel<<<dim3((E + PA_CHUNK - 1) / PA_CHUNK, 3), 256, 0, stream>>>(
        e0, e1, e2, offs3, gfill, pairs, E, N);
    placeB_kernel<<<3 * nbins, 256, 0, stream>>>(pairs, offs3, csr3, E, N, nbins);

    const int ATT_GRID = 1024;
    auto agg = [&](unsigned short* xt, int lab, float* lout) {
        agg_kernel<<<(N + 3) / 4, 256, 0, stream>>>(
            xt, csr3 + (size_t)lab * E, offs3 + (size_t)lab * (N + 1), lout, N);
    };
    auto run_layer = [&](const float* lin, float* lout, int l, int relu_in) {
        // sets: root (fp32 -> lout) + e0 (bf16 -> xtA)
        attn2_kernel<<<ATT_GRID, 256, 0, stream>>>(
            lin, (void*)lout, (void*)xtA, qkv, fw1, fb1, fw2, fb2,
            l * 4 + 0, l * 4 + 1, N, relu_in, /*bf16_mask=*/0b10);
        agg(xtA, 0, lout);
        // sets: e1 (bf16 -> xtB) + e2 (bf16 -> xtA, safe: agg(xtA) retired)
        attn2_kernel<<<ATT_GRID, 256, 0, stream>>>(
            lin, (void*)xtB, (void*)xtA, qkv, fw1, fb1, fw2, fb2,
            l * 4 + 2, l * 4 + 3, N, relu_in, /*bf16_mask=*/0b11);
        agg(xtB, 1, lout);
        agg(xtA, 2, lout);
    };
    run_layer(buf0, buf1, 0, /*relu_in=*/0);
    run_layer(buf1, buf0, 1, /*relu_in=*/1);

    pool_kernel<<<(N + 63) / 64, 256, 0, stream>>>(buf0, bat, gsum, N);
    cnt_kernel<<<(N + 255) / 256, 256, 0, stream>>>(bat, gcnt, N);
    dec_kernel<<<64, 128, 0, stream>>>(gsum, gcnt, mw1, mb1, mw2, mb2, outp);
}

// Round 4
// 906.669 us; speedup vs baseline: 3.5440x; 1.2137x over previous
//
#include <hip/hip_runtime.h>
#include <hip/hip_bf16.h>
#include <cstdint>
#include <cstddef>

// ---------------------------------------------------------------------------
// RGNN_53755810677120 — round 4.
//   enc:    x[N,112] -> pad/PE/W_emb -> h0[N,128] (bf16)
//   CSR:    bucket hist (LDS-binned) -> 768-scan -> placeA (bucketed pairs)
//           -> placeB (per-bucket local count/scan/scatter; writes offs3+csr)
//   attn2:  2 param-sets/launch, bf16 MFMA, bf16 in/out
//   agg3:   h_out = relu(root + 3x CSR gather sums), fp32 regs, single write
//   pool/dec: fp32 accumulate
// ---------------------------------------------------------------------------

typedef __attribute__((ext_vector_type(8))) short bf16x8;
typedef __attribute__((ext_vector_type(4))) float f32x4;

__device__ inline short f2bf(float f) {
    union { float f; unsigned u; } v; v.f = f;
    unsigned r = (v.u + 0x7FFFu + ((v.u >> 16) & 1u)) >> 16;   // RNE
    return (short)r;
}
__device__ inline float bf2f(unsigned short b) {
    union { unsigned u; float f; } v; v.u = ((unsigned)b) << 16;
    return v.f;
}

// ---------------------------- encoder --------------------------------------
__global__ __launch_bounds__(128) void enc_kernel(
    const float* __restrict__ x, const float* __restrict__ Wemb,
    unsigned short* __restrict__ h, int N)
{
    __shared__ float sxr[8 * 112];
    __shared__ float spe[128];
    __shared__ float sW[1024];
    const int t = threadIdx.x;
    const int n0 = blockIdx.x * 8;

    {
        int s = t >> 5, f = t & 31;
        int i2 = f >> 1;
        float div = __expf(-(float)(2 * i2) * (logf(10000.0f) / 32.0f));
        float ang = (float)s * div;
        spe[t] = (f & 1) ? cosf(ang) : sinf(ang);
    }
    for (int i = t; i < 1024; i += 128) sW[i] = Wemb[i];
    for (int i = t; i < 8 * 112; i += 128) {
        int n = n0 + i / 112;
        sxr[i] = (n < N) ? x[(size_t)n0 * 112 + i] : 0.f;
    }
    __syncthreads();

    const int ts = t >> 5, c = t & 31;
    const int offs_[4] = {0, 16, 48, 80};
    const int lens_[4] = {16, 32, 32, 32};
    const int off = offs_[ts], len = lens_[ts];

    float acc[8];
#pragma unroll
    for (int i = 0; i < 8; ++i) acc[i] = 0.f;
    float pw = 0.f;
    for (int f = 0; f < 32; ++f) {
        float wv = sW[f * 32 + c];
        float pv = spe[ts * 32 + f];
        pw += pv * wv;
        if (f < len) {
#pragma unroll
            for (int i = 0; i < 8; ++i) acc[i] += sxr[i * 112 + off + f] * wv;
        }
    }
#pragma unroll
    for (int i = 0; i < 8; ++i) {
        int n = n0 + i;
        if (n < N)
            h[(size_t)n * 128 + ts * 32 + c] = (unsigned short)f2bf(acc[i] + pw);
    }
}

// ---------------------------- dual-set MFMA attention -----------------------
// 4 waves/block, wave-private LDS scratch, 2 parameter sets per launch.
// bf16 input (no relu needed: layer outputs are stored pre-relu'd).
#define ATT_WAVES 4
#define WLDS 4864

__global__ __launch_bounds__(256, 2) void attn2_kernel(
    const unsigned short* __restrict__ in,
    unsigned short* __restrict__ out0, unsigned short* __restrict__ out1,
    const float* __restrict__ qkv, const float* __restrict__ fw1,
    const float* __restrict__ fb1, const float* __restrict__ fw2,
    const float* __restrict__ fb2,
    int pi0, int pi1, int N)
{
    __shared__ char smem[ATT_WAVES * WLDS];
    const int lane = threadIdx.x & 63;
    const int wave = threadIdx.x >> 6;
    const int q = lane >> 4;
    const int m = lane & 15;

    char* wb = smem + wave * WLDS;
    short* Qb = (short*)(wb);          // [16][40] shorts (also Y)
    short* Kb = (short*)(wb + 1280);   // [16][40] (also Z)
    short* VT = (short*)(wb + 2560);   // [32][24] shorts (V^T)
    short* Pb = (short*)(wb + 4096);   // [16][24] shorts

    const f32x4 zf = {0.f, 0.f, 0.f, 0.f};

    // ---- register weight fragments for both sets ----
    bf16x8 wqkv[2][6], w1f[2][2], w2f[2][2];
    float b1v[2][2], b2v[2][2];
    const int pis[2] = {pi0, pi1};
#pragma unroll
    for (int s = 0; s < 2; ++s) {
        const float* Wq = qkv + (size_t)pis[s] * 32 * 96;
        const float* W1 = fw1 + (size_t)pis[s] * 32 * 32;
        const float* W2 = fw2 + (size_t)pis[s] * 32 * 32;
#pragma unroll
        for (int ci = 0; ci < 6; ++ci) {
            bf16x8 f;
#pragma unroll
            for (int j = 0; j < 8; ++j)
                f[j] = f2bf(Wq[(q * 8 + j) * 96 + ci * 16 + m]);
            wqkv[s][ci] = f;
        }
#pragma unroll
        for (int t = 0; t < 2; ++t) {
            bf16x8 f1, f2;
#pragma unroll
            for (int j = 0; j < 8; ++j) {
                f1[j] = f2bf(W1[(q * 8 + j) * 32 + t * 16 + m]);
                f2[j] = f2bf(W2[(q * 8 + j) * 32 + t * 16 + m]);
            }
            w1f[s][t] = f1; w2f[s][t] = f2;
            b1v[s][t] = fb1[pis[s] * 32 + t * 16 + m];
            b2v[s][t] = fb2[pis[s] * 32 + t * 16 + m];
        }
    }

    const int ntiles = (N + 3) >> 2;
    for (int tile = blockIdx.x * ATT_WAVES + wave; tile < ntiles;
         tile += gridDim.x * ATT_WAVES) {
        const int n0 = tile * 4;
        const int node_m = n0 + (m >> 2);

        // ---- shared X A-frag: 8 contiguous bf16 (16B) ----
        bf16x8 ax = {0, 0, 0, 0, 0, 0, 0, 0};
        if (node_m < N)
            ax = *(const bf16x8*)(in + (size_t)n0 * 128 + m * 32 + q * 8);

#pragma unroll
        for (int s = 0; s < 2; ++s) {
            // ---- qkv ----
            f32x4 accq[6];
#pragma unroll
            for (int ci = 0; ci < 6; ++ci)
                accq[ci] = __builtin_amdgcn_mfma_f32_16x16x32_bf16(ax, wqkv[s][ci], zf, 0, 0, 0);
#pragma unroll
            for (int t = 0; t < 2; ++t) {
#pragma unroll
                for (int r = 0; r < 4; ++r) {
                    Qb[(q * 4 + r) * 40 + m + 16 * t] = f2bf(accq[t][r]);
                    Kb[(q * 4 + r) * 40 + m + 16 * t] = f2bf(accq[2 + t][r]);
                }
                uint2 d;
                d.x = (unsigned short)f2bf(accq[4 + t][0]) |
                      ((unsigned)(unsigned short)f2bf(accq[4 + t][1]) << 16);
                d.y = (unsigned short)f2bf(accq[4 + t][2]) |
                      ((unsigned)(unsigned short)f2bf(accq[4 + t][3]) << 16);
                *(uint2*)((char*)VT + (size_t)(m + 16 * t) * 48 + q * 8) = d;
            }

            // ---- scores ----
            bf16x8 aq = *(const bf16x8*)((char*)Qb + m * 80 + q * 16);
            bf16x8 bk = *(const bf16x8*)((char*)Kb + m * 80 + q * 16);
            f32x4 sc = __builtin_amdgcn_mfma_f32_16x16x32_bf16(aq, bk, zf, 0, 0, 0);

            // ---- softmax over 4 tokens ----
            const bool valid = ((m >> 2) == q);
            float p[4];
#pragma unroll
            for (int r = 0; r < 4; ++r) {
                float v = sc[r] * 0.1767766952966369f;
                float mx = fmaxf(v, __shfl_xor(v, 1));
                mx = fmaxf(mx, __shfl_xor(mx, 2));
                float e = __expf(v - mx);
                float sm = e + __shfl_xor(e, 1);
                sm += __shfl_xor(sm, 2);
                p[r] = e / sm;
            }
#pragma unroll
            for (int r = 0; r < 4; ++r)
                Pb[(q * 4 + r) * 24 + m] = valid ? f2bf(p[r]) : (short)0;

            // ---- PV ----
            bf16x8 ap = {0, 0, 0, 0, 0, 0, 0, 0};
            if (q < 2) ap = *(const bf16x8*)((char*)Pb + m * 48 + q * 16);
            f32x4 y[2];
#pragma unroll
            for (int t = 0; t < 2; ++t) {
                bf16x8 bv = {0, 0, 0, 0, 0, 0, 0, 0};
                if (q < 2) bv = *(const bf16x8*)((char*)VT + (size_t)(m + 16 * t) * 48 + q * 16);
                y[t] = __builtin_amdgcn_mfma_f32_16x16x32_bf16(ap, bv, zf, 0, 0, 0);
            }

            // ---- ffn1 ----
#pragma unroll
            for (int t = 0; t < 2; ++t)
#pragma unroll
                for (int r = 0; r < 4; ++r)
                    Qb[(q * 4 + r) * 40 + m + 16 * t] = f2bf(y[t][r]);
            bf16x8 ay = *(const bf16x8*)((char*)Qb + m * 80 + q * 16);
            f32x4 z1[2];
#pragma unroll
            for (int t = 0; t < 2; ++t)
                z1[t] = __builtin_amdgcn_mfma_f32_16x16x32_bf16(ay, w1f[s][t], zf, 0, 0, 0);

            // ---- ffn2 ----
#pragma unroll
            for (int t = 0; t < 2; ++t)
#pragma unroll
                for (int r = 0; r < 4; ++r)
                    Kb[(q * 4 + r) * 40 + m + 16 * t] = f2bf(fmaxf(z1[t][r] + b1v[s][t], 0.f));
            bf16x8 az = *(const bf16x8*)((char*)Kb + m * 80 + q * 16);
            f32x4 o[2];
#pragma unroll
            for (int t = 0; t < 2; ++t)
                o[t] = __builtin_amdgcn_mfma_f32_16x16x32_bf16(az, w2f[s][t], zf, 0, 0, 0);

            // ---- epilogue: residual + bias -> bf16 store ----
            unsigned short* op = s ? out1 : out0;
#pragma unroll
            for (int t = 0; t < 2; ++t)
#pragma unroll
                for (int r = 0; r < 4; ++r) {
                    int row = q * 4 + r;
                    int node = n0 + (row >> 2);
                    if (node < N)
                        op[(size_t)n0 * 128 + row * 32 + m + 16 * t] =
                            (unsigned short)f2bf(y[t][r] + o[t][r] + b2v[s][t]);
                }
        }
    }
}

// ---------------------------- CSR build (bucketed) --------------------------
#define PA_CHUNK 4096
#define PA_SHIFT 9
#define PA_MAXB  256
#define HB_K     16

// bucket histogram, LDS-binned; blockIdx.y = label
__global__ __launch_bounds__(256) void histB_kernel(
    const int* __restrict__ e0, const int* __restrict__ e1,
    const int* __restrict__ e2, int* __restrict__ bcnt, int E)
{
    __shared__ int lh[PA_MAXB];
    const int lab = blockIdx.y;
    const int* e = (lab == 0) ? e0 : (lab == 1) ? e1 : e2;
    const int t = threadIdx.x;
    for (int i = t; i < PA_MAXB; i += 256) lh[i] = 0;
    __syncthreads();
    const int base = blockIdx.x * 256 * HB_K;
#pragma unroll
    for (int k = 0; k < HB_K; ++k) {
        int i = base + k * 256 + t;
        if (i < E) atomicAdd(&lh[e[E + i] >> PA_SHIFT], 1);
    }
    __syncthreads();
    for (int i = t; i < PA_MAXB; i += 256)
        if (lh[i]) atomicAdd(&bcnt[lab * PA_MAXB + i], lh[i]);
}

// exclusive scan of 256 buckets per label (1 block)
__global__ __launch_bounds__(256) void bscan_kernel(
    const int* __restrict__ bcnt, int* __restrict__ bbase)
{
    __shared__ int sd[PA_MAXB];
    const int t = threadIdx.x;
    for (int lab = 0; lab < 3; ++lab) {
        sd[t] = bcnt[lab * PA_MAXB + t];
        __syncthreads();
        int own = sd[t];
        for (int o = 1; o < 256; o <<= 1) {
            int v = (t >= o) ? sd[t - o] : 0;
            __syncthreads();
            sd[t] += v;
            __syncthreads();
        }
        bbase[lab * PA_MAXB + t] = sd[t] - own;
        __syncthreads();
    }
}

// Phase A: bin edges by dst>>9 into per-bucket runs of (src,dst) pairs.
__global__ __launch_bounds__(256) void placeA_kernel(
    const int* __restrict__ e0, const int* __restrict__ e1, const int* __restrict__ e2,
    const int* __restrict__ bbase, int* __restrict__ gres,
    int2* __restrict__ pairs, int E, int N)
{
    __shared__ int2 sStage[PA_CHUNK];
    __shared__ int sCnt[PA_MAXB], sScan[PA_MAXB], sCur[PA_MAXB], sGB[PA_MAXB];

    const int lab = blockIdx.y;
    const int t = threadIdx.x;
    const int base = blockIdx.x * PA_CHUNK;
    const int* e = (lab == 0) ? e0 : (lab == 1) ? e1 : e2;
    const int nbins = (N + (1 << PA_SHIFT) - 1) >> PA_SHIFT;

    for (int i = t; i < PA_MAXB; i += 256) { sCnt[i] = 0; sCur[i] = 0; }
    __syncthreads();

    int msrc[16], mdst[16];
    const int cnt_total = min(PA_CHUNK, E - base);
#pragma unroll
    for (int k = 0; k < 16; ++k) {
        int i = base + k * 256 + t;
        if (i < E) {
            msrc[k] = e[i];
            int d = e[E + i];
            mdst[k] = d;
            atomicAdd(&sCnt[d >> PA_SHIFT], 1);
        } else mdst[k] = -1;
    }
    __syncthreads();

    sScan[t] = sCnt[t];
    __syncthreads();
    for (int o = 1; o < 256; o <<= 1) {
        int v = (t >= o) ? sScan[t - o] : 0;
        __syncthreads();
        sScan[t] += v;
        __syncthreads();
    }
    if (t < nbins && sCnt[t] > 0)
        sGB[t] = bbase[lab * PA_MAXB + t] + atomicAdd(&gres[lab * PA_MAXB + t], sCnt[t]);
    __syncthreads();

#pragma unroll
    for (int k = 0; k < 16; ++k) {
        if (mdst[k] >= 0) {
            int bin = mdst[k] >> PA_SHIFT;
            int r = atomicAdd(&sCur[bin], 1);
            sStage[(sScan[bin] - sCnt[bin]) + r] = make_int2(msrc[k], mdst[k]);
        }
    }
    __syncthreads();

    int2* gp = pairs + (size_t)lab * E;
    for (int i = t; i < cnt_total; i += 256) {
        int2 pr = sStage[i];
        int bin = pr.y >> PA_SHIFT;
        gp[sGB[bin] + (i - (sScan[bin] - sCnt[bin]))] = pr;
    }
}

// Phase B: per (label,bucket): local per-node count + scan -> offs3 + csr.
__global__ __launch_bounds__(512) void placeB_kernel(
    const int2* __restrict__ pairs, const int* __restrict__ bbase,
    const int* __restrict__ bcnt, int* __restrict__ offs3,
    int* __restrict__ csr3, int E, int N, int nbins)
{
    __shared__ int sCnt[512], sScan[512], sFill[512];
    const int lab = blockIdx.x / nbins;
    const int bin = blockIdx.x % nbins;
    const int t = threadIdx.x;
    const int n0 = bin << PA_SHIFT;
    const int n1 = min(n0 + 512, N);
    const int len = n1 - n0;
    const int rb  = bbase[lab * PA_MAXB + bin];
    const int cnt = bcnt[lab * PA_MAXB + bin];
    const int2* gp = pairs + (size_t)lab * E + rb;

    sCnt[t] = 0; sFill[t] = 0;
    __syncthreads();
    for (int i = t; i < cnt; i += 512)
        atomicAdd(&sCnt[gp[i].y - n0], 1);
    __syncthreads();
    sScan[t] = sCnt[t];
    __syncthreads();
    for (int o = 1; o < 512; o <<= 1) {
        int v = (t >= o) ? sScan[t - o] : 0;
        __syncthreads();
        sScan[t] += v;
        __syncthreads();
    }
    const int excl = sScan[t] - sCnt[t];
    if (t < len) offs3[(size_t)lab * (N + 1) + n0 + t] = rb + excl;
    if (bin == nbins - 1 && t == 0) offs3[(size_t)lab * (N + 1) + N] = rb + cnt;
    sScan[t] = excl;
    __syncthreads();

    int* csr = csr3 + (size_t)lab * E + rb;
    for (int i = t; i < cnt; i += 512) {
        int2 pr = gp[i];
        int ln = pr.y - n0;
        int p = atomicAdd(&sFill[ln], 1);
        csr[sScan[ln] + p] = pr.x;
    }
}

// ---------------------------- fused aggregation -----------------------------
// h_out[dst] = relu( root[dst] + sum_{lab} sum_{src in csr} xt_lab[src] )
__global__ __launch_bounds__(256) void agg3_kernel(
    const unsigned short* __restrict__ xtR,
    const unsigned short* __restrict__ xt0,
    const unsigned short* __restrict__ xt1,
    const unsigned short* __restrict__ xt2,
    const int* __restrict__ csr3, const int* __restrict__ offs3,
    unsigned short* __restrict__ hout, int N, int E)
{
    int w = threadIdx.x >> 6, lane = threadIdx.x & 63;
    int dst = blockIdx.x * 4 + w;
    if (dst >= N) return;

    const ushort2* r2 = (const ushort2*)xtR;
    ushort2 rv = r2[(size_t)dst * 64 + lane];
    float2 acc = make_float2(bf2f(rv.x), bf2f(rv.y));

    const unsigned short* xts[3] = {xt0, xt1, xt2};
    for (int lab = 0; lab < 3; ++lab) {
        const int* offs = offs3 + (size_t)lab * (N + 1);
        const int* csr  = csr3 + (size_t)lab * E;
        const ushort2* x2 = (const ushort2*)xts[lab];
        int beg = offs[dst], end = offs[dst + 1];
        for (int k = beg; k < end; ++k) {
            int src = csr[k];                       // wave-uniform broadcast
            ushort2 v = x2[(size_t)src * 64 + lane]; // 256B coalesced row
            acc.x += bf2f(v.x); acc.y += bf2f(v.y);
        }
    }
    ushort2 o;
    o.x = (unsigned short)f2bf(fmaxf(acc.x, 0.f));
    o.y = (unsigned short)f2bf(fmaxf(acc.y, 0.f));
    ((ushort2*)hout)[(size_t)dst * 64 + lane] = o;
}

// ---------------------------- pool / counts / decoder ----------------------
__global__ __launch_bounds__(256) void pool_kernel(
    const unsigned short* __restrict__ in, const int* __restrict__ batch,
    float* __restrict__ gsum, int N)
{
    int t = threadIdx.x;
    int j = t & 127, half = t >> 7;
    int n0 = blockIdx.x * 64 + half * 32;
    float acc = 0.f; int cur = -1;
    for (int i = 0; i < 32; ++i) {
        int n = n0 + i;
        if (n >= N) break;
        int g = batch[n];
        if (g != cur) {
            if (cur >= 0) atomicAdd(&gsum[cur * 128 + j], acc);
            cur = g; acc = 0.f;
        }
        acc += bf2f(in[(size_t)n * 128 + j]);   // h already relu'd
    }
    if (cur >= 0) atomicAdd(&gsum[cur * 128 + j], acc);
}

__global__ __launch_bounds__(256) void cnt_kernel(
    const int* __restrict__ batch, float* __restrict__ gcnt, int N)
{
    __shared__ float lh[64];
    int t = threadIdx.x;
    if (t < 64) lh[t] = 0.f;
    __syncthreads();
    int i = blockIdx.x * 256 + t;
    if (i < N) atomicAdd(&lh[batch[i]], 1.0f);
    __syncthreads();
    if (t < 64 && lh[t] != 0.f) atomicAdd(&gcnt[t], lh[t]);
}

__global__ __launch_bounds__(128) void dec_kernel(
    const float* __restrict__ gsum, const float* __restrict__ gcnt,
    const float* __restrict__ W1, const float* __restrict__ B1,
    const float* __restrict__ W2, const float* __restrict__ B2,
    float* __restrict__ out)
{
    __shared__ float sg[128];
    __shared__ float sh[128];
    int t = threadIdx.x, b = blockIdx.x;
    float cinv = 1.0f / fmaxf(gcnt[b], 1.0f);
    sg[t] = gsum[b * 128 + t] * cinv;
    __syncthreads();
    float acc = B1[t];
    for (int f = 0; f < 128; ++f) acc += sg[f] * W1[f * 128 + t];
    sh[t] = fmaxf(acc, 0.f) * W2[t];
    __syncthreads();
    for (int o = 64; o > 0; o >>= 1) {
        if (t < o) sh[t] += sh[t + o];
        __syncthreads();
    }
    if (t == 0) out[b] = sh[0] + B2[0];
}

// ---------------------------- launch ---------------------------------------
extern "C" void kernel_launch(void* const* d_in, const int* in_sizes, int n_in,
                              void* d_out, int out_size, void* d_ws, size_t ws_size,
                              hipStream_t stream)
{
    const float* x    = (const float*)d_in[0];
    const int*   e0   = (const int*)d_in[1];
    const int*   e1   = (const int*)d_in[2];
    const int*   e2   = (const int*)d_in[3];
    const int*   bat  = (const int*)d_in[4];
    const float* Wemb = (const float*)d_in[5];
    const float* qkv  = (const float*)d_in[6];
    const float* fw1  = (const float*)d_in[7];
    const float* fb1  = (const float*)d_in[8];
    const float* fw2  = (const float*)d_in[9];
    const float* fb2  = (const float*)d_in[10];
    const float* mw1  = (const float*)d_in[11];
    const float* mb1  = (const float*)d_in[12];
    const float* mw2  = (const float*)d_in[13];
    const float* mb2  = (const float*)d_in[14];
    const int N = in_sizes[0] / 112;
    const int E = in_sizes[1] / 2;
    float* outp = (float*)d_out;
    (void)n_in; (void)out_size; (void)ws_size;

    char* w = (char*)d_ws;
    auto alloc = [&](size_t bytes) {
        char* p = w; w += (bytes + 255) & ~(size_t)255; return p;
    };
    unsigned short* h0  = (unsigned short*)alloc((size_t)N * 128 * 2);
    unsigned short* h1  = (unsigned short*)alloc((size_t)N * 128 * 2);
    unsigned short* xtR = (unsigned short*)alloc((size_t)N * 128 * 2);
    unsigned short* xtA = (unsigned short*)alloc((size_t)N * 128 * 2);
    unsigned short* xtB = (unsigned short*)alloc((size_t)N * 128 * 2);
    unsigned short* xtC = (unsigned short*)alloc((size_t)N * 128 * 2);
    int*   csr3  = (int*)alloc((size_t)3 * E * 4);
    int*   offs3 = (int*)alloc((size_t)3 * (N + 1) * 4);
    int*   bcnt  = (int*)alloc(3 * PA_MAXB * 4);
    int*   bbase = (int*)alloc(3 * PA_MAXB * 4);
    int*   gres  = (int*)alloc(3 * PA_MAXB * 4);
    float* gsum  = (float*)alloc(64 * 128 * 4);
    float* gcnt  = (float*)alloc(64 * 4);
    // pairs (3*E*8 = 19.2 MB) aliased into xtR (25.6 MB): dead before attn2
    // first writes xtR (placeA/placeB complete earlier in stream order).
    int2* pairs = (int2*)xtR;

    const int nbins = (N + (1 << PA_SHIFT) - 1) >> PA_SHIFT;

    hipMemsetAsync(bcnt, 0, 3 * PA_MAXB * 4, stream);
    hipMemsetAsync(gres, 0, 3 * PA_MAXB * 4, stream);
    hipMemsetAsync(gsum, 0, 64 * 128 * 4, stream);
    hipMemsetAsync(gcnt, 0, 64 * 4, stream);

    enc_kernel<<<(N + 7) / 8, 128, 0, stream>>>(x, Wemb, h0, N);

    histB_kernel<<<dim3((E + 256 * HB_K - 1) / (256 * HB_K), 3), 256, 0, stream>>>(
        e0, e1, e2, bcnt, E);
    bscan_kernel<<<1, 256, 0, stream>>>(bcnt, bbase);
    placeA_kernel<<<dim3((E + PA_CHUNK - 1) / PA_CHUNK, 3), 256, 0, stream>>>(
        e0, e1, e2, bbase, gres, pairs, E, N);
    placeB_kernel<<<3 * nbins, 512, 0, stream>>>(
        pairs, bbase, bcnt, offs3, csr3, E, N, nbins);

    const int ATT_GRID = 1024;
    auto run_layer = [&](const unsigned short* lin, unsigned short* lout, int l) {
        attn2_kernel<<<ATT_GRID, 256, 0, stream>>>(
            lin, xtR, xtA, qkv, fw1, fb1, fw2, fb2, l * 4 + 0, l * 4 + 1, N);
        attn2_kernel<<<ATT_GRID, 256, 0, stream>>>(
            lin, xtB, xtC, qkv, fw1, fb1, fw2, fb2, l * 4 + 2, l * 4 + 3, N);
        agg3_kernel<<<(N + 3) / 4, 256, 0, stream>>>(
            xtR, xtA, xtB, xtC, csr3, offs3, lout, N, E);
    };
    run_layer(h0, h1, 0);
    run_layer(h1, h0, 1);

    pool_kernel<<<(N + 63) / 64, 256, 0, stream>>>(h0, bat, gsum, N);
    cnt_kernel<<<(N + 255) / 256, 256, 0, stream>>>(bat, gcnt, N);
    dec_kernel<<<64, 128, 0, stream>>>(gsum, gcnt, mw1, mb1, mw2, mb2, outp);
}

// Round 5
// 671.820 us; speedup vs baseline: 4.7828x; 1.3496x over previous
//
#include <hip/hip_runtime.h>
#include <hip/hip_bf16.h>
#include <cstdint>
#include <cstddef>

// ---------------------------------------------------------------------------
// RGNN_53755810677120 — round 5.
//   enc:    x[N,112] -> pad/PE/W_emb -> h0[N,128] (bf16)
//   CSR:    FUSED across labels: bucket hist -> 256-scan -> placeA
//           (pairs store lab*N+src) -> placeB (single offs[N+1] + csr[3E])
//   attn2:  2 param-sets/launch, bf16 MFMA, outputs into xtR / xt3 slices
//   agg3:   h_out = relu(root + fused-CSR gather sum), unroll-4 MLP
//   pool/dec: fp32 accumulate
// ---------------------------------------------------------------------------

typedef __attribute__((ext_vector_type(8))) short bf16x8;
typedef __attribute__((ext_vector_type(4))) float f32x4;

__device__ inline short f2bf(float f) {
    union { float f; unsigned u; } v; v.f = f;
    unsigned r = (v.u + 0x7FFFu + ((v.u >> 16) & 1u)) >> 16;   // RNE
    return (short)r;
}
__device__ inline float bf2f(unsigned short b) {
    union { unsigned u; float f; } v; v.u = ((unsigned)b) << 16;
    return v.f;
}

// ---------------------------- encoder --------------------------------------
__global__ __launch_bounds__(128) void enc_kernel(
    const float* __restrict__ x, const float* __restrict__ Wemb,
    unsigned short* __restrict__ h, int N)
{
    __shared__ float sxr[8 * 112];
    __shared__ float spe[128];
    __shared__ float sW[1024];
    const int t = threadIdx.x;
    const int n0 = blockIdx.x * 8;

    {
        int s = t >> 5, f = t & 31;
        int i2 = f >> 1;
        float div = __expf(-(float)(2 * i2) * (logf(10000.0f) / 32.0f));
        float ang = (float)s * div;
        spe[t] = (f & 1) ? cosf(ang) : sinf(ang);
    }
    for (int i = t; i < 1024; i += 128) sW[i] = Wemb[i];
    for (int i = t; i < 8 * 112; i += 128) {
        int n = n0 + i / 112;
        sxr[i] = (n < N) ? x[(size_t)n0 * 112 + i] : 0.f;
    }
    __syncthreads();

    const int ts = t >> 5, c = t & 31;
    const int offs_[4] = {0, 16, 48, 80};
    const int lens_[4] = {16, 32, 32, 32};
    const int off = offs_[ts], len = lens_[ts];

    float acc[8];
#pragma unroll
    for (int i = 0; i < 8; ++i) acc[i] = 0.f;
    float pw = 0.f;
    for (int f = 0; f < 32; ++f) {
        float wv = sW[f * 32 + c];
        float pv = spe[ts * 32 + f];
        pw += pv * wv;
        if (f < len) {
#pragma unroll
            for (int i = 0; i < 8; ++i) acc[i] += sxr[i * 112 + off + f] * wv;
        }
    }
#pragma unroll
    for (int i = 0; i < 8; ++i) {
        int n = n0 + i;
        if (n < N)
            h[(size_t)n * 128 + ts * 32 + c] = (unsigned short)f2bf(acc[i] + pw);
    }
}

// ---------------------------- dual-set MFMA attention -----------------------
#define ATT_WAVES 4
#define WLDS 4864

__global__ __launch_bounds__(256, 2) void attn2_kernel(
    const unsigned short* __restrict__ in,
    unsigned short* __restrict__ out0, unsigned short* __restrict__ out1,
    const float* __restrict__ qkv, const float* __restrict__ fw1,
    const float* __restrict__ fb1, const float* __restrict__ fw2,
    const float* __restrict__ fb2,
    int pi0, int pi1, int N)
{
    __shared__ char smem[ATT_WAVES * WLDS];
    const int lane = threadIdx.x & 63;
    const int wave = threadIdx.x >> 6;
    const int q = lane >> 4;
    const int m = lane & 15;

    char* wb = smem + wave * WLDS;
    short* Qb = (short*)(wb);          // [16][40] shorts (also Y)
    short* Kb = (short*)(wb + 1280);   // [16][40] (also Z)
    short* VT = (short*)(wb + 2560);   // [32][24] shorts (V^T)
    short* Pb = (short*)(wb + 4096);   // [16][24] shorts

    const f32x4 zf = {0.f, 0.f, 0.f, 0.f};

    bf16x8 wqkv[2][6], w1f[2][2], w2f[2][2];
    float b1v[2][2], b2v[2][2];
    const int pis[2] = {pi0, pi1};
#pragma unroll
    for (int s = 0; s < 2; ++s) {
        const float* Wq = qkv + (size_t)pis[s] * 32 * 96;
        const float* W1 = fw1 + (size_t)pis[s] * 32 * 32;
        const float* W2 = fw2 + (size_t)pis[s] * 32 * 32;
#pragma unroll
        for (int ci = 0; ci < 6; ++ci) {
            bf16x8 f;
#pragma unroll
            for (int j = 0; j < 8; ++j)
                f[j] = f2bf(Wq[(q * 8 + j) * 96 + ci * 16 + m]);
            wqkv[s][ci] = f;
        }
#pragma unroll
        for (int t = 0; t < 2; ++t) {
            bf16x8 f1, f2;
#pragma unroll
            for (int j = 0; j < 8; ++j) {
                f1[j] = f2bf(W1[(q * 8 + j) * 32 + t * 16 + m]);
                f2[j] = f2bf(W2[(q * 8 + j) * 32 + t * 16 + m]);
            }
            w1f[s][t] = f1; w2f[s][t] = f2;
            b1v[s][t] = fb1[pis[s] * 32 + t * 16 + m];
            b2v[s][t] = fb2[pis[s] * 32 + t * 16 + m];
        }
    }

    const int ntiles = (N + 3) >> 2;
    for (int tile = blockIdx.x * ATT_WAVES + wave; tile < ntiles;
         tile += gridDim.x * ATT_WAVES) {
        const int n0 = tile * 4;
        const int node_m = n0 + (m >> 2);

        bf16x8 ax = {0, 0, 0, 0, 0, 0, 0, 0};
        if (node_m < N)
            ax = *(const bf16x8*)(in + (size_t)n0 * 128 + m * 32 + q * 8);

#pragma unroll
        for (int s = 0; s < 2; ++s) {
            // ---- qkv ----
            f32x4 accq[6];
#pragma unroll
            for (int ci = 0; ci < 6; ++ci)
                accq[ci] = __builtin_amdgcn_mfma_f32_16x16x32_bf16(ax, wqkv[s][ci], zf, 0, 0, 0);
#pragma unroll
            for (int t = 0; t < 2; ++t) {
#pragma unroll
                for (int r = 0; r < 4; ++r) {
                    Qb[(q * 4 + r) * 40 + m + 16 * t] = f2bf(accq[t][r]);
                    Kb[(q * 4 + r) * 40 + m + 16 * t] = f2bf(accq[2 + t][r]);
                }
                uint2 d;
                d.x = (unsigned short)f2bf(accq[4 + t][0]) |
                      ((unsigned)(unsigned short)f2bf(accq[4 + t][1]) << 16);
                d.y = (unsigned short)f2bf(accq[4 + t][2]) |
                      ((unsigned)(unsigned short)f2bf(accq[4 + t][3]) << 16);
                *(uint2*)((char*)VT + (size_t)(m + 16 * t) * 48 + q * 8) = d;
            }

            // ---- scores ----
            bf16x8 aq = *(const bf16x8*)((char*)Qb + m * 80 + q * 16);
            bf16x8 bk = *(const bf16x8*)((char*)Kb + m * 80 + q * 16);
            f32x4 sc = __builtin_amdgcn_mfma_f32_16x16x32_bf16(aq, bk, zf, 0, 0, 0);

            // ---- softmax over 4 tokens ----
            const bool valid = ((m >> 2) == q);
            float p[4];
#pragma unroll
            for (int r = 0; r < 4; ++r) {
                float v = sc[r] * 0.1767766952966369f;
                float mx = fmaxf(v, __shfl_xor(v, 1));
                mx = fmaxf(mx, __shfl_xor(mx, 2));
                float e = __expf(v - mx);
                float sm = e + __shfl_xor(e, 1);
                sm += __shfl_xor(sm, 2);
                p[r] = e / sm;
            }
#pragma unroll
            for (int r = 0; r < 4; ++r)
                Pb[(q * 4 + r) * 24 + m] = valid ? f2bf(p[r]) : (short)0;

            // ---- PV ----
            bf16x8 ap = {0, 0, 0, 0, 0, 0, 0, 0};
            if (q < 2) ap = *(const bf16x8*)((char*)Pb + m * 48 + q * 16);
            f32x4 y[2];
#pragma unroll
            for (int t = 0; t < 2; ++t) {
                bf16x8 bv = {0, 0, 0, 0, 0, 0, 0, 0};
                if (q < 2) bv = *(const bf16x8*)((char*)VT + (size_t)(m + 16 * t) * 48 + q * 16);
                y[t] = __builtin_amdgcn_mfma_f32_16x16x32_bf16(ap, bv, zf, 0, 0, 0);
            }

            // ---- ffn1 ----
#pragma unroll
            for (int t = 0; t < 2; ++t)
#pragma unroll
                for (int r = 0; r < 4; ++r)
                    Qb[(q * 4 + r) * 40 + m + 16 * t] = f2bf(y[t][r]);
            bf16x8 ay = *(const bf16x8*)((char*)Qb + m * 80 + q * 16);
            f32x4 z1[2];
#pragma unroll
            for (int t = 0; t < 2; ++t)
                z1[t] = __builtin_amdgcn_mfma_f32_16x16x32_bf16(ay, w1f[s][t], zf, 0, 0, 0);

            // ---- ffn2 ----
#pragma unroll
            for (int t = 0; t < 2; ++t)
#pragma unroll
                for (int r = 0; r < 4; ++r)
                    Kb[(q * 4 + r) * 40 + m + 16 * t] = f2bf(fmaxf(z1[t][r] + b1v[s][t], 0.f));
            bf16x8 az = *(const bf16x8*)((char*)Kb + m * 80 + q * 16);
            f32x4 o[2];
#pragma unroll
            for (int t = 0; t < 2; ++t)
                o[t] = __builtin_amdgcn_mfma_f32_16x16x32_bf16(az, w2f[s][t], zf, 0, 0, 0);

            // ---- epilogue ----
            unsigned short* op = s ? out1 : out0;
#pragma unroll
            for (int t = 0; t < 2; ++t)
#pragma unroll
                for (int r = 0; r < 4; ++r) {
                    int row = q * 4 + r;
                    int node = n0 + (row >> 2);
                    if (node < N)
                        op[(size_t)n0 * 128 + row * 32 + m + 16 * t] =
                            (unsigned short)f2bf(y[t][r] + o[t][r] + b2v[s][t]);
                }
        }
    }
}

// ---------------------------- fused CSR build -------------------------------
#define PA_CHUNK 4096
#define PA_SHIFT 9
#define PA_MAXB  256
#define HB_K     16

// bucket histogram over ALL labels; blockIdx.y = label
__global__ __launch_bounds__(256) void histB_kernel(
    const int* __restrict__ e0, const int* __restrict__ e1,
    const int* __restrict__ e2, int* __restrict__ bcnt, int E)
{
    __shared__ int lh[PA_MAXB];
    const int lab = blockIdx.y;
    const int* e = (lab == 0) ? e0 : (lab == 1) ? e1 : e2;
    const int t = threadIdx.x;
    for (int i = t; i < PA_MAXB; i += 256) lh[i] = 0;
    __syncthreads();
    const int base = blockIdx.x * 256 * HB_K;
#pragma unroll
    for (int k = 0; k < HB_K; ++k) {
        int i = base + k * 256 + t;
        if (i < E) atomicAdd(&lh[e[E + i] >> PA_SHIFT], 1);
    }
    __syncthreads();
    for (int i = t; i < PA_MAXB; i += 256)
        if (lh[i]) atomicAdd(&bcnt[i], lh[i]);
}

// exclusive scan of 256 buckets (1 block)
__global__ __launch_bounds__(256) void bscan_kernel(
    const int* __restrict__ bcnt, int* __restrict__ bbase)
{
    __shared__ int sd[PA_MAXB];
    const int t = threadIdx.x;
    sd[t] = bcnt[t];
    __syncthreads();
    int own = sd[t];
    for (int o = 1; o < 256; o <<= 1) {
        int v = (t >= o) ? sd[t - o] : 0;
        __syncthreads();
        sd[t] += v;
        __syncthreads();
    }
    bbase[t] = sd[t] - own;
}

// Phase A: bin edges by dst>>9; pairs store (lab*N+src, dst).
__global__ __launch_bounds__(256) void placeA_kernel(
    const int* __restrict__ e0, const int* __restrict__ e1, const int* __restrict__ e2,
    const int* __restrict__ bbase, int* __restrict__ gres,
    int2* __restrict__ pairs, int E, int N)
{
    __shared__ int2 sStage[PA_CHUNK];
    __shared__ int sCnt[PA_MAXB], sScan[PA_MAXB], sCur[PA_MAXB], sGB[PA_MAXB];

    const int lab = blockIdx.y;
    const int t = threadIdx.x;
    const int base = blockIdx.x * PA_CHUNK;
    const int* e = (lab == 0) ? e0 : (lab == 1) ? e1 : e2;
    const int srcoff = lab * N;
    const int nbins = (N + (1 << PA_SHIFT) - 1) >> PA_SHIFT;

    for (int i = t; i < PA_MAXB; i += 256) { sCnt[i] = 0; sCur[i] = 0; }
    __syncthreads();

    int msrc[16], mdst[16];
    const int cnt_total = min(PA_CHUNK, E - base);
#pragma unroll
    for (int k = 0; k < 16; ++k) {
        int i = base + k * 256 + t;
        if (i < E) {
            msrc[k] = srcoff + e[i];
            int d = e[E + i];
            mdst[k] = d;
            atomicAdd(&sCnt[d >> PA_SHIFT], 1);
        } else mdst[k] = -1;
    }
    __syncthreads();

    sScan[t] = sCnt[t];
    __syncthreads();
    for (int o = 1; o < 256; o <<= 1) {
        int v = (t >= o) ? sScan[t - o] : 0;
        __syncthreads();
        sScan[t] += v;
        __syncthreads();
    }
    if (t < nbins && sCnt[t] > 0)
        sGB[t] = bbase[t] + atomicAdd(&gres[t], sCnt[t]);
    __syncthreads();

#pragma unroll
    for (int k = 0; k < 16; ++k) {
        if (mdst[k] >= 0) {
            int bin = mdst[k] >> PA_SHIFT;
            int r = atomicAdd(&sCur[bin], 1);
            sStage[(sScan[bin] - sCnt[bin]) + r] = make_int2(msrc[k], mdst[k]);
        }
    }
    __syncthreads();

    for (int i = t; i < cnt_total; i += 256) {
        int2 pr = sStage[i];
        int bin = pr.y >> PA_SHIFT;
        pairs[sGB[bin] + (i - (sScan[bin] - sCnt[bin]))] = pr;
    }
}

// Phase B: per bucket: local per-node count + scan -> offs[N+1] + csr[3E].
__global__ __launch_bounds__(512) void placeB_kernel(
    const int2* __restrict__ pairs, const int* __restrict__ bbase,
    const int* __restrict__ bcnt, int* __restrict__ offs,
    int* __restrict__ csr, int N, int nbins)
{
    __shared__ int sCnt[512], sScan[512], sFill[512];
    const int bin = blockIdx.x;
    const int t = threadIdx.x;
    const int n0 = bin << PA_SHIFT;
    const int n1 = min(n0 + 512, N);
    const int len = n1 - n0;
    const int rb  = bbase[bin];
    const int cnt = bcnt[bin];
    const int2* gp = pairs + rb;

    sCnt[t] = 0; sFill[t] = 0;
    __syncthreads();
    for (int i = t; i < cnt; i += 512)
        atomicAdd(&sCnt[gp[i].y - n0], 1);
    __syncthreads();
    sScan[t] = sCnt[t];
    __syncthreads();
    for (int o = 1; o < 512; o <<= 1) {
        int v = (t >= o) ? sScan[t - o] : 0;
        __syncthreads();
        sScan[t] += v;
        __syncthreads();
    }
    const int excl = sScan[t] - sCnt[t];
    if (t < len) offs[n0 + t] = rb + excl;
    if (bin == nbins - 1 && t == 0) offs[N] = rb + cnt;
    sScan[t] = excl;
    __syncthreads();

    for (int i = t; i < cnt; i += 512) {
        int2 pr = gp[i];
        int ln = pr.y - n0;
        int p = atomicAdd(&sFill[ln], 1);
        csr[rb + sScan[ln] + p] = pr.x;
    }
}

// ---------------------------- fused aggregation -----------------------------
// h_out[dst] = relu( root[dst] + sum_{k in offs[dst]..offs[dst+1]} xt3[csr[k]] )
// csr entries index rows of xt3[3*N][128]; unroll-4 for memory-level parallelism.
__global__ __launch_bounds__(256) void agg3_kernel(
    const unsigned short* __restrict__ xtR,
    const unsigned short* __restrict__ xt3,
    const int* __restrict__ csr, const int* __restrict__ offs,
    unsigned short* __restrict__ hout, int N)
{
    int w = threadIdx.x >> 6, lane = threadIdx.x & 63;
    int dst = blockIdx.x * 4 + w;
    if (dst >= N) return;

    const ushort2* r2 = (const ushort2*)xtR;
    ushort2 rv = r2[(size_t)dst * 64 + lane];
    float2 a0 = make_float2(bf2f(rv.x), bf2f(rv.y));
    float2 a1 = make_float2(0.f, 0.f);
    float2 a2 = make_float2(0.f, 0.f);
    float2 a3 = make_float2(0.f, 0.f);

    const ushort2* x2 = (const ushort2*)xt3;
    const int beg = offs[dst], end = offs[dst + 1];
    int k = beg;
    for (; k + 4 <= end; k += 4) {
        int s0 = csr[k], s1 = csr[k + 1], s2 = csr[k + 2], s3 = csr[k + 3];
        ushort2 v0 = x2[(size_t)s0 * 64 + lane];
        ushort2 v1 = x2[(size_t)s1 * 64 + lane];
        ushort2 v2 = x2[(size_t)s2 * 64 + lane];
        ushort2 v3 = x2[(size_t)s3 * 64 + lane];
        a0.x += bf2f(v0.x); a0.y += bf2f(v0.y);
        a1.x += bf2f(v1.x); a1.y += bf2f(v1.y);
        a2.x += bf2f(v2.x); a2.y += bf2f(v2.y);
        a3.x += bf2f(v3.x); a3.y += bf2f(v3.y);
    }
    for (; k < end; ++k) {
        int s0 = csr[k];
        ushort2 v0 = x2[(size_t)s0 * 64 + lane];
        a0.x += bf2f(v0.x); a0.y += bf2f(v0.y);
    }
    float sx = (a0.x + a1.x) + (a2.x + a3.x);
    float sy = (a0.y + a1.y) + (a2.y + a3.y);
    ushort2 o;
    o.x = (unsigned short)f2bf(fmaxf(sx, 0.f));
    o.y = (unsigned short)f2bf(fmaxf(sy, 0.f));
    ((ushort2*)hout)[(size_t)dst * 64 + lane] = o;
}

// ---------------------------- pool / counts / decoder ----------------------
__global__ __launch_bounds__(256) void pool_kernel(
    const unsigned short* __restrict__ in, const int* __restrict__ batch,
    float* __restrict__ gsum, int N)
{
    int t = threadIdx.x;
    int j = t & 127, half = t >> 7;
    int n0 = blockIdx.x * 64 + half * 32;
    float acc = 0.f; int cur = -1;
    for (int i = 0; i < 32; ++i) {
        int n = n0 + i;
        if (n >= N) break;
        int g = batch[n];
        if (g != cur) {
            if (cur >= 0) atomicAdd(&gsum[cur * 128 + j], acc);
            cur = g; acc = 0.f;
        }
        acc += bf2f(in[(size_t)n * 128 + j]);   // h already relu'd
    }
    if (cur >= 0) atomicAdd(&gsum[cur * 128 + j], acc);
}

__global__ __launch_bounds__(256) void cnt_kernel(
    const int* __restrict__ batch, float* __restrict__ gcnt, int N)
{
    __shared__ float lh[64];
    int t = threadIdx.x;
    if (t < 64) lh[t] = 0.f;
    __syncthreads();
    int i = blockIdx.x * 256 + t;
    if (i < N) atomicAdd(&lh[batch[i]], 1.0f);
    __syncthreads();
    if (t < 64 && lh[t] != 0.f) atomicAdd(&gcnt[t], lh[t]);
}

__global__ __launch_bounds__(128) void dec_kernel(
    const float* __restrict__ gsum, const float* __restrict__ gcnt,
    const float* __restrict__ W1, const float* __restrict__ B1,
    const float* __restrict__ W2, const float* __restrict__ B2,
    float* __restrict__ out)
{
    __shared__ float sg[128];
    __shared__ float sh[128];
    int t = threadIdx.x, b = blockIdx.x;
    float cinv = 1.0f / fmaxf(gcnt[b], 1.0f);
    sg[t] = gsum[b * 128 + t] * cinv;
    __syncthreads();
    float acc = B1[t];
    for (int f = 0; f < 128; ++f) acc += sg[f] * W1[f * 128 + t];
    sh[t] = fmaxf(acc, 0.f) * W2[t];
    __syncthreads();
    for (int o = 64; o > 0; o >>= 1) {
        if (t < o) sh[t] += sh[t + o];
        __syncthreads();
    }
    if (t == 0) out[b] = sh[0] + B2[0];
}

// ---------------------------- launch ---------------------------------------
extern "C" void kernel_launch(void* const* d_in, const int* in_sizes, int n_in,
                              void* d_out, int out_size, void* d_ws, size_t ws_size,
                              hipStream_t stream)
{
    const float* x    = (const float*)d_in[0];
    const int*   e0   = (const int*)d_in[1];
    const int*   e1   = (const int*)d_in[2];
    const int*   e2   = (const int*)d_in[3];
    const int*   bat  = (const int*)d_in[4];
    const float* Wemb = (const float*)d_in[5];
    const float* qkv  = (const float*)d_in[6];
    const float* fw1  = (const float*)d_in[7];
    const float* fb1  = (const float*)d_in[8];
    const float* fw2  = (const float*)d_in[9];
    const float* fb2  = (const float*)d_in[10];
    const float* mw1  = (const float*)d_in[11];
    const float* mb1  = (const float*)d_in[12];
    const float* mw2  = (const float*)d_in[13];
    const float* mb2  = (const float*)d_in[14];
    const int N = in_sizes[0] / 112;
    const int E = in_sizes[1] / 2;
    float* outp = (float*)d_out;
    (void)n_in; (void)out_size; (void)ws_size;

    char* w = (char*)d_ws;
    auto alloc = [&](size_t bytes) {
        char* p = w; w += (bytes + 255) & ~(size_t)255; return p;
    };
    unsigned short* h0  = (unsigned short*)alloc((size_t)N * 128 * 2);
    unsigned short* h1  = (unsigned short*)alloc((size_t)N * 128 * 2);
    unsigned short* xtR = (unsigned short*)alloc((size_t)N * 128 * 2);
    unsigned short* xt3 = (unsigned short*)alloc((size_t)3 * N * 128 * 2);
    int*   csr   = (int*)alloc((size_t)3 * E * 4);
    int*   offs  = (int*)alloc((size_t)(N + 1) * 4);
    int*   bcnt  = (int*)alloc(PA_MAXB * 4);
    int*   bbase = (int*)alloc(PA_MAXB * 4);
    int*   gres  = (int*)alloc(PA_MAXB * 4);
    float* gsum  = (float*)alloc(64 * 128 * 4);
    float* gcnt  = (float*)alloc(64 * 4);
    // pairs (3*E*8 = 19.2 MB) aliased into xtR (25.6 MB): consumed by placeB
    // before attn2 first writes xtR (stream-ordered).
    int2* pairs = (int2*)xtR;

    const int nbins = (N + (1 << PA_SHIFT) - 1) >> PA_SHIFT;

    hipMemsetAsync(bcnt, 0, PA_MAXB * 4, stream);
    hipMemsetAsync(gres, 0, PA_MAXB * 4, stream);
    hipMemsetAsync(gsum, 0, 64 * 128 * 4, stream);
    hipMemsetAsync(gcnt, 0, 64 * 4, stream);

    enc_kernel<<<(N + 7) / 8, 128, 0, stream>>>(x, Wemb, h0, N);

    histB_kernel<<<dim3((E + 256 * HB_K - 1) / (256 * HB_K), 3), 256, 0, stream>>>(
        e0, e1, e2, bcnt, E);
    bscan_kernel<<<1, 256, 0, stream>>>(bcnt, bbase);
    placeA_kernel<<<dim3((E + PA_CHUNK - 1) / PA_CHUNK, 3), 256, 0, stream>>>(
        e0, e1, e2, bbase, gres, pairs, E, N);
    placeB_kernel<<<nbins, 512, 0, stream>>>(pairs, bbase, bcnt, offs, csr, N, nbins);

    const int ATT_GRID = 1024;
    auto run_layer = [&](const unsigned short* lin, unsigned short* lout, int l) {
        attn2_kernel<<<ATT_GRID, 256, 0, stream>>>(
            lin, xtR, xt3, qkv, fw1, fb1, fw2, fb2, l * 4 + 0, l * 4 + 1, N);
        attn2_kernel<<<ATT_GRID, 256, 0, stream>>>(
            lin, xt3 + (size_t)N * 128, xt3 + (size_t)2 * N * 128,
            qkv, fw1, fb1, fw2, fb2, l * 4 + 2, l * 4 + 3, N);
        agg3_kernel<<<(N + 3) / 4, 256, 0, stream>>>(xtR, xt3, csr, offs, lout, N);
    };
    run_layer(h0, h1, 0);
    run_layer(h1, h0, 1);

    pool_kernel<<<(N + 63) / 64, 256, 0, stream>>>(h0, bat, gsum, N);
    cnt_kernel<<<(N + 255) / 256, 256, 0, stream>>>(bat, gcnt, N);
    dec_kernel<<<64, 128, 0, stream>>>(gsum, gcnt, mw1, mb1, mw2, mb2, outp);
}

// Round 6
// 645.521 us; speedup vs baseline: 4.9777x; 1.0407x over previous
//
#include <hip/hip_runtime.h>
#include <hip/hip_bf16.h>
#include <cstdint>
#include <cstddef>

// ---------------------------------------------------------------------------
// RGNN_53755810677120 — round 6.
//   wprep:  repack qkv/W1/W2 (8 sets) into bf16 MFMA B-frag lane order
//   enc:    x[N,112] -> pad/PE/W_emb -> h0[N,128] (bf16)
//   CSR:    fused-label bucket CSR (hist -> scan -> placeA -> placeB)
//   attn2:  2 param-sets/launch, bf16 MFMA, coalesced frag preamble
//   agg3:   h_out = relu(root + fused gather sum), unroll-8 MLP
//   pool/dec: fp32 accumulate
// ---------------------------------------------------------------------------

typedef __attribute__((ext_vector_type(8))) short bf16x8;
typedef __attribute__((ext_vector_type(4))) float f32x4;

__device__ inline short f2bf(float f) {
    union { float f; unsigned u; } v; v.f = f;
    unsigned r = (v.u + 0x7FFFu + ((v.u >> 16) & 1u)) >> 16;   // RNE
    return (short)r;
}
__device__ inline float bf2f(unsigned short b) {
    union { unsigned u; float f; } v; v.u = ((unsigned)b) << 16;
    return v.f;
}

// ---------------------------- weight prep ----------------------------------
// wpack[((pi*10 + f)*64 + lane)*8 + j], f: 0..5 qkv cols, 6..7 W1, 8..9 W2.
__global__ __launch_bounds__(64) void wprep_kernel(
    const float* __restrict__ qkv, const float* __restrict__ fw1,
    const float* __restrict__ fw2, unsigned short* __restrict__ wpack)
{
    const int pi = blockIdx.x;
    const int lane = threadIdx.x;
    const int q = lane >> 4, m = lane & 15;
    const float* Wq = qkv + (size_t)pi * 32 * 96;
    const float* W1 = fw1 + (size_t)pi * 32 * 32;
    const float* W2 = fw2 + (size_t)pi * 32 * 32;
    unsigned short* dst = wpack + (size_t)pi * 10 * 64 * 8;
#pragma unroll
    for (int ci = 0; ci < 6; ++ci)
#pragma unroll
        for (int j = 0; j < 8; ++j)
            dst[(ci * 64 + lane) * 8 + j] =
                (unsigned short)f2bf(Wq[(q * 8 + j) * 96 + ci * 16 + m]);
#pragma unroll
    for (int t = 0; t < 2; ++t)
#pragma unroll
        for (int j = 0; j < 8; ++j) {
            dst[((6 + t) * 64 + lane) * 8 + j] =
                (unsigned short)f2bf(W1[(q * 8 + j) * 32 + t * 16 + m]);
            dst[((8 + t) * 64 + lane) * 8 + j] =
                (unsigned short)f2bf(W2[(q * 8 + j) * 32 + t * 16 + m]);
        }
}

// ---------------------------- encoder --------------------------------------
__global__ __launch_bounds__(128) void enc_kernel(
    const float* __restrict__ x, const float* __restrict__ Wemb,
    unsigned short* __restrict__ h, int N)
{
    __shared__ float sxr[8 * 112];
    __shared__ float spe[128];
    __shared__ float sW[1024];
    const int t = threadIdx.x;
    const int n0 = blockIdx.x * 8;

    {
        int s = t >> 5, f = t & 31;
        int i2 = f >> 1;
        float div = __expf(-(float)(2 * i2) * (logf(10000.0f) / 32.0f));
        float ang = (float)s * div;
        spe[t] = (f & 1) ? cosf(ang) : sinf(ang);
    }
    for (int i = t; i < 1024; i += 128) sW[i] = Wemb[i];
    for (int i = t; i < 8 * 112; i += 128) {
        int n = n0 + i / 112;
        sxr[i] = (n < N) ? x[(size_t)n0 * 112 + i] : 0.f;
    }
    __syncthreads();

    const int ts = t >> 5, c = t & 31;
    const int offs_[4] = {0, 16, 48, 80};
    const int lens_[4] = {16, 32, 32, 32};
    const int off = offs_[ts], len = lens_[ts];

    float acc[8];
#pragma unroll
    for (int i = 0; i < 8; ++i) acc[i] = 0.f;
    float pw = 0.f;
    for (int f = 0; f < 32; ++f) {
        float wv = sW[f * 32 + c];
        float pv = spe[ts * 32 + f];
        pw += pv * wv;
        if (f < len) {
#pragma unroll
            for (int i = 0; i < 8; ++i) acc[i] += sxr[i * 112 + off + f] * wv;
        }
    }
#pragma unroll
    for (int i = 0; i < 8; ++i) {
        int n = n0 + i;
        if (n < N)
            h[(size_t)n * 128 + ts * 32 + c] = (unsigned short)f2bf(acc[i] + pw);
    }
}

// ---------------------------- dual-set MFMA attention -----------------------
#define ATT_WAVES 4
#define WLDS 4864

__global__ __launch_bounds__(256, 2) void attn2_kernel(
    const unsigned short* __restrict__ in,
    unsigned short* __restrict__ out0, unsigned short* __restrict__ out1,
    const unsigned short* __restrict__ wpack,
    const float* __restrict__ fb1, const float* __restrict__ fb2,
    int pi0, int pi1, int N)
{
    __shared__ char smem[ATT_WAVES * WLDS];
    const int lane = threadIdx.x & 63;
    const int wave = threadIdx.x >> 6;
    const int q = lane >> 4;
    const int m = lane & 15;

    char* wb = smem + wave * WLDS;
    short* Qb = (short*)(wb);          // [16][40] shorts (also Y)
    short* Kb = (short*)(wb + 1280);   // [16][40] (also Z)
    short* VT = (short*)(wb + 2560);   // [32][24] shorts (V^T)
    short* Pb = (short*)(wb + 4096);   // [16][24] shorts

    const f32x4 zf = {0.f, 0.f, 0.f, 0.f};

    // ---- weight B-frags: coalesced 16B loads from wpack ----
    bf16x8 wqkv[2][6], w1f[2][2], w2f[2][2];
    float b1v[2][2], b2v[2][2];
    const int pis[2] = {pi0, pi1};
#pragma unroll
    for (int s = 0; s < 2; ++s) {
        const unsigned short* wp = wpack + ((size_t)pis[s] * 10 * 64 + lane) * 8;
#pragma unroll
        for (int ci = 0; ci < 6; ++ci)
            wqkv[s][ci] = *(const bf16x8*)(wp + ci * 64 * 8);
#pragma unroll
        for (int t = 0; t < 2; ++t) {
            w1f[s][t] = *(const bf16x8*)(wp + (6 + t) * 64 * 8);
            w2f[s][t] = *(const bf16x8*)(wp + (8 + t) * 64 * 8);
            b1v[s][t] = fb1[pis[s] * 32 + t * 16 + m];
            b2v[s][t] = fb2[pis[s] * 32 + t * 16 + m];
        }
    }

    const int ntiles = (N + 3) >> 2;
    for (int tile = blockIdx.x * ATT_WAVES + wave; tile < ntiles;
         tile += gridDim.x * ATT_WAVES) {
        const int n0 = tile * 4;
        const int node_m = n0 + (m >> 2);

        bf16x8 ax = {0, 0, 0, 0, 0, 0, 0, 0};
        if (node_m < N)
            ax = *(const bf16x8*)(in + (size_t)n0 * 128 + m * 32 + q * 8);

#pragma unroll
        for (int s = 0; s < 2; ++s) {
            // ---- qkv ----
            f32x4 accq[6];
#pragma unroll
            for (int ci = 0; ci < 6; ++ci)
                accq[ci] = __builtin_amdgcn_mfma_f32_16x16x32_bf16(ax, wqkv[s][ci], zf, 0, 0, 0);
#pragma unroll
            for (int t = 0; t < 2; ++t) {
#pragma unroll
                for (int r = 0; r < 4; ++r) {
                    Qb[(q * 4 + r) * 40 + m + 16 * t] = f2bf(accq[t][r]);
                    Kb[(q * 4 + r) * 40 + m + 16 * t] = f2bf(accq[2 + t][r]);
                }
                uint2 d;
                d.x = (unsigned short)f2bf(accq[4 + t][0]) |
                      ((unsigned)(unsigned short)f2bf(accq[4 + t][1]) << 16);
                d.y = (unsigned short)f2bf(accq[4 + t][2]) |
                      ((unsigned)(unsigned short)f2bf(accq[4 + t][3]) << 16);
                *(uint2*)((char*)VT + (size_t)(m + 16 * t) * 48 + q * 8) = d;
            }

            // ---- scores ----
            bf16x8 aq = *(const bf16x8*)((char*)Qb + m * 80 + q * 16);
            bf16x8 bk = *(const bf16x8*)((char*)Kb + m * 80 + q * 16);
            f32x4 sc = __builtin_amdgcn_mfma_f32_16x16x32_bf16(aq, bk, zf, 0, 0, 0);

            // ---- softmax over 4 tokens ----
            const bool valid = ((m >> 2) == q);
            float p[4];
#pragma unroll
            for (int r = 0; r < 4; ++r) {
                float v = sc[r] * 0.1767766952966369f;
                float mx = fmaxf(v, __shfl_xor(v, 1));
                mx = fmaxf(mx, __shfl_xor(mx, 2));
                float e = __expf(v - mx);
                float sm = e + __shfl_xor(e, 1);
                sm += __shfl_xor(sm, 2);
                p[r] = e / sm;
            }
#pragma unroll
            for (int r = 0; r < 4; ++r)
                Pb[(q * 4 + r) * 24 + m] = valid ? f2bf(p[r]) : (short)0;

            // ---- PV ----
            bf16x8 ap = {0, 0, 0, 0, 0, 0, 0, 0};
            if (q < 2) ap = *(const bf16x8*)((char*)Pb + m * 48 + q * 16);
            f32x4 y[2];
#pragma unroll
            for (int t = 0; t < 2; ++t) {
                bf16x8 bv = {0, 0, 0, 0, 0, 0, 0, 0};
                if (q < 2) bv = *(const bf16x8*)((char*)VT + (size_t)(m + 16 * t) * 48 + q * 16);
                y[t] = __builtin_amdgcn_mfma_f32_16x16x32_bf16(ap, bv, zf, 0, 0, 0);
            }

            // ---- ffn1 ----
#pragma unroll
            for (int t = 0; t < 2; ++t)
#pragma unroll
                for (int r = 0; r < 4; ++r)
                    Qb[(q * 4 + r) * 40 + m + 16 * t] = f2bf(y[t][r]);
            bf16x8 ay = *(const bf16x8*)((char*)Qb + m * 80 + q * 16);
            f32x4 z1[2];
#pragma unroll
            for (int t = 0; t < 2; ++t)
                z1[t] = __builtin_amdgcn_mfma_f32_16x16x32_bf16(ay, w1f[s][t], zf, 0, 0, 0);

            // ---- ffn2 ----
#pragma unroll
            for (int t = 0; t < 2; ++t)
#pragma unroll
                for (int r = 0; r < 4; ++r)
                    Kb[(q * 4 + r) * 40 + m + 16 * t] = f2bf(fmaxf(z1[t][r] + b1v[s][t], 0.f));
            bf16x8 az = *(const bf16x8*)((char*)Kb + m * 80 + q * 16);
            f32x4 o[2];
#pragma unroll
            for (int t = 0; t < 2; ++t)
                o[t] = __builtin_amdgcn_mfma_f32_16x16x32_bf16(az, w2f[s][t], zf, 0, 0, 0);

            // ---- epilogue ----
            unsigned short* op = s ? out1 : out0;
#pragma unroll
            for (int t = 0; t < 2; ++t)
#pragma unroll
                for (int r = 0; r < 4; ++r) {
                    int row = q * 4 + r;
                    int node = n0 + (row >> 2);
                    if (node < N)
                        op[(size_t)n0 * 128 + row * 32 + m + 16 * t] =
                            (unsigned short)f2bf(y[t][r] + o[t][r] + b2v[s][t]);
                }
        }
    }
}

// ---------------------------- fused CSR build -------------------------------
#define PA_CHUNK 4096
#define PA_SHIFT 9
#define PA_MAXB  256
#define HB_K     16

__global__ __launch_bounds__(256) void histB_kernel(
    const int* __restrict__ e0, const int* __restrict__ e1,
    const int* __restrict__ e2, int* __restrict__ bcnt, int E)
{
    __shared__ int lh[PA_MAXB];
    const int lab = blockIdx.y;
    const int* e = (lab == 0) ? e0 : (lab == 1) ? e1 : e2;
    const int t = threadIdx.x;
    for (int i = t; i < PA_MAXB; i += 256) lh[i] = 0;
    __syncthreads();
    const int base = blockIdx.x * 256 * HB_K;
#pragma unroll
    for (int k = 0; k < HB_K; ++k) {
        int i = base + k * 256 + t;
        if (i < E) atomicAdd(&lh[e[E + i] >> PA_SHIFT], 1);
    }
    __syncthreads();
    for (int i = t; i < PA_MAXB; i += 256)
        if (lh[i]) atomicAdd(&bcnt[i], lh[i]);
}

__global__ __launch_bounds__(256) void bscan_kernel(
    const int* __restrict__ bcnt, int* __restrict__ bbase)
{
    __shared__ int sd[PA_MAXB];
    const int t = threadIdx.x;
    sd[t] = bcnt[t];
    __syncthreads();
    int own = sd[t];
    for (int o = 1; o < 256; o <<= 1) {
        int v = (t >= o) ? sd[t - o] : 0;
        __syncthreads();
        sd[t] += v;
        __syncthreads();
    }
    bbase[t] = sd[t] - own;
}

__global__ __launch_bounds__(256) void placeA_kernel(
    const int* __restrict__ e0, const int* __restrict__ e1, const int* __restrict__ e2,
    const int* __restrict__ bbase, int* __restrict__ gres,
    int2* __restrict__ pairs, int E, int N)
{
    __shared__ int2 sStage[PA_CHUNK];
    __shared__ int sCnt[PA_MAXB], sScan[PA_MAXB], sCur[PA_MAXB], sGB[PA_MAXB];

    const int lab = blockIdx.y;
    const int t = threadIdx.x;
    const int base = blockIdx.x * PA_CHUNK;
    const int* e = (lab == 0) ? e0 : (lab == 1) ? e1 : e2;
    const int srcoff = lab * N;
    const int nbins = (N + (1 << PA_SHIFT) - 1) >> PA_SHIFT;

    for (int i = t; i < PA_MAXB; i += 256) { sCnt[i] = 0; sCur[i] = 0; }
    __syncthreads();

    int msrc[16], mdst[16];
    const int cnt_total = min(PA_CHUNK, E - base);
#pragma unroll
    for (int k = 0; k < 16; ++k) {
        int i = base + k * 256 + t;
        if (i < E) {
            msrc[k] = srcoff + e[i];
            int d = e[E + i];
            mdst[k] = d;
            atomicAdd(&sCnt[d >> PA_SHIFT], 1);
        } else mdst[k] = -1;
    }
    __syncthreads();

    sScan[t] = sCnt[t];
    __syncthreads();
    for (int o = 1; o < 256; o <<= 1) {
        int v = (t >= o) ? sScan[t - o] : 0;
        __syncthreads();
        sScan[t] += v;
        __syncthreads();
    }
    if (t < nbins && sCnt[t] > 0)
        sGB[t] = bbase[t] + atomicAdd(&gres[t], sCnt[t]);
    __syncthreads();

#pragma unroll
    for (int k = 0; k < 16; ++k) {
        if (mdst[k] >= 0) {
            int bin = mdst[k] >> PA_SHIFT;
            int r = atomicAdd(&sCur[bin], 1);
            sStage[(sScan[bin] - sCnt[bin]) + r] = make_int2(msrc[k], mdst[k]);
        }
    }
    __syncthreads();

    for (int i = t; i < cnt_total; i += 256) {
        int2 pr = sStage[i];
        int bin = pr.y >> PA_SHIFT;
        pairs[sGB[bin] + (i - (sScan[bin] - sCnt[bin]))] = pr;
    }
}

__global__ __launch_bounds__(512) void placeB_kernel(
    const int2* __restrict__ pairs, const int* __restrict__ bbase,
    const int* __restrict__ bcnt, int* __restrict__ offs,
    int* __restrict__ csr, int N, int nbins)
{
    __shared__ int sCnt[512], sScan[512], sFill[512];
    const int bin = blockIdx.x;
    const int t = threadIdx.x;
    const int n0 = bin << PA_SHIFT;
    const int n1 = min(n0 + 512, N);
    const int len = n1 - n0;
    const int rb  = bbase[bin];
    const int cnt = bcnt[bin];
    const int2* gp = pairs + rb;

    sCnt[t] = 0; sFill[t] = 0;
    __syncthreads();
    for (int i = t; i < cnt; i += 512)
        atomicAdd(&sCnt[gp[i].y - n0], 1);
    __syncthreads();
    sScan[t] = sCnt[t];
    __syncthreads();
    for (int o = 1; o < 512; o <<= 1) {
        int v = (t >= o) ? sScan[t - o] : 0;
        __syncthreads();
        sScan[t] += v;
        __syncthreads();
    }
    const int excl = sScan[t] - sCnt[t];
    if (t < len) offs[n0 + t] = rb + excl;
    if (bin == nbins - 1 && t == 0) offs[N] = rb + cnt;
    sScan[t] = excl;
    __syncthreads();

    for (int i = t; i < cnt; i += 512) {
        int2 pr = gp[i];
        int ln = pr.y - n0;
        int p = atomicAdd(&sFill[ln], 1);
        csr[rb + sScan[ln] + p] = pr.x;
    }
}

// ---------------------------- fused aggregation -----------------------------
__global__ __launch_bounds__(256) void agg3_kernel(
    const unsigned short* __restrict__ xtR,
    const unsigned short* __restrict__ xt3,
    const int* __restrict__ csr, const int* __restrict__ offs,
    unsigned short* __restrict__ hout, int N)
{
    int w = threadIdx.x >> 6, lane = threadIdx.x & 63;
    int dst = blockIdx.x * 4 + w;
    if (dst >= N) return;

    const ushort2* r2 = (const ushort2*)xtR;
    ushort2 rv = r2[(size_t)dst * 64 + lane];
    float2 a[8];
    a[0] = make_float2(bf2f(rv.x), bf2f(rv.y));
#pragma unroll
    for (int i = 1; i < 8; ++i) a[i] = make_float2(0.f, 0.f);

    const ushort2* x2 = (const ushort2*)xt3;
    const int beg = offs[dst], end = offs[dst + 1];
    int k = beg;
    for (; k + 8 <= end; k += 8) {
        int s[8];
#pragma unroll
        for (int i = 0; i < 8; ++i) s[i] = csr[k + i];
        ushort2 v[8];
#pragma unroll
        for (int i = 0; i < 8; ++i) v[i] = x2[(size_t)s[i] * 64 + lane];
#pragma unroll
        for (int i = 0; i < 8; ++i) {
            a[i].x += bf2f(v[i].x); a[i].y += bf2f(v[i].y);
        }
    }
    for (; k + 2 <= end; k += 2) {
        int s0 = csr[k], s1 = csr[k + 1];
        ushort2 v0 = x2[(size_t)s0 * 64 + lane];
        ushort2 v1 = x2[(size_t)s1 * 64 + lane];
        a[0].x += bf2f(v0.x); a[0].y += bf2f(v0.y);
        a[1].x += bf2f(v1.x); a[1].y += bf2f(v1.y);
    }
    for (; k < end; ++k) {
        int s0 = csr[k];
        ushort2 v0 = x2[(size_t)s0 * 64 + lane];
        a[0].x += bf2f(v0.x); a[0].y += bf2f(v0.y);
    }
    float sx = ((a[0].x + a[1].x) + (a[2].x + a[3].x)) +
               ((a[4].x + a[5].x) + (a[6].x + a[7].x));
    float sy = ((a[0].y + a[1].y) + (a[2].y + a[3].y)) +
               ((a[4].y + a[5].y) + (a[6].y + a[7].y));
    ushort2 o;
    o.x = (unsigned short)f2bf(fmaxf(sx, 0.f));
    o.y = (unsigned short)f2bf(fmaxf(sy, 0.f));
    ((ushort2*)hout)[(size_t)dst * 64 + lane] = o;
}

// ---------------------------- pool / counts / decoder ----------------------
__global__ __launch_bounds__(256) void pool_kernel(
    const unsigned short* __restrict__ in, const int* __restrict__ batch,
    float* __restrict__ gsum, int N)
{
    int t = threadIdx.x;
    int j = t & 127, half = t >> 7;
    int n0 = blockIdx.x * 64 + half * 32;
    float acc = 0.f; int cur = -1;
    for (int i = 0; i < 32; ++i) {
        int n = n0 + i;
        if (n >= N) break;
        int g = batch[n];
        if (g != cur) {
            if (cur >= 0) atomicAdd(&gsum[cur * 128 + j], acc);
            cur = g; acc = 0.f;
        }
        acc += bf2f(in[(size_t)n * 128 + j]);   // h already relu'd
    }
    if (cur >= 0) atomicAdd(&gsum[cur * 128 + j], acc);
}

__global__ __launch_bounds__(256) void cnt_kernel(
    const int* __restrict__ batch, float* __restrict__ gcnt, int N)
{
    __shared__ float lh[64];
    int t = threadIdx.x;
    if (t < 64) lh[t] = 0.f;
    __syncthreads();
    int i = blockIdx.x * 256 + t;
    if (i < N) atomicAdd(&lh[batch[i]], 1.0f);
    __syncthreads();
    if (t < 64 && lh[t] != 0.f) atomicAdd(&gcnt[t], lh[t]);
}

__global__ __launch_bounds__(128) void dec_kernel(
    const float* __restrict__ gsum, const float* __restrict__ gcnt,
    const float* __restrict__ W1, const float* __restrict__ B1,
    const float* __restrict__ W2, const float* __restrict__ B2,
    float* __restrict__ out)
{
    __shared__ float sg[128];
    __shared__ float sh[128];
    int t = threadIdx.x, b = blockIdx.x;
    float cinv = 1.0f / fmaxf(gcnt[b], 1.0f);
    sg[t] = gsum[b * 128 + t] * cinv;
    __syncthreads();
    float acc = B1[t];
    for (int f = 0; f < 128; ++f) acc += sg[f] * W1[f * 128 + t];
    sh[t] = fmaxf(acc, 0.f) * W2[t];
    __syncthreads();
    for (int o = 64; o > 0; o >>= 1) {
        if (t < o) sh[t] += sh[t + o];
        __syncthreads();
    }
    if (t == 0) out[b] = sh[0] + B2[0];
}

// ---------------------------- launch ---------------------------------------
extern "C" void kernel_launch(void* const* d_in, const int* in_sizes, int n_in,
                              void* d_out, int out_size, void* d_ws, size_t ws_size,
                              hipStream_t stream)
{
    const float* x    = (const float*)d_in[0];
    const int*   e0   = (const int*)d_in[1];
    const int*   e1   = (const int*)d_in[2];
    const int*   e2   = (const int*)d_in[3];
    const int*   bat  = (const int*)d_in[4];
    const float* Wemb = (const float*)d_in[5];
    const float* qkv  = (const float*)d_in[6];
    const float* fw1  = (const float*)d_in[7];
    const float* fb1  = (const float*)d_in[8];
    const float* fw2  = (const float*)d_in[9];
    const float* fb2  = (const float*)d_in[10];
    const float* mw1  = (const float*)d_in[11];
    const float* mb1  = (const float*)d_in[12];
    const float* mw2  = (const float*)d_in[13];
    const float* mb2  = (const float*)d_in[14];
    const int N = in_sizes[0] / 112;
    const int E = in_sizes[1] / 2;
    float* outp = (float*)d_out;
    (void)n_in; (void)out_size; (void)ws_size;

    char* w = (char*)d_ws;
    auto alloc = [&](size_t bytes) {
        char* p = w; w += (bytes + 255) & ~(size_t)255; return p;
    };
    unsigned short* h0    = (unsigned short*)alloc((size_t)N * 128 * 2);
    unsigned short* h1    = (unsigned short*)alloc((size_t)N * 128 * 2);
    unsigned short* xtR   = (unsigned short*)alloc((size_t)N * 128 * 2);
    unsigned short* xt3   = (unsigned short*)alloc((size_t)3 * N * 128 * 2);
    unsigned short* wpack = (unsigned short*)alloc(8 * 10 * 64 * 8 * 2);
    int*   csr   = (int*)alloc((size_t)3 * E * 4);
    int*   offs  = (int*)alloc((size_t)(N + 1) * 4);
    int*   bcnt  = (int*)alloc(PA_MAXB * 4);
    int*   bbase = (int*)alloc(PA_MAXB * 4);
    int*   gres  = (int*)alloc(PA_MAXB * 4);
    float* gsum  = (float*)alloc(64 * 128 * 4);
    float* gcnt  = (float*)alloc(64 * 4);
    // pairs (3*E*8 = 19.2 MB) aliased into xtR (25.6 MB): consumed by placeB
    // before attn2 first writes xtR (stream-ordered).
    int2* pairs = (int2*)xtR;

    const int nbins = (N + (1 << PA_SHIFT) - 1) >> PA_SHIFT;

    hipMemsetAsync(bcnt, 0, PA_MAXB * 4, stream);
    hipMemsetAsync(gres, 0, PA_MAXB * 4, stream);
    hipMemsetAsync(gsum, 0, 64 * 128 * 4, stream);
    hipMemsetAsync(gcnt, 0, 64 * 4, stream);

    wprep_kernel<<<8, 64, 0, stream>>>(qkv, fw1, fw2, wpack);
    enc_kernel<<<(N + 7) / 8, 128, 0, stream>>>(x, Wemb, h0, N);

    histB_kernel<<<dim3((E + 256 * HB_K - 1) / (256 * HB_K), 3), 256, 0, stream>>>(
        e0, e1, e2, bcnt, E);
    bscan_kernel<<<1, 256, 0, stream>>>(bcnt, bbase);
    placeA_kernel<<<dim3((E + PA_CHUNK - 1) / PA_CHUNK, 3), 256, 0, stream>>>(
        e0, e1, e2, bbase, gres, pairs, E, N);
    placeB_kernel<<<nbins, 512, 0, stream>>>(pairs, bbase, bcnt, offs, csr, N, nbins);

    const int ATT_GRID = 1024;
    auto run_layer = [&](const unsigned short* lin, unsigned short* lout, int l) {
        attn2_kernel<<<ATT_GRID, 256, 0, stream>>>(
            lin, xtR, xt3, wpack, fb1, fb2, l * 4 + 0, l * 4 + 1, N);
        attn2_kernel<<<ATT_GRID, 256, 0, stream>>>(
            lin, xt3 + (size_t)N * 128, xt3 + (size_t)2 * N * 128,
            wpack, fb1, fb2, l * 4 + 2, l * 4 + 3, N);
        agg3_kernel<<<(N + 3) / 4, 256, 0, stream>>>(xtR, xt3, csr, offs, lout, N);
    };
    run_layer(h0, h1, 0);
    run_layer(h1, h0, 1);

    pool_kernel<<<(N + 63) / 64, 256, 0, stream>>>(h0, bat, gsum, N);
    cnt_kernel<<<(N + 255) / 256, 256, 0, stream>>>(bat, gcnt, N);
    dec_kernel<<<64, 128, 0, stream>>>(gsum, gcnt, mw1, mb1, mw2, mb2, outp);
}

// Round 7
// 604.230 us; speedup vs baseline: 5.3179x; 1.0683x over previous
//
#include <hip/hip_runtime.h>
#include <hip/hip_bf16.h>
#include <cstdint>
#include <cstddef>

// ---------------------------------------------------------------------------
// RGNN_53755810677120 — round 7.
//   attn2:  transposed-operand MFMA pipeline — all LDS bounces are packed
//           b64 writes / b128 reads; in-lane softmax (no shuffles).
//   agg3:   8 dst/block, 32 lanes/row, uint2 gathers (half the addresses).
//   rest:   as round 6.
// ---------------------------------------------------------------------------

typedef __attribute__((ext_vector_type(8))) short bf16x8;
typedef __attribute__((ext_vector_type(4))) float f32x4;

__device__ inline short f2bf(float f) {
    union { float f; unsigned u; } v; v.f = f;
    unsigned r = (v.u + 0x7FFFu + ((v.u >> 16) & 1u)) >> 16;   // RNE
    return (short)r;
}
__device__ inline float bf2f(unsigned short b) {
    union { unsigned u; float f; } v; v.u = ((unsigned)b) << 16;
    return v.f;
}
__device__ inline float bflo(unsigned u) {
    union { unsigned u; float f; } v; v.u = u << 16; return v.f;
}
__device__ inline float bfhi(unsigned u) {
    union { unsigned u; float f; } v; v.u = u & 0xffff0000u; return v.f;
}
__device__ inline unsigned pk2(float a, float b) {
    return (unsigned)(unsigned short)f2bf(a) |
           ((unsigned)(unsigned short)f2bf(b) << 16);
}

// ---------------------------- weight prep ----------------------------------
// wpack[((pi*10 + f)*64 + lane)*8 + j]; lane map serves as BOTH A- and B-frag.
__global__ __launch_bounds__(64) void wprep_kernel(
    const float* __restrict__ qkv, const float* __restrict__ fw1,
    const float* __restrict__ fw2, unsigned short* __restrict__ wpack)
{
    const int pi = blockIdx.x;
    const int lane = threadIdx.x;
    const int q = lane >> 4, m = lane & 15;
    const float* Wq = qkv + (size_t)pi * 32 * 96;
    const float* W1 = fw1 + (size_t)pi * 32 * 32;
    const float* W2 = fw2 + (size_t)pi * 32 * 32;
    unsigned short* dst = wpack + (size_t)pi * 10 * 64 * 8;
#pragma unroll
    for (int ci = 0; ci < 6; ++ci)
#pragma unroll
        for (int j = 0; j < 8; ++j)
            dst[(ci * 64 + lane) * 8 + j] =
                (unsigned short)f2bf(Wq[(q * 8 + j) * 96 + ci * 16 + m]);
#pragma unroll
    for (int t = 0; t < 2; ++t)
#pragma unroll
        for (int j = 0; j < 8; ++j) {
            dst[((6 + t) * 64 + lane) * 8 + j] =
                (unsigned short)f2bf(W1[(q * 8 + j) * 32 + t * 16 + m]);
            dst[((8 + t) * 64 + lane) * 8 + j] =
                (unsigned short)f2bf(W2[(q * 8 + j) * 32 + t * 16 + m]);
        }
}

// ---------------------------- encoder --------------------------------------
__global__ __launch_bounds__(128) void enc_kernel(
    const float* __restrict__ x, const float* __restrict__ Wemb,
    unsigned short* __restrict__ h, int N)
{
    __shared__ float sxr[8 * 112];
    __shared__ float spe[128];
    __shared__ float sW[1024];
    const int t = threadIdx.x;
    const int n0 = blockIdx.x * 8;

    {
        int s = t >> 5, f = t & 31;
        int i2 = f >> 1;
        float div = __expf(-(float)(2 * i2) * (logf(10000.0f) / 32.0f));
        float ang = (float)s * div;
        spe[t] = (f & 1) ? cosf(ang) : sinf(ang);
    }
    for (int i = t; i < 1024; i += 128) sW[i] = Wemb[i];
    for (int i = t; i < 8 * 112; i += 128) {
        int n = n0 + i / 112;
        sxr[i] = (n < N) ? x[(size_t)n0 * 112 + i] : 0.f;
    }
    __syncthreads();

    const int ts = t >> 5, c = t & 31;
    const int offs_[4] = {0, 16, 48, 80};
    const int lens_[4] = {16, 32, 32, 32};
    const int off = offs_[ts], len = lens_[ts];

    float acc[8];
#pragma unroll
    for (int i = 0; i < 8; ++i) acc[i] = 0.f;
    float pw = 0.f;
    for (int f = 0; f < 32; ++f) {
        float wv = sW[f * 32 + c];
        float pv = spe[ts * 32 + f];
        pw += pv * wv;
        if (f < len) {
#pragma unroll
            for (int i = 0; i < 8; ++i) acc[i] += sxr[i * 112 + off + f] * wv;
        }
    }
#pragma unroll
    for (int i = 0; i < 8; ++i) {
        int n = n0 + i;
        if (n < N)
            h[(size_t)n * 128 + ts * 32 + c] = (unsigned short)f2bf(acc[i] + pw);
    }
}

// ---------------------------- dual-set MFMA attention -----------------------
// Per-wave LDS (5376 B): Qb[16][40] (also Y), Kb[16][40] (also Z),
// VT[32][24] (V^T), Pb[16][40] (P, invalid key slots stay zero).
// All stage tensors produced in "transposed C-layout" so each lane holds
// contiguous 4-element row runs -> packed b64 writes, b128 reads, no shfl.
#define ATT_WAVES 4
#define WLDS 5376

__global__ __launch_bounds__(256, 2) void attn2_kernel(
    const unsigned short* __restrict__ in,
    unsigned short* __restrict__ out0, unsigned short* __restrict__ out1,
    const unsigned short* __restrict__ wpack,
    const float* __restrict__ fb1, const float* __restrict__ fb2,
    int pi0, int pi1, int N)
{
    __shared__ char smem[ATT_WAVES * WLDS];
    const int lane = threadIdx.x & 63;
    const int wave = threadIdx.x >> 6;
    const int q = lane >> 4;
    const int m = lane & 15;

    char* wb = smem + wave * WLDS;
    short* Qb = (short*)(wb);          // [16][40]  Q[nt][hid]   (also Y)
    short* Kb = (short*)(wb + 1280);   // [16][40]  K[nt][hid]   (also Z)
    short* VT = (short*)(wb + 2560);   // [32][24]  V^T[hid][nt]
    short* Pb = (short*)(wb + 4096);   // [16][40]  P[query][key0..15]

    // zero Pb once: each tile rewrites only its fixed valid slots
    {
        int* p32 = (int*)Pb;
        for (int i = lane; i < 320; i += 64) p32[i] = 0;
    }

    const f32x4 zf = {0.f, 0.f, 0.f, 0.f};

    // ---- weights: coalesced 16B frag loads; per-lane biases (hid-indexed) --
    bf16x8 wqkv[2][6], w1f[2][2], w2f[2][2];
    float b1r[2][2][4], b2r[2][2][4];
    const int pis[2] = {pi0, pi1};
#pragma unroll
    for (int s = 0; s < 2; ++s) {
        const unsigned short* wp = wpack + ((size_t)pis[s] * 10 * 64 + lane) * 8;
#pragma unroll
        for (int ci = 0; ci < 6; ++ci)
            wqkv[s][ci] = *(const bf16x8*)(wp + ci * 64 * 8);
#pragma unroll
        for (int t = 0; t < 2; ++t) {
            w1f[s][t] = *(const bf16x8*)(wp + (6 + t) * 64 * 8);
            w2f[s][t] = *(const bf16x8*)(wp + (8 + t) * 64 * 8);
#pragma unroll
            for (int r = 0; r < 4; ++r) {
                b1r[s][t][r] = fb1[pis[s] * 32 + 16 * t + q * 4 + r];
                b2r[s][t][r] = fb2[pis[s] * 32 + 16 * t + q * 4 + r];
            }
        }
    }

    const int ntiles = (N + 3) >> 2;
    for (int tile = blockIdx.x * ATT_WAVES + wave; tile < ntiles;
         tile += gridDim.x * ATT_WAVES) {
        const int n0 = tile * 4;
        const int node_m = n0 + (m >> 2);

        bf16x8 ax = {0, 0, 0, 0, 0, 0, 0, 0};
        if (node_m < N)
            ax = *(const bf16x8*)(in + (size_t)n0 * 128 + m * 32 + q * 8);

#pragma unroll
        for (int s = 0; s < 2; ++s) {
            // ---- qkv: Q,K transposed-operand (row runs in-lane); V direct --
            f32x4 aQ[2], aK[2], aV[2];
#pragma unroll
            for (int t = 0; t < 2; ++t) {
                aQ[t] = __builtin_amdgcn_mfma_f32_16x16x32_bf16(wqkv[s][t],     ax, zf, 0, 0, 0);
                aK[t] = __builtin_amdgcn_mfma_f32_16x16x32_bf16(wqkv[s][2 + t], ax, zf, 0, 0, 0);
                aV[t] = __builtin_amdgcn_mfma_f32_16x16x32_bf16(ax, wqkv[s][4 + t], zf, 0, 0, 0);
            }
#pragma unroll
            for (int t = 0; t < 2; ++t) {
                uint2 dq, dk, dv;
                dq.x = pk2(aQ[t][0], aQ[t][1]); dq.y = pk2(aQ[t][2], aQ[t][3]);
                dk.x = pk2(aK[t][0], aK[t][1]); dk.y = pk2(aK[t][2], aK[t][3]);
                dv.x = pk2(aV[t][0], aV[t][1]); dv.y = pk2(aV[t][2], aV[t][3]);
                *(uint2*)(Qb + m * 40 + 16 * t + q * 4) = dq;   // Q[m][16t+4q..+3]
                *(uint2*)(Kb + m * 40 + 16 * t + q * 4) = dk;
                *(uint2*)(VT + (16 * t + m) * 24 + q * 4) = dv; // V^T[16t+m][4q..+3]
            }

            // ---- scores: S^T = K·Q^T -> lane holds S[m][q*4+r] ----
            bf16x8 aKf = *(const bf16x8*)(Kb + m * 40 + q * 8);
            bf16x8 bQf = *(const bf16x8*)(Qb + m * 40 + q * 8);
            f32x4 st = __builtin_amdgcn_mfma_f32_16x16x32_bf16(aKf, bQf, zf, 0, 0, 0);

            // ---- softmax fully in-lane (valid lane: q == m>>2) ----
            float v0 = st[0] * 0.1767766952966369f;
            float v1 = st[1] * 0.1767766952966369f;
            float v2 = st[2] * 0.1767766952966369f;
            float v3 = st[3] * 0.1767766952966369f;
            float mx = fmaxf(fmaxf(v0, v1), fmaxf(v2, v3));
            float e0 = __expf(v0 - mx), e1 = __expf(v1 - mx);
            float e2 = __expf(v2 - mx), e3 = __expf(v3 - mx);
            float inv = 1.0f / (e0 + e1 + e2 + e3);
            if (q == (m >> 2)) {
                uint2 dp;
                dp.x = pk2(e0 * inv, e1 * inv);
                dp.y = pk2(e2 * inv, e3 * inv);
                *(uint2*)(Pb + m * 40 + q * 4) = dp;   // keys (m>>2)*4..+3
            }

            // ---- PV: Y^T = V^T · P^T -> lane holds Y[m][16t+4q+r] ----
            f32x4 y[2];
#pragma unroll
            for (int t = 0; t < 2; ++t) {
                bf16x8 aVf = {0, 0, 0, 0, 0, 0, 0, 0};
                bf16x8 bPf = {0, 0, 0, 0, 0, 0, 0, 0};
                if (q < 2) {
                    aVf = *(const bf16x8*)(VT + (16 * t + m) * 24 + q * 8);
                    bPf = *(const bf16x8*)(Pb + m * 40 + q * 8);
                }
                y[t] = __builtin_amdgcn_mfma_f32_16x16x32_bf16(aVf, bPf, zf, 0, 0, 0);
            }
#pragma unroll
            for (int t = 0; t < 2; ++t) {
                uint2 dy;
                dy.x = pk2(y[t][0], y[t][1]); dy.y = pk2(y[t][2], y[t][3]);
                *(uint2*)(Qb + m * 40 + 16 * t + q * 4) = dy;   // Y into Qb
            }

            // ---- ffn1: Z^T = W1^T · Y^T ----
            bf16x8 bY = *(const bf16x8*)(Qb + m * 40 + q * 8);
            f32x4 z1[2];
#pragma unroll
            for (int t = 0; t < 2; ++t)
                z1[t] = __builtin_amdgcn_mfma_f32_16x16x32_bf16(w1f[s][t], bY, zf, 0, 0, 0);
#pragma unroll
            for (int t = 0; t < 2; ++t) {
                uint2 dz;
                dz.x = pk2(fmaxf(z1[t][0] + b1r[s][t][0], 0.f),
                           fmaxf(z1[t][1] + b1r[s][t][1], 0.f));
                dz.y = pk2(fmaxf(z1[t][2] + b1r[s][t][2], 0.f),
                           fmaxf(z1[t][3] + b1r[s][t][3], 0.f));
                *(uint2*)(Kb + m * 40 + 16 * t + q * 4) = dz;   // Z into Kb
            }

            // ---- ffn2: O^T = W2^T · Z^T ----
            bf16x8 bZ = *(const bf16x8*)(Kb + m * 40 + q * 8);
            f32x4 o[2];
#pragma unroll
            for (int t = 0; t < 2; ++t)
                o[t] = __builtin_amdgcn_mfma_f32_16x16x32_bf16(w2f[s][t], bZ, zf, 0, 0, 0);

            // ---- epilogue: residual + bias -> packed uint2 stores ----
            if (node_m < N) {
                unsigned short* op = s ? out1 : out0;
#pragma unroll
                for (int t = 0; t < 2; ++t) {
                    uint2 dd;
                    dd.x = pk2(y[t][0] + o[t][0] + b2r[s][t][0],
                               y[t][1] + o[t][1] + b2r[s][t][1]);
                    dd.y = pk2(y[t][2] + o[t][2] + b2r[s][t][2],
                               y[t][3] + o[t][3] + b2r[s][t][3]);
                    *(uint2*)(op + (size_t)n0 * 128 + m * 32 + 16 * t + q * 4) = dd;
                }
            }
        }
    }
}

// ---------------------------- fused CSR build -------------------------------
#define PA_CHUNK 4096
#define PA_SHIFT 9
#define PA_MAXB  256
#define HB_K     16

__global__ __launch_bounds__(256) void histB_kernel(
    const int* __restrict__ e0, const int* __restrict__ e1,
    const int* __restrict__ e2, int* __restrict__ bcnt, int E)
{
    __shared__ int lh[PA_MAXB];
    const int lab = blockIdx.y;
    const int* e = (lab == 0) ? e0 : (lab == 1) ? e1 : e2;
    const int t = threadIdx.x;
    for (int i = t; i < PA_MAXB; i += 256) lh[i] = 0;
    __syncthreads();
    const int base = blockIdx.x * 256 * HB_K;
#pragma unroll
    for (int k = 0; k < HB_K; ++k) {
        int i = base + k * 256 + t;
        if (i < E) atomicAdd(&lh[e[E + i] >> PA_SHIFT], 1);
    }
    __syncthreads();
    for (int i = t; i < PA_MAXB; i += 256)
        if (lh[i]) atomicAdd(&bcnt[i], lh[i]);
}

__global__ __launch_bounds__(256) void bscan_kernel(
    const int* __restrict__ bcnt, int* __restrict__ bbase)
{
    __shared__ int sd[PA_MAXB];
    const int t = threadIdx.x;
    sd[t] = bcnt[t];
    __syncthreads();
    int own = sd[t];
    for (int o = 1; o < 256; o <<= 1) {
        int v = (t >= o) ? sd[t - o] : 0;
        __syncthreads();
        sd[t] += v;
        __syncthreads();
    }
    bbase[t] = sd[t] - own;
}

__global__ __launch_bounds__(256) void placeA_kernel(
    const int* __restrict__ e0, const int* __restrict__ e1, const int* __restrict__ e2,
    const int* __restrict__ bbase, int* __restrict__ gres,
    int2* __restrict__ pairs, int E, int N)
{
    __shared__ int2 sStage[PA_CHUNK];
    __shared__ int sCnt[PA_MAXB], sScan[PA_MAXB], sCur[PA_MAXB], sGB[PA_MAXB];

    const int lab = blockIdx.y;
    const int t = threadIdx.x;
    const int base = blockIdx.x * PA_CHUNK;
    const int* e = (lab == 0) ? e0 : (lab == 1) ? e1 : e2;
    const int srcoff = lab * N;
    const int nbins = (N + (1 << PA_SHIFT) - 1) >> PA_SHIFT;

    for (int i = t; i < PA_MAXB; i += 256) { sCnt[i] = 0; sCur[i] = 0; }
    __syncthreads();

    int msrc[16], mdst[16];
    const int cnt_total = min(PA_CHUNK, E - base);
#pragma unroll
    for (int k = 0; k < 16; ++k) {
        int i = base + k * 256 + t;
        if (i < E) {
            msrc[k] = srcoff + e[i];
            int d = e[E + i];
            mdst[k] = d;
            atomicAdd(&sCnt[d >> PA_SHIFT], 1);
        } else mdst[k] = -1;
    }
    __syncthreads();

    sScan[t] = sCnt[t];
    __syncthreads();
    for (int o = 1; o < 256; o <<= 1) {
        int v = (t >= o) ? sScan[t - o] : 0;
        __syncthreads();
        sScan[t] += v;
        __syncthreads();
    }
    if (t < nbins && sCnt[t] > 0)
        sGB[t] = bbase[t] + atomicAdd(&gres[t], sCnt[t]);
    __syncthreads();

#pragma unroll
    for (int k = 0; k < 16; ++k) {
        if (mdst[k] >= 0) {
            int bin = mdst[k] >> PA_SHIFT;
            int r = atomicAdd(&sCur[bin], 1);
            sStage[(sScan[bin] - sCnt[bin]) + r] = make_int2(msrc[k], mdst[k]);
        }
    }
    __syncthreads();

    for (int i = t; i < cnt_total; i += 256) {
        int2 pr = sStage[i];
        int bin = pr.y >> PA_SHIFT;
        pairs[sGB[bin] + (i - (sScan[bin] - sCnt[bin]))] = pr;
    }
}

__global__ __launch_bounds__(512) void placeB_kernel(
    const int2* __restrict__ pairs, const int* __restrict__ bbase,
    const int* __restrict__ bcnt, int* __restrict__ offs,
    int* __restrict__ csr, int N, int nbins)
{
    __shared__ int sCnt[512], sScan[512], sFill[512];
    const int bin = blockIdx.x;
    const int t = threadIdx.x;
    const int n0 = bin << PA_SHIFT;
    const int n1 = min(n0 + 512, N);
    const int len = n1 - n0;
    const int rb  = bbase[bin];
    const int cnt = bcnt[bin];
    const int2* gp = pairs + rb;

    sCnt[t] = 0; sFill[t] = 0;
    __syncthreads();
    for (int i = t; i < cnt; i += 512)
        atomicAdd(&sCnt[gp[i].y - n0], 1);
    __syncthreads();
    sScan[t] = sCnt[t];
    __syncthreads();
    for (int o = 1; o < 512; o <<= 1) {
        int v = (t >= o) ? sScan[t - o] : 0;
        __syncthreads();
        sScan[t] += v;
        __syncthreads();
    }
    const int excl = sScan[t] - sCnt[t];
    if (t < len) offs[n0 + t] = rb + excl;
    if (bin == nbins - 1 && t == 0) offs[N] = rb + cnt;
    sScan[t] = excl;
    __syncthreads();

    for (int i = t; i < cnt; i += 512) {
        int2 pr = gp[i];
        int ln = pr.y - n0;
        int p = atomicAdd(&sFill[ln], 1);
        csr[rb + sScan[ln] + p] = pr.x;
    }
}

// ---------------------------- fused aggregation -----------------------------
// 8 dst/block; each dst handled by 32 lanes with uint2 (8B) gathers.
__global__ __launch_bounds__(256) void agg3_kernel(
    const unsigned short* __restrict__ xtR,
    const unsigned short* __restrict__ xt3,
    const int* __restrict__ csr, const int* __restrict__ offs,
    unsigned short* __restrict__ hout, int N)
{
    const int sub = threadIdx.x >> 5;
    const int l32 = threadIdx.x & 31;
    const int dst = blockIdx.x * 8 + sub;
    if (dst >= N) return;

    const uint2* x4 = (const uint2*)xt3;
    uint2 rv = ((const uint2*)xtR)[(size_t)dst * 32 + l32];
    float4 a[8];
    a[0] = make_float4(bflo(rv.x), bfhi(rv.x), bflo(rv.y), bfhi(rv.y));
#pragma unroll
    for (int i = 1; i < 8; ++i) a[i] = make_float4(0.f, 0.f, 0.f, 0.f);

    const int beg = offs[dst], end = offs[dst + 1];
    int k = beg;
    for (; k + 8 <= end; k += 8) {
        int s[8];
#pragma unroll
        for (int i = 0; i < 8; ++i) s[i] = csr[k + i];
        uint2 v[8];
#pragma unroll
        for (int i = 0; i < 8; ++i) v[i] = x4[(size_t)s[i] * 32 + l32];
#pragma unroll
        for (int i = 0; i < 8; ++i) {
            a[i].x += bflo(v[i].x); a[i].y += bfhi(v[i].x);
            a[i].z += bflo(v[i].y); a[i].w += bfhi(v[i].y);
        }
    }
    for (; k < end; ++k) {
        uint2 v = x4[(size_t)csr[k] * 32 + l32];
        a[0].x += bflo(v.x); a[0].y += bfhi(v.x);
        a[0].z += bflo(v.y); a[0].w += bfhi(v.y);
    }
    float sx = ((a[0].x + a[1].x) + (a[2].x + a[3].x)) +
               ((a[4].x + a[5].x) + (a[6].x + a[7].x));
    float sy = ((a[0].y + a[1].y) + (a[2].y + a[3].y)) +
               ((a[4].y + a[5].y) + (a[6].y + a[7].y));
    float sz = ((a[0].z + a[1].z) + (a[2].z + a[3].z)) +
               ((a[4].z + a[5].z) + (a[6].z + a[7].z));
    float sw = ((a[0].w + a[1].w) + (a[2].w + a[3].w)) +
               ((a[4].w + a[5].w) + (a[6].w + a[7].w));
    uint2 o;
    o.x = pk2(fmaxf(sx, 0.f), fmaxf(sy, 0.f));
    o.y = pk2(fmaxf(sz, 0.f), fmaxf(sw, 0.f));
    ((uint2*)hout)[(size_t)dst * 32 + l32] = o;
}

// ---------------------------- pool / counts / decoder ----------------------
__global__ __launch_bounds__(256) void pool_kernel(
    const unsigned short* __restrict__ in, const int* __restrict__ batch,
    float* __restrict__ gsum, int N)
{
    int t = threadIdx.x;
    int j = t & 127, half = t >> 7;
    int n0 = blockIdx.x * 64 + half * 32;
    float acc = 0.f; int cur = -1;
    for (int i = 0; i < 32; ++i) {
        int n = n0 + i;
        if (n >= N) break;
        int g = batch[n];
        if (g != cur) {
            if (cur >= 0) atomicAdd(&gsum[cur * 128 + j], acc);
            cur = g; acc = 0.f;
        }
        acc += bf2f(in[(size_t)n * 128 + j]);   // h already relu'd
    }
    if (cur >= 0) atomicAdd(&gsum[cur * 128 + j], acc);
}

__global__ __launch_bounds__(256) void cnt_kernel(
    const int* __restrict__ batch, float* __restrict__ gcnt, int N)
{
    __shared__ float lh[64];
    int t = threadIdx.x;
    if (t < 64) lh[t] = 0.f;
    __syncthreads();
    int i = blockIdx.x * 256 + t;
    if (i < N) atomicAdd(&lh[batch[i]], 1.0f);
    __syncthreads();
    if (t < 64 && lh[t] != 0.f) atomicAdd(&gcnt[t], lh[t]);
}

__global__ __launch_bounds__(128) void dec_kernel(
    const float* __restrict__ gsum, const float* __restrict__ gcnt,
    const float* __restrict__ W1, const float* __restrict__ B1,
    const float* __restrict__ W2, const float* __restrict__ B2,
    float* __restrict__ out)
{
    __shared__ float sg[128];
    __shared__ float sh[128];
    int t = threadIdx.x, b = blockIdx.x;
    float cinv = 1.0f / fmaxf(gcnt[b], 1.0f);
    sg[t] = gsum[b * 128 + t] * cinv;
    __syncthreads();
    float acc = B1[t];
    for (int f = 0; f < 128; ++f) acc += sg[f] * W1[f * 128 + t];
    sh[t] = fmaxf(acc, 0.f) * W2[t];
    __syncthreads();
    for (int o = 64; o > 0; o >>= 1) {
        if (t < o) sh[t] += sh[t + o];
        __syncthreads();
    }
    if (t == 0) out[b] = sh[0] + B2[0];
}

// ---------------------------- launch ---------------------------------------
extern "C" void kernel_launch(void* const* d_in, const int* in_sizes, int n_in,
                              void* d_out, int out_size, void* d_ws, size_t ws_size,
                              hipStream_t stream)
{
    const float* x    = (const float*)d_in[0];
    const int*   e0   = (const int*)d_in[1];
    const int*   e1   = (const int*)d_in[2];
    const int*   e2   = (const int*)d_in[3];
    const int*   bat  = (const int*)d_in[4];
    const float* Wemb = (const float*)d_in[5];
    const float* qkv  = (const float*)d_in[6];
    const float* fw1  = (const float*)d_in[7];
    const float* fb1  = (const float*)d_in[8];
    const float* fw2  = (const float*)d_in[9];
    const float* fb2  = (const float*)d_in[10];
    const float* mw1  = (const float*)d_in[11];
    const float* mb1  = (const float*)d_in[12];
    const float* mw2  = (const float*)d_in[13];
    const float* mb2  = (const float*)d_in[14];
    const int N = in_sizes[0] / 112;
    const int E = in_sizes[1] / 2;
    float* outp = (float*)d_out;
    (void)n_in; (void)out_size; (void)ws_size;

    char* w = (char*)d_ws;
    auto alloc = [&](size_t bytes) {
        char* p = w; w += (bytes + 255) & ~(size_t)255; return p;
    };
    unsigned short* h0    = (unsigned short*)alloc((size_t)N * 128 * 2);
    unsigned short* h1    = (unsigned short*)alloc((size_t)N * 128 * 2);
    unsigned short* xtR   = (unsigned short*)alloc((size_t)N * 128 * 2);
    unsigned short* xt3   = (unsigned short*)alloc((size_t)3 * N * 128 * 2);
    unsigned short* wpack = (unsigned short*)alloc(8 * 10 * 64 * 8 * 2);
    int*   csr   = (int*)alloc((size_t)3 * E * 4);
    int*   offs  = (int*)alloc((size_t)(N + 1) * 4);
    int*   bcnt  = (int*)alloc(PA_MAXB * 4);
    int*   bbase = (int*)alloc(PA_MAXB * 4);
    int*   gres  = (int*)alloc(PA_MAXB * 4);
    float* gsum  = (float*)alloc(64 * 128 * 4);
    float* gcnt  = (float*)alloc(64 * 4);
    // pairs (3*E*8 = 19.2 MB) aliased into xtR (25.6 MB): consumed by placeB
    // before attn2 first writes xtR (stream-ordered).
    int2* pairs = (int2*)xtR;

    const int nbins = (N + (1 << PA_SHIFT) - 1) >> PA_SHIFT;

    hipMemsetAsync(bcnt, 0, PA_MAXB * 4, stream);
    hipMemsetAsync(gres, 0, PA_MAXB * 4, stream);
    hipMemsetAsync(gsum, 0, 64 * 128 * 4, stream);
    hipMemsetAsync(gcnt, 0, 64 * 4, stream);

    wprep_kernel<<<8, 64, 0, stream>>>(qkv, fw1, fw2, wpack);
    enc_kernel<<<(N + 7) / 8, 128, 0, stream>>>(x, Wemb, h0, N);

    histB_kernel<<<dim3((E + 256 * HB_K - 1) / (256 * HB_K), 3), 256, 0, stream>>>(
        e0, e1, e2, bcnt, E);
    bscan_kernel<<<1, 256, 0, stream>>>(bcnt, bbase);
    placeA_kernel<<<dim3((E + PA_CHUNK - 1) / PA_CHUNK, 3), 256, 0, stream>>>(
        e0, e1, e2, bbase, gres, pairs, E, N);
    placeB_kernel<<<nbins, 512, 0, stream>>>(pairs, bbase, bcnt, offs, csr, N, nbins);

    const int ATT_GRID = 1024;
    auto run_layer = [&](const unsigned short* lin, unsigned short* lout, int l) {
        attn2_kernel<<<ATT_GRID, 256, 0, stream>>>(
            lin, xtR, xt3, wpack, fb1, fb2, l * 4 + 0, l * 4 + 1, N);
        attn2_kernel<<<ATT_GRID, 256, 0, stream>>>(
            lin, xt3 + (size_t)N * 128, xt3 + (size_t)2 * N * 128,
            wpack, fb1, fb2, l * 4 + 2, l * 4 + 3, N);
        agg3_kernel<<<(N + 7) / 8, 256, 0, stream>>>(xtR, xt3, csr, offs, lout, N);
    };
    run_layer(h0, h1, 0);
    run_layer(h1, h0, 1);

    pool_kernel<<<(N + 63) / 64, 256, 0, stream>>>(h0, bat, gsum, N);
    cnt_kernel<<<(N + 255) / 256, 256, 0, stream>>>(bat, gcnt, N);
    dec_kernel<<<64, 128, 0, stream>>>(gsum, gcnt, mw1, mb1, mw2, mb2, outp);
}

// Round 8
// 578.696 us; speedup vs baseline: 5.5525x; 1.0441x over previous
//
#include <hip/hip_runtime.h>
#include <hip/hip_bf16.h>
#include <cstdint>
#include <cstddef>

// ---------------------------------------------------------------------------
// RGNN_53755810677120 — round 8.
//   attn4:  ONE launch/layer. 4 waves/block = 4 param sets; each block
//           iteration covers an 8-node supertile (2 independent 4-node tile
//           chains per wave, unrolled for ILP). Transposed-operand MFMA
//           pipeline as round 7.
//   agg3:   reverted to round-6 form (ushort2, 4 dst/block, 74% occ).
//   rest:   as round 7.
// ---------------------------------------------------------------------------

typedef __attribute__((ext_vector_type(8))) short bf16x8;
typedef __attribute__((ext_vector_type(4))) float f32x4;

__device__ inline short f2bf(float f) {
    union { float f; unsigned u; } v; v.f = f;
    unsigned r = (v.u + 0x7FFFu + ((v.u >> 16) & 1u)) >> 16;   // RNE
    return (short)r;
}
__device__ inline float bf2f(unsigned short b) {
    union { unsigned u; float f; } v; v.u = ((unsigned)b) << 16;
    return v.f;
}
__device__ inline unsigned pk2(float a, float b) {
    return (unsigned)(unsigned short)f2bf(a) |
           ((unsigned)(unsigned short)f2bf(b) << 16);
}

// ---------------------------- weight prep ----------------------------------
// wpack[((pi*10 + f)*64 + lane)*8 + j]; lane map serves as BOTH A- and B-frag.
__global__ __launch_bounds__(64) void wprep_kernel(
    const float* __restrict__ qkv, const float* __restrict__ fw1,
    const float* __restrict__ fw2, unsigned short* __restrict__ wpack)
{
    const int pi = blockIdx.x;
    const int lane = threadIdx.x;
    const int q = lane >> 4, m = lane & 15;
    const float* Wq = qkv + (size_t)pi * 32 * 96;
    const float* W1 = fw1 + (size_t)pi * 32 * 32;
    const float* W2 = fw2 + (size_t)pi * 32 * 32;
    unsigned short* dst = wpack + (size_t)pi * 10 * 64 * 8;
#pragma unroll
    for (int ci = 0; ci < 6; ++ci)
#pragma unroll
        for (int j = 0; j < 8; ++j)
            dst[(ci * 64 + lane) * 8 + j] =
                (unsigned short)f2bf(Wq[(q * 8 + j) * 96 + ci * 16 + m]);
#pragma unroll
    for (int t = 0; t < 2; ++t)
#pragma unroll
        for (int j = 0; j < 8; ++j) {
            dst[((6 + t) * 64 + lane) * 8 + j] =
                (unsigned short)f2bf(W1[(q * 8 + j) * 32 + t * 16 + m]);
            dst[((8 + t) * 64 + lane) * 8 + j] =
                (unsigned short)f2bf(W2[(q * 8 + j) * 32 + t * 16 + m]);
        }
}

// ---------------------------- encoder --------------------------------------
__global__ __launch_bounds__(128) void enc_kernel(
    const float* __restrict__ x, const float* __restrict__ Wemb,
    unsigned short* __restrict__ h, int N)
{
    __shared__ float sxr[8 * 112];
    __shared__ float spe[128];
    __shared__ float sW[1024];
    const int t = threadIdx.x;
    const int n0 = blockIdx.x * 8;

    {
        int s = t >> 5, f = t & 31;
        int i2 = f >> 1;
        float div = __expf(-(float)(2 * i2) * (logf(10000.0f) / 32.0f));
        float ang = (float)s * div;
        spe[t] = (f & 1) ? cosf(ang) : sinf(ang);
    }
    for (int i = t; i < 1024; i += 128) sW[i] = Wemb[i];
    for (int i = t; i < 8 * 112; i += 128) {
        int n = n0 + i / 112;
        sxr[i] = (n < N) ? x[(size_t)n0 * 112 + i] : 0.f;
    }
    __syncthreads();

    const int ts = t >> 5, c = t & 31;
    const int offs_[4] = {0, 16, 48, 80};
    const int lens_[4] = {16, 32, 32, 32};
    const int off = offs_[ts], len = lens_[ts];

    float acc[8];
#pragma unroll
    for (int i = 0; i < 8; ++i) acc[i] = 0.f;
    float pw = 0.f;
    for (int f = 0; f < 32; ++f) {
        float wv = sW[f * 32 + c];
        float pv = spe[ts * 32 + f];
        pw += pv * wv;
        if (f < len) {
#pragma unroll
            for (int i = 0; i < 8; ++i) acc[i] += sxr[i * 112 + off + f] * wv;
        }
    }
#pragma unroll
    for (int i = 0; i < 8; ++i) {
        int n = n0 + i;
        if (n < N)
            h[(size_t)n * 128 + ts * 32 + c] = (unsigned short)f2bf(acc[i] + pw);
    }
}

// ---------------------------- quad-set MFMA attention -----------------------
// 4 waves/block; wave w applies param set (pibase+w) to the block's 8-node
// supertile = 2 independent 4-node tile chains (unrolled -> ILP 2).
// Per-wave per-tile LDS (5376 B): Qb[16][40] (also Y), Kb[16][40] (also Z),
// VT[32][24] (V^T), Pb[16][40] (invalid key slots stay zero).
#define ATT_WAVES 4
#define WLDS 5376

__global__ __launch_bounds__(256, 2) void attn4_kernel(
    const unsigned short* __restrict__ in,
    unsigned short* __restrict__ outR, unsigned short* __restrict__ out3,
    const unsigned short* __restrict__ wpack,
    const float* __restrict__ fb1, const float* __restrict__ fb2,
    int pibase, int N)
{
    __shared__ char smem[ATT_WAVES * 2 * WLDS];
    const int lane = threadIdx.x & 63;
    const int wave = threadIdx.x >> 6;
    const int q = lane >> 4;
    const int m = lane & 15;

    char* wb0 = smem + wave * (2 * WLDS);

    // zero both tile-buffers' P once (tiles rewrite only their valid slots)
#pragma unroll
    for (int u = 0; u < 2; ++u) {
        int* p32 = (int*)(wb0 + u * WLDS + 4096);
        for (int i = lane; i < 320; i += 64) p32[i] = 0;
    }

    const f32x4 zf = {0.f, 0.f, 0.f, 0.f};
    const int pi = pibase + wave;
    unsigned short* outw = (wave == 0) ? outR
                                       : out3 + (size_t)(wave - 1) * N * 128;

    // ---- weights for this wave's single set: coalesced 16B frag loads ----
    bf16x8 wqkv[6], w1f[2], w2f[2];
    float b1r[2][4], b2r[2][4];
    {
        const unsigned short* wp = wpack + ((size_t)pi * 10 * 64 + lane) * 8;
#pragma unroll
        for (int ci = 0; ci < 6; ++ci)
            wqkv[ci] = *(const bf16x8*)(wp + ci * 64 * 8);
#pragma unroll
        for (int t = 0; t < 2; ++t) {
            w1f[t] = *(const bf16x8*)(wp + (6 + t) * 64 * 8);
            w2f[t] = *(const bf16x8*)(wp + (8 + t) * 64 * 8);
#pragma unroll
            for (int r = 0; r < 4; ++r) {
                b1r[t][r] = fb1[pi * 32 + 16 * t + q * 4 + r];
                b2r[t][r] = fb2[pi * 32 + 16 * t + q * 4 + r];
            }
        }
    }

    const int nsuper = (N + 7) >> 3;
    for (int stile = blockIdx.x; stile < nsuper; stile += gridDim.x) {
        const int n0 = stile * 8;

        // ---- load both tiles' X frags (independent) ----
        bf16x8 ax[2];
#pragma unroll
        for (int u = 0; u < 2; ++u) {
            bf16x8 a = {0, 0, 0, 0, 0, 0, 0, 0};
            int nm = n0 + 4 * u + (m >> 2);
            if (nm < N)
                a = *(const bf16x8*)(in + (size_t)(n0 + 4 * u) * 128 + m * 32 + q * 8);
            ax[u] = a;
        }

        // ---- two independent tile chains (compiler interleaves) ----
#pragma unroll
        for (int u = 0; u < 2; ++u) {
            char* wbu = wb0 + u * WLDS;
            short* Qb = (short*)(wbu);          // [16][40] Q (also Y)
            short* Kb = (short*)(wbu + 1280);   // [16][40] K (also Z)
            short* VT = (short*)(wbu + 2560);   // [32][24] V^T
            short* Pb = (short*)(wbu + 4096);   // [16][40] P

            // ---- qkv: Q,K transposed-operand; V direct ----
            f32x4 aQ[2], aK[2], aV[2];
#pragma unroll
            for (int t = 0; t < 2; ++t) {
                aQ[t] = __builtin_amdgcn_mfma_f32_16x16x32_bf16(wqkv[t],     ax[u], zf, 0, 0, 0);
                aK[t] = __builtin_amdgcn_mfma_f32_16x16x32_bf16(wqkv[2 + t], ax[u], zf, 0, 0, 0);
                aV[t] = __builtin_amdgcn_mfma_f32_16x16x32_bf16(ax[u], wqkv[4 + t], zf, 0, 0, 0);
            }
#pragma unroll
            for (int t = 0; t < 2; ++t) {
                uint2 dq, dk, dv;
                dq.x = pk2(aQ[t][0], aQ[t][1]); dq.y = pk2(aQ[t][2], aQ[t][3]);
                dk.x = pk2(aK[t][0], aK[t][1]); dk.y = pk2(aK[t][2], aK[t][3]);
                dv.x = pk2(aV[t][0], aV[t][1]); dv.y = pk2(aV[t][2], aV[t][3]);
                *(uint2*)(Qb + m * 40 + 16 * t + q * 4) = dq;
                *(uint2*)(Kb + m * 40 + 16 * t + q * 4) = dk;
                *(uint2*)(VT + (16 * t + m) * 24 + q * 4) = dv;
            }

            // ---- scores: S^T = K·Q^T -> lane holds S[m][q*4+r] ----
            bf16x8 aKf = *(const bf16x8*)(Kb + m * 40 + q * 8);
            bf16x8 bQf = *(const bf16x8*)(Qb + m * 40 + q * 8);
            f32x4 st = __builtin_amdgcn_mfma_f32_16x16x32_bf16(aKf, bQf, zf, 0, 0, 0);

            // ---- softmax fully in-lane (valid lane: q == m>>2) ----
            float v0 = st[0] * 0.1767766952966369f;
            float v1 = st[1] * 0.1767766952966369f;
            float v2 = st[2] * 0.1767766952966369f;
            float v3 = st[3] * 0.1767766952966369f;
            float mx = fmaxf(fmaxf(v0, v1), fmaxf(v2, v3));
            float e0 = __expf(v0 - mx), e1 = __expf(v1 - mx);
            float e2 = __expf(v2 - mx), e3 = __expf(v3 - mx);
            float inv = 1.0f / (e0 + e1 + e2 + e3);
            if (q == (m >> 2)) {
                uint2 dp;
                dp.x = pk2(e0 * inv, e1 * inv);
                dp.y = pk2(e2 * inv, e3 * inv);
                *(uint2*)(Pb + m * 40 + q * 4) = dp;
            }

            // ---- PV: Y^T = V^T · P^T ----
            f32x4 y[2];
#pragma unroll
            for (int t = 0; t < 2; ++t) {
                bf16x8 aVf = {0, 0, 0, 0, 0, 0, 0, 0};
                bf16x8 bPf = {0, 0, 0, 0, 0, 0, 0, 0};
                if (q < 2) {
                    aVf = *(const bf16x8*)(VT + (16 * t + m) * 24 + q * 8);
                    bPf = *(const bf16x8*)(Pb + m * 40 + q * 8);
                }
                y[t] = __builtin_amdgcn_mfma_f32_16x16x32_bf16(aVf, bPf, zf, 0, 0, 0);
            }
#pragma unroll
            for (int t = 0; t < 2; ++t) {
                uint2 dy;
                dy.x = pk2(y[t][0], y[t][1]); dy.y = pk2(y[t][2], y[t][3]);
                *(uint2*)(Qb + m * 40 + 16 * t + q * 4) = dy;   // Y into Qb
            }

            // ---- ffn1: Z^T = W1^T · Y^T ----
            bf16x8 bY = *(const bf16x8*)(Qb + m * 40 + q * 8);
            f32x4 z1[2];
#pragma unroll
            for (int t = 0; t < 2; ++t)
                z1[t] = __builtin_amdgcn_mfma_f32_16x16x32_bf16(w1f[t], bY, zf, 0, 0, 0);
#pragma unroll
            for (int t = 0; t < 2; ++t) {
                uint2 dz;
                dz.x = pk2(fmaxf(z1[t][0] + b1r[t][0], 0.f),
                           fmaxf(z1[t][1] + b1r[t][1], 0.f));
                dz.y = pk2(fmaxf(z1[t][2] + b1r[t][2], 0.f),
                           fmaxf(z1[t][3] + b1r[t][3], 0.f));
                *(uint2*)(Kb + m * 40 + 16 * t + q * 4) = dz;   // Z into Kb
            }

            // ---- ffn2: O^T = W2^T · Z^T ----
            bf16x8 bZ = *(const bf16x8*)(Kb + m * 40 + q * 8);
            f32x4 o[2];
#pragma unroll
            for (int t = 0; t < 2; ++t)
                o[t] = __builtin_amdgcn_mfma_f32_16x16x32_bf16(w2f[t], bZ, zf, 0, 0, 0);

            // ---- epilogue: residual + bias -> packed uint2 stores ----
            if (n0 + 4 * u + (m >> 2) < N) {
#pragma unroll
                for (int t = 0; t < 2; ++t) {
                    uint2 dd;
                    dd.x = pk2(y[t][0] + o[t][0] + b2r[t][0],
                               y[t][1] + o[t][1] + b2r[t][1]);
                    dd.y = pk2(y[t][2] + o[t][2] + b2r[t][2],
                               y[t][3] + o[t][3] + b2r[t][3]);
                    *(uint2*)(outw + (size_t)(n0 + 4 * u) * 128 + m * 32 + 16 * t + q * 4) = dd;
                }
            }
        }
    }
}

// ---------------------------- fused CSR build -------------------------------
#define PA_CHUNK 4096
#define PA_SHIFT 9
#define PA_MAXB  256
#define HB_K     16

__global__ __launch_bounds__(256) void histB_kernel(
    const int* __restrict__ e0, const int* __restrict__ e1,
    const int* __restrict__ e2, int* __restrict__ bcnt, int E)
{
    __shared__ int lh[PA_MAXB];
    const int lab = blockIdx.y;
    const int* e = (lab == 0) ? e0 : (lab == 1) ? e1 : e2;
    const int t = threadIdx.x;
    for (int i = t; i < PA_MAXB; i += 256) lh[i] = 0;
    __syncthreads();
    const int base = blockIdx.x * 256 * HB_K;
#pragma unroll
    for (int k = 0; k < HB_K; ++k) {
        int i = base + k * 256 + t;
        if (i < E) atomicAdd(&lh[e[E + i] >> PA_SHIFT], 1);
    }
    __syncthreads();
    for (int i = t; i < PA_MAXB; i += 256)
        if (lh[i]) atomicAdd(&bcnt[i], lh[i]);
}

__global__ __launch_bounds__(256) void bscan_kernel(
    const int* __restrict__ bcnt, int* __restrict__ bbase)
{
    __shared__ int sd[PA_MAXB];
    const int t = threadIdx.x;
    sd[t] = bcnt[t];
    __syncthreads();
    int own = sd[t];
    for (int o = 1; o < 256; o <<= 1) {
        int v = (t >= o) ? sd[t - o] : 0;
        __syncthreads();
        sd[t] += v;
        __syncthreads();
    }
    bbase[t] = sd[t] - own;
}

__global__ __launch_bounds__(256) void placeA_kernel(
    const int* __restrict__ e0, const int* __restrict__ e1, const int* __restrict__ e2,
    const int* __restrict__ bbase, int* __restrict__ gres,
    int2* __restrict__ pairs, int E, int N)
{
    __shared__ int2 sStage[PA_CHUNK];
    __shared__ int sCnt[PA_MAXB], sScan[PA_MAXB], sCur[PA_MAXB], sGB[PA_MAXB];

    const int lab = blockIdx.y;
    const int t = threadIdx.x;
    const int base = blockIdx.x * PA_CHUNK;
    const int* e = (lab == 0) ? e0 : (lab == 1) ? e1 : e2;
    const int srcoff = lab * N;
    const int nbins = (N + (1 << PA_SHIFT) - 1) >> PA_SHIFT;

    for (int i = t; i < PA_MAXB; i += 256) { sCnt[i] = 0; sCur[i] = 0; }
    __syncthreads();

    int msrc[16], mdst[16];
    const int cnt_total = min(PA_CHUNK, E - base);
#pragma unroll
    for (int k = 0; k < 16; ++k) {
        int i = base + k * 256 + t;
        if (i < E) {
            msrc[k] = srcoff + e[i];
            int d = e[E + i];
            mdst[k] = d;
            atomicAdd(&sCnt[d >> PA_SHIFT], 1);
        } else mdst[k] = -1;
    }
    __syncthreads();

    sScan[t] = sCnt[t];
    __syncthreads();
    for (int o = 1; o < 256; o <<= 1) {
        int v = (t >= o) ? sScan[t - o] : 0;
        __syncthreads();
        sScan[t] += v;
        __syncthreads();
    }
    if (t < nbins && sCnt[t] > 0)
        sGB[t] = bbase[t] + atomicAdd(&gres[t], sCnt[t]);
    __syncthreads();

#pragma unroll
    for (int k = 0; k < 16; ++k) {
        if (mdst[k] >= 0) {
            int bin = mdst[k] >> PA_SHIFT;
            int r = atomicAdd(&sCur[bin], 1);
            sStage[(sScan[bin] - sCnt[bin]) + r] = make_int2(msrc[k], mdst[k]);
        }
    }
    __syncthreads();

    for (int i = t; i < cnt_total; i += 256) {
        int2 pr = sStage[i];
        int bin = pr.y >> PA_SHIFT;
        pairs[sGB[bin] + (i - (sScan[bin] - sCnt[bin]))] = pr;
    }
}

__global__ __launch_bounds__(512) void placeB_kernel(
    const int2* __restrict__ pairs, const int* __restrict__ bbase,
    const int* __restrict__ bcnt, int* __restrict__ offs,
    int* __restrict__ csr, int N, int nbins)
{
    __shared__ int sCnt[512], sScan[512], sFill[512];
    const int bin = blockIdx.x;
    const int t = threadIdx.x;
    const int n0 = bin << PA_SHIFT;
    const int n1 = min(n0 + 512, N);
    const int len = n1 - n0;
    const int rb  = bbase[bin];
    const int cnt = bcnt[bin];
    const int2* gp = pairs + rb;

    sCnt[t] = 0; sFill[t] = 0;
    __syncthreads();
    for (int i = t; i < cnt; i += 512)
        atomicAdd(&sCnt[gp[i].y - n0], 1);
    __syncthreads();
    sScan[t] = sCnt[t];
    __syncthreads();
    for (int o = 1; o < 512; o <<= 1) {
        int v = (t >= o) ? sScan[t - o] : 0;
        __syncthreads();
        sScan[t] += v;
        __syncthreads();
    }
    const int excl = sScan[t] - sCnt[t];
    if (t < len) offs[n0 + t] = rb + excl;
    if (bin == nbins - 1 && t == 0) offs[N] = rb + cnt;
    sScan[t] = excl;
    __syncthreads();

    for (int i = t; i < cnt; i += 512) {
        int2 pr = gp[i];
        int ln = pr.y - n0;
        int p = atomicAdd(&sFill[ln], 1);
        csr[rb + sScan[ln] + p] = pr.x;
    }
}

// ---------------------------- fused aggregation -----------------------------
// round-6 form: 4 dst/block, 64 lanes/row (ushort2), unroll-8.
__global__ __launch_bounds__(256) void agg3_kernel(
    const unsigned short* __restrict__ xtR,
    const unsigned short* __restrict__ xt3,
    const int* __restrict__ csr, const int* __restrict__ offs,
    unsigned short* __restrict__ hout, int N)
{
    int w = threadIdx.x >> 6, lane = threadIdx.x & 63;
    int dst = blockIdx.x * 4 + w;
    if (dst >= N) return;

    const ushort2* r2 = (const ushort2*)xtR;
    ushort2 rv = r2[(size_t)dst * 64 + lane];
    float2 a[8];
    a[0] = make_float2(bf2f(rv.x), bf2f(rv.y));
#pragma unroll
    for (int i = 1; i < 8; ++i) a[i] = make_float2(0.f, 0.f);

    const ushort2* x2 = (const ushort2*)xt3;
    const int beg = offs[dst], end = offs[dst + 1];
    int k = beg;
    for (; k + 8 <= end; k += 8) {
        int s[8];
#pragma unroll
        for (int i = 0; i < 8; ++i) s[i] = csr[k + i];
        ushort2 v[8];
#pragma unroll
        for (int i = 0; i < 8; ++i) v[i] = x2[(size_t)s[i] * 64 + lane];
#pragma unroll
        for (int i = 0; i < 8; ++i) {
            a[i].x += bf2f(v[i].x); a[i].y += bf2f(v[i].y);
        }
    }
    for (; k + 2 <= end; k += 2) {
        int s0 = csr[k], s1 = csr[k + 1];
        ushort2 v0 = x2[(size_t)s0 * 64 + lane];
        ushort2 v1 = x2[(size_t)s1 * 64 + lane];
        a[0].x += bf2f(v0.x); a[0].y += bf2f(v0.y);
        a[1].x += bf2f(v1.x); a[1].y += bf2f(v1.y);
    }
    for (; k < end; ++k) {
        int s0 = csr[k];
        ushort2 v0 = x2[(size_t)s0 * 64 + lane];
        a[0].x += bf2f(v0.x); a[0].y += bf2f(v0.y);
    }
    float sx = ((a[0].x + a[1].x) + (a[2].x + a[3].x)) +
               ((a[4].x + a[5].x) + (a[6].x + a[7].x));
    float sy = ((a[0].y + a[1].y) + (a[2].y + a[3].y)) +
               ((a[4].y + a[5].y) + (a[6].y + a[7].y));
    ushort2 o;
    o.x = (unsigned short)f2bf(fmaxf(sx, 0.f));
    o.y = (unsigned short)f2bf(fmaxf(sy, 0.f));
    ((ushort2*)hout)[(size_t)dst * 64 + lane] = o;
}

// ---------------------------- pool / counts / decoder ----------------------
__global__ __launch_bounds__(256) void pool_kernel(
    const unsigned short* __restrict__ in, const int* __restrict__ batch,
    float* __restrict__ gsum, int N)
{
    int t = threadIdx.x;
    int j = t & 127, half = t >> 7;
    int n0 = blockIdx.x * 64 + half * 32;
    float acc = 0.f; int cur = -1;
    for (int i = 0; i < 32; ++i) {
        int n = n0 + i;
        if (n >= N) break;
        int g = batch[n];
        if (g != cur) {
            if (cur >= 0) atomicAdd(&gsum[cur * 128 + j], acc);
            cur = g; acc = 0.f;
        }
        acc += bf2f(in[(size_t)n * 128 + j]);   // h already relu'd
    }
    if (cur >= 0) atomicAdd(&gsum[cur * 128 + j], acc);
}

__global__ __launch_bounds__(256) void cnt_kernel(
    const int* __restrict__ batch, float* __restrict__ gcnt, int N)
{
    __shared__ float lh[64];
    int t = threadIdx.x;
    if (t < 64) lh[t] = 0.f;
    __syncthreads();
    int i = blockIdx.x * 256 + t;
    if (i < N) atomicAdd(&lh[batch[i]], 1.0f);
    __syncthreads();
    if (t < 64 && lh[t] != 0.f) atomicAdd(&gcnt[t], lh[t]);
}

__global__ __launch_bounds__(128) void dec_kernel(
    const float* __restrict__ gsum, const float* __restrict__ gcnt,
    const float* __restrict__ W1, const float* __restrict__ B1,
    const float* __restrict__ W2, const float* __restrict__ B2,
    float* __restrict__ out)
{
    __shared__ float sg[128];
    __shared__ float sh[128];
    int t = threadIdx.x, b = blockIdx.x;
    float cinv = 1.0f / fmaxf(gcnt[b], 1.0f);
    sg[t] = gsum[b * 128 + t] * cinv;
    __syncthreads();
    float acc = B1[t];
    for (int f = 0; f < 128; ++f) acc += sg[f] * W1[f * 128 + t];
    sh[t] = fmaxf(acc, 0.f) * W2[t];
    __syncthreads();
    for (int o = 64; o > 0; o >>= 1) {
        if (t < o) sh[t] += sh[t + o];
        __syncthreads();
    }
    if (t == 0) out[b] = sh[0] + B2[0];
}

// ---------------------------- launch ---------------------------------------
extern "C" void kernel_launch(void* const* d_in, const int* in_sizes, int n_in,
                              void* d_out, int out_size, void* d_ws, size_t ws_size,
                              hipStream_t stream)
{
    const float* x    = (const float*)d_in[0];
    const int*   e0   = (const int*)d_in[1];
    const int*   e1   = (const int*)d_in[2];
    const int*   e2   = (const int*)d_in[3];
    const int*   bat  = (const int*)d_in[4];
    const float* Wemb = (const float*)d_in[5];
    const float* qkv  = (const float*)d_in[6];
    const float* fw1  = (const float*)d_in[7];
    const float* fb1  = (const float*)d_in[8];
    const float* fw2  = (const float*)d_in[9];
    const float* fb2  = (const float*)d_in[10];
    const float* mw1  = (const float*)d_in[11];
    const float* mb1  = (const float*)d_in[12];
    const float* mw2  = (const float*)d_in[13];
    const float* mb2  = (const float*)d_in[14];
    const int N = in_sizes[0] / 112;
    const int E = in_sizes[1] / 2;
    float* outp = (float*)d_out;
    (void)n_in; (void)out_size; (void)ws_size;

    char* w = (char*)d_ws;
    auto alloc = [&](size_t bytes) {
        char* p = w; w += (bytes + 255) & ~(size_t)255; return p;
    };
    unsigned short* h0    = (unsigned short*)alloc((size_t)N * 128 * 2);
    unsigned short* h1    = (unsigned short*)alloc((size_t)N * 128 * 2);
    unsigned short* xtR   = (unsigned short*)alloc((size_t)N * 128 * 2);
    unsigned short* xt3   = (unsigned short*)alloc((size_t)3 * N * 128 * 2);
    unsigned short* wpack = (unsigned short*)alloc(8 * 10 * 64 * 8 * 2);
    int*   csr   = (int*)alloc((size_t)3 * E * 4);
    int*   offs  = (int*)alloc((size_t)(N + 1) * 4);
    int*   bcnt  = (int*)alloc(PA_MAXB * 4);
    int*   bbase = (int*)alloc(PA_MAXB * 4);
    int*   gres  = (int*)alloc(PA_MAXB * 4);
    float* gsum  = (float*)alloc(64 * 128 * 4);
    float* gcnt  = (float*)alloc(64 * 4);
    // pairs (3*E*8 = 19.2 MB) aliased into xtR (25.6 MB): consumed by placeB
    // before attn4 first writes xtR (stream-ordered).
    int2* pairs = (int2*)xtR;

    const int nbins = (N + (1 << PA_SHIFT) - 1) >> PA_SHIFT;

    hipMemsetAsync(bcnt, 0, PA_MAXB * 4, stream);
    hipMemsetAsync(gres, 0, PA_MAXB * 4, stream);
    hipMemsetAsync(gsum, 0, 64 * 128 * 4, stream);
    hipMemsetAsync(gcnt, 0, 64 * 4, stream);

    wprep_kernel<<<8, 64, 0, stream>>>(qkv, fw1, fw2, wpack);
    enc_kernel<<<(N + 7) / 8, 128, 0, stream>>>(x, Wemb, h0, N);

    histB_kernel<<<dim3((E + 256 * HB_K - 1) / (256 * HB_K), 3), 256, 0, stream>>>(
        e0, e1, e2, bcnt, E);
    bscan_kernel<<<1, 256, 0, stream>>>(bcnt, bbase);
    placeA_kernel<<<dim3((E + PA_CHUNK - 1) / PA_CHUNK, 3), 256, 0, stream>>>(
        e0, e1, e2, bbase, gres, pairs, E, N);
    placeB_kernel<<<nbins, 512, 0, stream>>>(pairs, bbase, bcnt, offs, csr, N, nbins);

    const int ATT_GRID = 1024;
    auto run_layer = [&](const unsigned short* lin, unsigned short* lout, int l) {
        attn4_kernel<<<ATT_GRID, 256, 0, stream>>>(
            lin, xtR, xt3, wpack, fb1, fb2, l * 4, N);
        agg3_kernel<<<(N + 3) / 4, 256, 0, stream>>>(xtR, xt3, csr, offs, lout, N);
    };
    run_layer(h0, h1, 0);
    run_layer(h1, h0, 1);

    pool_kernel<<<(N + 63) / 64, 256, 0, stream>>>(h0, bat, gsum, N);
    cnt_kernel<<<(N + 255) / 256, 256, 0, stream>>>(bat, gcnt, N);
    dec_kernel<<<64, 128, 0, stream>>>(gsum, gcnt, mw1, mb1, mw2, mb2, outp);
}